// Round 1
// baseline (23913.127 us; speedup 1.0000x reference)
//
#include <hip/hip_runtime.h>
#include <math.h>

// ---------------- problem constants ----------------
#define TN   256
#define TWM  64
#define TR   4
#define TH   512
#define TD   512
#define TT   128
#define TB   32
#define IFACE 471
#define EPSI 1e-6f

// ---------------- workspace layout (floats) ----------------
#define OFF_H      0          // 2 x 32*512 ping-pong
#define OFF_C      32768
#define OFF_M      49152      // 32*256*64
#define OFF_USAGE  573440
#define OFF_RW     581632     // 32*4*256
#define OFF_WW     614400
#define OFF_PRECA  622592     // prec ping/pong (2 x 8192)
#define OFF_LINK   638976     // 32*256*256
#define OFF_RVEC   2736128
#define OFF_MNORM  2744320    // 32*256 row norms of current M
#define OFF_ZP     2752512    // 16 x 32 x 480 z partials (cols 471..479 are pad)
#define OFF_PARSE  2998272    // 32 x 448 parsed interface (cols 404..447 unwritten)
#define OFF_CRS    3012608    // 32 x 4 x 256 cr logits
#define OFF_FW     3045376    // 32 x 4 x 256
#define OFF_BWP    3078144    // 256 x 4 x 256 bw chunk partials
#define TOTAL_STATE 3340288

// barrier cells: in PARSE pad columns (>=416) — lines NEVER touched by plain
// stores after k_init, so cross-XCD dirty-line writeback can't clobber them.
#define BAR_GRP(g) (OFF_PARSE + (g)*448 + 416)
#define BAR_ROOT   (OFF_PARSE + 8*448 + 416)
#define BAR_GEN    (OFF_PARSE + 9*448 + 416)

__device__ __forceinline__ float sigm(float x)  { return 1.0f / (1.0f + expf(-x)); }
__device__ __forceinline__ float softpl(float x){ return x > 20.0f ? x : log1pf(expf(x)); }

// ---------------- init ----------------
__global__ void k_init(float* ws) {
    int idx = blockIdx.x * 256 + threadIdx.x;
    if (idx >= TOTAL_STATE) return;
    float v = 0.0f;
    if (idx >= OFF_M && idx < OFF_M + TB*TN*TWM) v = EPSI;
    if (idx >= OFF_MNORM && idx < OFF_MNORM + TB*TN) v = 8e-6f;  // sqrt(64*EPS^2)
    ws[idx] = v;
}

// ---------------- two-level grid barrier (256 blocks = 8 groups of 32) ----------------
__device__ __forceinline__ void gsync(float* ws, unsigned& lgen, const int tid, const int blk)
{
    __syncthreads();
    if (tid == 0) {
        ++lgen;
        __threadfence();   // agent-scope release: L2 writeback so other XCDs see our stores
        unsigned* grp  = (unsigned*)(ws + BAR_GRP(blk >> 5));
        unsigned* root = (unsigned*)(ws + BAR_ROOT);
        unsigned* gen  = (unsigned*)(ws + BAR_GEN);
        bool done = false;
        if (__hip_atomic_fetch_add(grp, 1u, __ATOMIC_ACQ_REL, __HIP_MEMORY_SCOPE_AGENT) == 31u) {
            __hip_atomic_store(grp, 0u, __ATOMIC_RELAXED, __HIP_MEMORY_SCOPE_AGENT);
            if (__hip_atomic_fetch_add(root, 1u, __ATOMIC_ACQ_REL, __HIP_MEMORY_SCOPE_AGENT) == 7u) {
                __hip_atomic_store(root, 0u, __ATOMIC_RELAXED, __HIP_MEMORY_SCOPE_AGENT);
                __hip_atomic_store(gen, lgen, __ATOMIC_RELEASE, __HIP_MEMORY_SCOPE_AGENT);
                done = true;
            }
        }
        if (!done) {
            while (__hip_atomic_load(gen, __ATOMIC_RELAXED, __HIP_MEMORY_SCOPE_AGENT) < lgen)
                __builtin_amdgcn_s_sleep(1);
        }
        __threadfence();   // acquire side: invalidate L1/L2 so we read fresh data
    }
    __syncthreads();
}

// ---------------- out(t-1) GEMM: one of 128 jobs (B2 in [0,128)) ----------------
__device__ __forceinline__ void out_phase(
    const float* __restrict__ W_pre, const float* __restrict__ b_pre,
    const float* __restrict__ W_rout, const float* __restrict__ ws,
    float* __restrict__ out, float* sm, const int tid, const int B2, const int t)
{
    float* act_s = sm;          // 4 batches x 768
    float* red_s = sm + 3072;   // 16 ksub x 4 b x 32 col
    const int q = B2 >> 5, s = (B2 >> 3) & 3, bg = B2 & 7, b0 = bg * 4;
    for (int i = tid; i < 768; i += 512) {
        const int bb = i / 192;
        const int k0 = (i - bb*192) * 4;
        const float* src = (k0 < 512) ? &ws[OFF_H + (t&1)*(TB*TH) + (b0+bb)*TH + k0]
                                      : &ws[OFF_RVEC + (b0+bb)*256 + (k0 - 512)];
        *(float4*)&act_s[bb*768 + k0] = *(const float4*)src;
    }
    __syncthreads();
    const int c0 = q*128 + s*32;
    const int col = tid & 31;
    const int ksb = tid >> 5;     // 0..15, 48 k each
    float a0=0, a1=0, a2=0, a3=0;
    for (int kk = ksb*48; kk < ksb*48 + 48; ++kk) {
        const float w = (kk < 512) ? W_pre[(size_t)kk * 512 + c0 + col]
                                   : W_rout[(size_t)(kk - 512) * 512 + c0 + col];
        a0 += act_s[kk]        * w;
        a1 += act_s[768 + kk]  * w;
        a2 += act_s[1536 + kk] * w;
        a3 += act_s[2304 + kk] * w;
    }
    red_s[(ksb*4 + 0)*32 + col] = a0;
    red_s[(ksb*4 + 1)*32 + col] = a1;
    red_s[(ksb*4 + 2)*32 + col] = a2;
    red_s[(ksb*4 + 3)*32 + col] = a3;
    __syncthreads();
    if (tid < 128) {
        const int cc = tid & 31, bb = tid >> 5;
        float ssum = 0.0f;
        #pragma unroll
        for (int ks2 = 0; ks2 < 16; ++ks2) ssum += red_s[(ks2*4 + bb)*32 + cc];
        ssum += b_pre[c0 + cc];
        out[(size_t)(t - 1) * (TB * TD) + (b0+bb) * TD + c0 + cc] = ssum;
    }
}

// ---------------- THE persistent kernel: all 128 timesteps, 5 phases/step ----------------
__global__ __launch_bounds__(512) void k_dnc(
    const float* __restrict__ emb, const float* __restrict__ Wx,
    const float* __restrict__ Wh,  const float* __restrict__ b_lstm,
    const float* __restrict__ W_pre, const float* __restrict__ b_pre,
    const float* __restrict__ W_if, const float* __restrict__ b_if,
    const float* __restrict__ W_rout,
    float* __restrict__ ws, float* __restrict__ out)
{
    __shared__ __align__(16) float sm[12352];   // 48.25 KB, reused by every phase
    const int blk = blockIdx.x;
    const int tid = threadIdx.x;
    unsigned lgen = 0;

    for (int t = 0; t < TT; ++t) {
        // ================= P1: gates GEMM + LSTM (all 256 blocks, 2 u-cols each) =================
        {
            const int u0 = blk * 2;
            const int cg = tid & 3;
            const int bg = (tid >> 2) & 7;
            const int ks = tid >> 5;
            const int col0 = cg * 512 + u0;
            const float* hbuf = ws + OFF_H + (t & 1) * (TB * TH);
            float acc[2][4] = {};

            for (int tile = 0; tile < 5; ++tile) {
                const int T0 = tile * 256;
                {
                    const int b = tid & 31, kf4 = tid >> 5;
                    #pragma unroll
                    for (int i = 0; i < 4; ++i) {
                        const int kl = (kf4 * 4 + i) * 4;
                        const int k  = T0 + kl;
                        const float* src;
                        if (k < 512)      src = emb + (size_t)t * (TB*TD) + b * TD + k;
                        else if (k < 768) src = ws + OFF_RVEC + b * 256 + (k - 512);
                        else              src = hbuf + b * TH + (k - 768);
                        float4 v = *(const float4*)src;
                        sm[(kl+0)*32 + b] = v.x;
                        sm[(kl+1)*32 + b] = v.y;
                        sm[(kl+2)*32 + b] = v.z;
                        sm[(kl+3)*32 + b] = v.w;
                    }
                }
                __syncthreads();
                {
                    const int k0 = T0 + ks * 16;
                    const float* wp = (k0 < 768 ? Wx + (size_t)k0 * 2048
                                                : Wh + (size_t)(k0 - 768) * 2048) + col0;
                    const float* ap = &sm[(ks * 16) * 32 + bg * 4];
                    #pragma unroll 8
                    for (int kk = 0; kk < 16; ++kk) {
                        float2 wv = *(const float2*)wp; wp += 2048;
                        float4 av = *(const float4*)ap; ap += 32;
                        acc[0][0] += wv.x*av.x; acc[0][1] += wv.x*av.y; acc[0][2] += wv.x*av.z; acc[0][3] += wv.x*av.w;
                        acc[1][0] += wv.y*av.x; acc[1][1] += wv.y*av.y; acc[1][2] += wv.y*av.z; acc[1][3] += wv.y*av.w;
                    }
                }
                __syncthreads();
            }
            {
                const int rbase = 8192 + ks * 256 + (cg * 2) * 32 + bg * 4;
                *(float4*)&sm[rbase]      = make_float4(acc[0][0], acc[0][1], acc[0][2], acc[0][3]);
                *(float4*)&sm[rbase + 32] = make_float4(acc[1][0], acc[1][1], acc[1][2], acc[1][3]);
            }
            __syncthreads();
            if (tid < 256) {
                float s = 0.0f;
                #pragma unroll
                for (int kq = 0; kq < 16; ++kq) s += sm[8192 + kq * 256 + tid];
                const int cb = tid >> 5;                 // cg*2 + d
                s += b_lstm[(cb >> 1) * 512 + u0 + (cb & 1)];
                sm[tid] = s;                             // layout cb*32 + b
            }
            __syncthreads();
            if (tid < 64) {
                const int d = tid >> 5, b = tid & 31;
                const float ig = sm[(0 + d) * 32 + b];
                const float fg = sm[(2 + d) * 32 + b];
                const float gg = sm[(4 + d) * 32 + b];
                const float og = sm[(6 + d) * 32 + b];
                const int ci = b * TH + u0 + d;
                const float cold = ws[OFF_C + ci];
                const float cn = sigm(fg) * cold + sigm(ig) * tanhf(gg);
                const float hn = sigm(og) * tanhf(cn);
                ws[OFF_C + ci] = cn;
                ws[OFF_H + ((t + 1) & 1) * (TB * TH) + ci] = hn;
            }
        }
        gsync(ws, lgen, tid, blk);

        // ================= P2: z partials (blk 0..127)  ||  out(t-1) (blk 128..255) =================
        if (blk < 128) {
            const int q = blk >> 5, s = (blk >> 3) & 3, bg = blk & 7, b0 = bg * 4;
            float* h1_s = sm;   // 4 batches x 32 k
            if (tid < 128) {
                const int bb = tid >> 5, kk = tid & 31;
                h1_s[bb*32 + kk] = ws[OFF_H + ((t+1)&1)*(TB*TH) + (b0+bb)*TH + q*128 + s*32 + kk];
            }
            __syncthreads();
            if (tid < IFACE) {
                const int col = tid;
                float a0=0, a1=0, a2=0, a3=0;
                const float* wb = W_if + (size_t)(q*128 + s*32) * IFACE + col;
                #pragma unroll 8
                for (int kk = 0; kk < 32; ++kk) {
                    const float w = *wb; wb += IFACE;
                    a0 += h1_s[kk]      * w;
                    a1 += h1_s[32+kk]   * w;
                    a2 += h1_s[64+kk]   * w;
                    a3 += h1_s[96+kk]   * w;
                }
                const size_t base = OFF_ZP + ((size_t)(q*4+s)*32 + b0) * 480 + col;
                ws[base]         = a0;
                ws[base + 480]   = a1;
                ws[base + 960]   = a2;
                ws[base + 1440]  = a3;
            }
        } else if (t > 0) {
            out_phase(W_pre, b_pre, W_rout, ws, out, sm, tid, blk - 128, t);
        }
        gsync(ws, lgen, tid, blk);

        // ================= P3: stepA (blocks 0..31, one batch each) =================
        if (blk < 32) {
            const int b = blk;
            float* z_s      = sm + 0;     // 480
            float* rwf_s    = sm + 480;   // 1024
            float* ww_old_s = sm + 1504;  // 256
            float* ww_s     = sm + 1760;  // 256
            float* u_s      = sm + 2016;  // 256
            float* prec_s   = sm + 2272;  // 256
            float* mnorm_s  = sm + 2528;  // 256
            float* alloc_s  = sm + 2784;  // 256
            float* cw_s     = sm + 3040;  // 256
            float* keysp    = sm + 3296;  // 256 (4x64)
            float* wkey_s   = sm + 3552;  // 64
            float* erase_s  = sm + 3616;  // 64
            float* wvec_s   = sm + 3680;  // 64
            float* rstr_s   = sm + 3744;  // 4
            float* free_s   = sm + 3748;  // 4
            float* modesp   = sm + 3752;  // 12
            float* knorm_s  = sm + 3764;  // 8
            float* sredA_s  = sm + 3772;  // 8
            float* sc_s     = sm + 3780;  // 8
            float* Pt_s     = sm + 3788;  // 512

            const float* wsM = ws + OFF_M + b * (TN * TWM);
            const float* precOld = ws + OFF_PRECA + (t & 1) * (TB * TN) + b * 256;
            float* precNew = ws + OFF_PRECA + ((t + 1) & 1) * (TB * TN) + b * 256;

            // ---- stage + z reduce ----
            if (tid < 256)       { *(float4*)&rwf_s[tid*4] = *(const float4*)&ws[OFF_RW + b*1024 + tid*4]; }
            else if (tid < 320)  { const int i = tid-256; *(float4*)&ww_old_s[i*4] = *(const float4*)&ws[OFF_WW + b*256 + i*4]; }
            else if (tid < 384)  { const int i = tid-320; *(float4*)&u_s[i*4]      = *(const float4*)&ws[OFF_USAGE + b*256 + i*4]; }
            else if (tid < 448)  { const int i = tid-384; *(float4*)&prec_s[i*4]   = *(const float4*)&precOld[i*4]; }
            else                 { const int i = tid-448; *(float4*)&mnorm_s[i*4]  = *(const float4*)&ws[OFF_MNORM + b*256 + i*4]; }
            if (tid < IFACE) {
                float zv = b_if[tid];
                #pragma unroll
                for (int p = 0; p < 16; ++p)
                    zv += ws[OFF_ZP + ((size_t)p*32 + b) * 480 + tid];
                z_s[tid] = zv;
            }
            __syncthreads();

            // ---- parse ----
            if (tid < IFACE) {
                const float v = z_s[tid];
                if (tid < 256)       keysp[(tid >> 6)*64 + (tid & 63)] = v;
                else if (tid < 260)  rstr_s[tid - 256] = 1.0f + softpl(v);
                else if (tid < 324)  wkey_s[tid - 260] = v;
                else if (tid == 324) sc_s[0] = 1.0f + softpl(v);
                else if (tid < 389)  erase_s[tid - 325] = sigm(v);
                else if (tid < 453)  wvec_s[tid - 389] = v;
                else if (tid < 457)  free_s[tid - 453] = sigm(v);
                else if (tid == 457) sc_s[1] = sigm(v);
                else if (tid == 458) sc_s[2] = sigm(v);
            }
            __syncthreads();
            // ---- key norms + modes ----
            if (tid < 320) {
                const int w5 = tid >> 6, lane = tid & 63;
                const float v = (w5 == 0) ? wkey_s[lane] : keysp[(w5 - 1)*64 + lane];
                float s = v * v;
                #pragma unroll
                for (int m = 1; m <= 32; m <<= 1) s += __shfl_xor(s, m);
                if (lane == 0) knorm_s[w5] = fmaxf(sqrtf(s), EPSI);
            } else if (tid >= 508) {
                const int r = tid - 508;
                const float m0 = z_s[459 + r*3], m1 = z_s[460 + r*3], m2 = z_s[461 + r*3];
                const float mx = fmaxf(m0, fmaxf(m1, m2));
                const float e0 = expf(m0 - mx), e1 = expf(m1 - mx), e2 = expf(m2 - mx);
                const float s = e0 + e1 + e2;
                modesp[r*3+0] = e0 / s; modesp[r*3+1] = e1 / s; modesp[r*3+2] = e2 / s;
            }
            __syncthreads();

            // ---- PARSE writeout + usage update ----
            if (tid < 404) {
                float v;
                if (tid < 256)       v = keysp[tid];
                else if (tid < 320)  v = erase_s[tid - 256];
                else if (tid < 384)  v = wvec_s[tid - 320];
                else if (tid < 388)  v = rstr_s[tid - 384];
                else if (tid < 392)  v = knorm_s[tid - 388 + 1];
                else                 v = modesp[tid - 392];
                ws[OFF_PARSE + b * 448 + tid] = v;
            }
            if (tid < 256) {
                float ret = 1.0f;
                #pragma unroll
                for (int r = 0; r < 4; ++r) ret *= 1.0f - free_s[r] * rwf_s[r*256 + tid];
                const float un = (u_s[tid] + ww_old_s[tid] - u_s[tid] * ww_old_s[tid]) * ret;
                u_s[tid] = un;
                ws[OFF_USAGE + b * 256 + tid] = un;
            }
            __syncthreads();

            // ---- allocation (stable lexicographic product) ----
            {
                const int q = tid >> 8, n = tid & 255;
                const float un = u_s[n];
                float p = 1.0f;
                #pragma unroll 8
                for (int m = q * 128; m < q * 128 + 128; ++m) {
                    const float um = u_s[m];
                    const bool lt = (um < un) || (um == un && m < n);
                    p *= lt ? um : 1.0f;
                }
                Pt_s[q * 256 + n] = p;
            }
            __syncthreads();
            if (tid < 256)
                alloc_s[tid] = (1.0f - u_s[tid]) * Pt_s[tid] * Pt_s[256 + tid];
            __syncthreads();

            // ---- cw content sim (M_old; norms precomputed) ----
            {
                const int n = tid >> 1, q2 = tid & 1;
                const float* mp = wsM + n * 64 + q2 * 32;
                float s = 0.0f;
                #pragma unroll
                for (int it = 0; it < 8; ++it) {
                    float4 mv = *(const float4*)(mp + it * 4);
                    float4 kv = *(const float4*)&wkey_s[q2 * 32 + it * 4];
                    s += mv.x*kv.x + mv.y*kv.y + mv.z*kv.z + mv.w*kv.w;
                }
                s += __shfl_xor(s, 1);
                if (q2 == 0) cw_s[n] = sc_s[0] * s / (knorm_s[0] * mnorm_s[n]);
            }
            __syncthreads();
            // ---- cw softmax ----
            {
                float v = 0.0f, e = 0.0f;
                if (tid < 256) {
                    v = cw_s[tid];
                    float m = v;
                    #pragma unroll
                    for (int mm = 1; mm <= 32; mm <<= 1) m = fmaxf(m, __shfl_xor(m, mm));
                    if ((tid & 63) == 0) sredA_s[tid >> 6] = m;
                }
                __syncthreads();
                if (tid == 0) sc_s[4] = fmaxf(fmaxf(sredA_s[0], sredA_s[1]), fmaxf(sredA_s[2], sredA_s[3]));
                __syncthreads();
                if (tid < 256) {
                    e = expf(v - sc_s[4]);
                    float s2 = e;
                    #pragma unroll
                    for (int mm = 1; mm <= 32; mm <<= 1) s2 += __shfl_xor(s2, mm);
                    if ((tid & 63) == 0) sredA_s[tid >> 6] = s2;
                }
                __syncthreads();
                if (tid == 0) sc_s[5] = sredA_s[0] + sredA_s[1] + sredA_s[2] + sredA_s[3];
                __syncthreads();
                if (tid < 256) cw_s[tid] = e / sc_s[5];
            }
            __syncthreads();

            // ---- ww, sum(ww), prec_new ----
            if (tid < 256) {
                const float wwn = sc_s[2] * (sc_s[1] * alloc_s[tid] + (1.0f - sc_s[1]) * cw_s[tid]);
                ww_s[tid] = wwn;
                ws[OFF_WW + b * 256 + tid] = wwn;
            }
            __syncthreads();
            if (tid < 256) {
                float s = ww_s[tid];
                #pragma unroll
                for (int mm = 1; mm <= 32; mm <<= 1) s += __shfl_xor(s, mm);
                if ((tid & 63) == 0) sredA_s[tid >> 6] = s;
            }
            __syncthreads();
            if (tid == 0) sc_s[3] = sredA_s[0] + sredA_s[1] + sredA_s[2] + sredA_s[3];
            __syncthreads();
            if (tid < 256)
                precNew[tid] = (1.0f - sc_s[3]) * prec_s[tid] + ww_s[tid];
        }
        gsync(ws, lgen, tid, blk);

        // ================= P4: link/M wide kernel (all 256 blocks) =================
        {
            const int bi = blk;
            const int b  = bi >> 3;
            const int c  = bi & 7;
            float* ww_s   = sm;          // 256
            float* prec_s = sm + 256;    // 256
            float* rw_s   = sm + 512;    // 1024
            float* pk_s   = sm + 1536;   // 448
            float* Lt     = sm + 2048;   // 32*257
            const float* precOld = ws + OFF_PRECA + (t & 1) * (TB * TN) + b * 256;

            if (tid < 64)        { *(float4*)&ww_s[tid*4] = *(const float4*)&ws[OFF_WW + b*256 + tid*4]; }
            else if (tid < 128)  { const int i = tid-64;  *(float4*)&prec_s[i*4] = *(const float4*)&precOld[i*4]; }
            else if (tid < 384)  { const int i = tid-128; *(float4*)&rw_s[i*4]   = *(const float4*)&ws[OFF_RW + b*1024 + i*4]; }
            else if (tid < 496)  { const int i = tid-384; *(float4*)&pk_s[i*4]   = *(const float4*)&ws[OFF_PARSE + b*448 + i*4]; }
            __syncthreads();

            // ---- M update + norms + cr logits for rows [32c, 32c+32) ----
            {
                const int ric = tid >> 4, c4 = (tid & 15) * 4;
                const int gi  = c * 32 + ric;
                float* mp = ws + OFF_M + b * (TN*TWM) + gi * 64 + c4;
                float4 m = *(const float4*)mp;
                const float wwi = ww_s[gi];
                float4 er = *(const float4*)&pk_s[256 + c4];
                float4 wv = *(const float4*)&pk_s[320 + c4];
                m.x = m.x * (1.0f - wwi * er.x) + wwi * wv.x;
                m.y = m.y * (1.0f - wwi * er.y) + wwi * wv.y;
                m.z = m.z * (1.0f - wwi * er.z) + wwi * wv.z;
                m.w = m.w * (1.0f - wwi * er.w) + wwi * wv.w;
                *(float4*)mp = m;
                float sn = m.x*m.x + m.y*m.y + m.z*m.z + m.w*m.w;
                float d0 = m.x*pk_s[c4]     + m.y*pk_s[c4+1]     + m.z*pk_s[c4+2]     + m.w*pk_s[c4+3];
                float d1 = m.x*pk_s[64+c4]  + m.y*pk_s[64+c4+1]  + m.z*pk_s[64+c4+2]  + m.w*pk_s[64+c4+3];
                float d2 = m.x*pk_s[128+c4] + m.y*pk_s[128+c4+1] + m.z*pk_s[128+c4+2] + m.w*pk_s[128+c4+3];
                float d3 = m.x*pk_s[192+c4] + m.y*pk_s[192+c4+1] + m.z*pk_s[192+c4+2] + m.w*pk_s[192+c4+3];
                #pragma unroll
                for (int mm = 1; mm <= 8; mm <<= 1) {
                    sn += __shfl_xor(sn, mm);
                    d0 += __shfl_xor(d0, mm); d1 += __shfl_xor(d1, mm);
                    d2 += __shfl_xor(d2, mm); d3 += __shfl_xor(d3, mm);
                }
                if ((tid & 15) == 0) {
                    const float mn = fmaxf(sqrtf(sn), EPSI);
                    ws[OFF_MNORM + b*256 + gi] = mn;
                    const float inv = 1.0f / mn;
                    ws[OFF_CRS + b*1024 + 0*256 + gi] = pk_s[384+0] * d0 * inv / pk_s[388+0];
                    ws[OFF_CRS + b*1024 + 1*256 + gi] = pk_s[384+1] * d1 * inv / pk_s[388+1];
                    ws[OFF_CRS + b*1024 + 2*256 + gi] = pk_s[384+2] * d2 * inv / pk_s[388+2];
                    ws[OFF_CRS + b*1024 + 3*256 + gi] = pk_s[384+3] * d3 * inv / pk_s[388+3];
                }
            }

            // ---- link rows update (phase A) ----
            {
                const int j = tid & 255, p = tid >> 8;
                const float wwj = ww_s[j], pj = prec_s[j];
                #pragma unroll 4
                for (int it = 0; it < 16; ++it) {
                    const int ric = it * 2 + p;
                    const int gi  = c * 32 + ric;
                    float* lp = ws + OFF_LINK + (size_t)b * (TN*TN) + (size_t)gi * 256 + j;
                    const float wwi = ww_s[gi];
                    float v = (1.0f - wwi - wwj) * (*lp) + wwi * pj;
                    if (j == gi) v = 0.0f;
                    *lp = v;
                    Lt[ric * 257 + j] = v;
                }
            }
            __syncthreads();

            // ---- fw (phase B) ----
            {
                const int ric = tid >> 4, g = tid & 15;
                const int gi = c * 32 + ric;
                float f0=0, f1=0, f2=0, f3=0;
                #pragma unroll 4
                for (int jj = 0; jj < 16; ++jj) {
                    const int j = g * 16 + jj;
                    const float v = Lt[ric * 257 + j];
                    f0 += v * rw_s[j]; f1 += v * rw_s[256+j];
                    f2 += v * rw_s[512+j]; f3 += v * rw_s[768+j];
                }
                #pragma unroll
                for (int mm = 1; mm <= 8; mm <<= 1) {
                    f0 += __shfl_xor(f0, mm); f1 += __shfl_xor(f1, mm);
                    f2 += __shfl_xor(f2, mm); f3 += __shfl_xor(f3, mm);
                }
                if (g == 0) {
                    ws[OFF_FW + b*1024 + gi]       = f0;
                    ws[OFF_FW + b*1024 + 256 + gi] = f1;
                    ws[OFF_FW + b*1024 + 512 + gi] = f2;
                    ws[OFF_FW + b*1024 + 768 + gi] = f3;
                }
            }

            // ---- bw partials (phase C) ----
            {
                const int j = tid & 255, p = tid >> 8;
                float b0=0, b1=0, b2=0, b3=0;
                #pragma unroll 4
                for (int it = 0; it < 16; ++it) {
                    const int ric = p * 16 + it;
                    const int gi  = c * 32 + ric;
                    const float v = Lt[ric * 257 + j];
                    b0 += v * rw_s[gi]; b1 += v * rw_s[256+gi];
                    b2 += v * rw_s[512+gi]; b3 += v * rw_s[768+gi];
                }
                __syncthreads();
                if (p == 1) { Lt[j] = b0; Lt[256+j] = b1; Lt[512+j] = b2; Lt[768+j] = b3; }
                __syncthreads();
                if (p == 0) {
                    ws[OFF_BWP + (size_t)bi*1024 + j]       = b0 + Lt[j];
                    ws[OFF_BWP + (size_t)bi*1024 + 256 + j] = b1 + Lt[256+j];
                    ws[OFF_BWP + (size_t)bi*1024 + 512 + j] = b2 + Lt[512+j];
                    ws[OFF_BWP + (size_t)bi*1024 + 768 + j] = b3 + Lt[768+j];
                }
            }
        }
        gsync(ws, lgen, tid, blk);

        // ================= P5: stepB (blocks 0..31) =================
        if (blk < 32) {
            const int b = blk;
            float* crp     = sm;          // 4 x 256
            float* rw2_s   = sm + 1024;   // 1024
            float* Lt2     = sm + 2048;   // 512
            float* md      = sm + 2560;   // 12
            float* sredA_s = sm + 2576;   // 8
            float* sredB_s = sm + 2584;   // 8
            float* gmax_s  = sm + 2592;   // 4
            float* gsum_s  = sm + 2596;   // 4
            const float* wsM = ws + OFF_M + b * (TN * TWM);

            crp[tid]       = ws[OFF_CRS + b*1024 + tid];
            crp[tid + 512] = ws[OFF_CRS + b*1024 + tid + 512];
            if (tid < 12) md[tid] = ws[OFF_PARSE + b*448 + 392 + tid];
            __syncthreads();

            // ---- cr softmax (heads rr, rr+2) ----
            {
                const int rr = tid >> 8, n = tid & 255, wv = tid >> 6, lane = tid & 63;
                float v0 = crp[rr*256 + n], v1 = crp[(rr + 2)*256 + n];
                float m0 = v0, m1 = v1;
                #pragma unroll
                for (int mm = 1; mm <= 32; mm <<= 1) {
                    m0 = fmaxf(m0, __shfl_xor(m0, mm));
                    m1 = fmaxf(m1, __shfl_xor(m1, mm));
                }
                if (lane == 0) { sredA_s[wv] = m0; sredB_s[wv] = m1; }
                __syncthreads();
                if (tid < 4) {
                    const float* base = (tid & 2) ? sredB_s : sredA_s;
                    const int off = (tid & 1) * 4;
                    gmax_s[tid] = fmaxf(fmaxf(base[off], base[off+1]), fmaxf(base[off+2], base[off+3]));
                }
                __syncthreads();
                const float e0 = expf(v0 - gmax_s[rr]);
                const float e1 = expf(v1 - gmax_s[rr + 2]);
                float s0 = e0, s1 = e1;
                #pragma unroll
                for (int mm = 1; mm <= 32; mm <<= 1) {
                    s0 += __shfl_xor(s0, mm); s1 += __shfl_xor(s1, mm);
                }
                if (lane == 0) { sredA_s[wv] = s0; sredB_s[wv] = s1; }
                __syncthreads();
                if (tid < 4) {
                    const float* base = (tid & 2) ? sredB_s : sredA_s;
                    const int off = (tid & 1) * 4;
                    gsum_s[tid] = base[off] + base[off+1] + base[off+2] + base[off+3];
                }
                __syncthreads();
                crp[rr*256 + n]       = e0 / gsum_s[rr];
                crp[(rr + 2)*256 + n] = e1 / gsum_s[rr + 2];
            }
            __syncthreads();

            // ---- bw reduce + rw update ----
            {
                const int rr = tid >> 8, n = tid & 255;
                #pragma unroll
                for (int p = 0; p < 2; ++p) {
                    const int r = rr + 2 * p;
                    float bw = 0.0f;
                    #pragma unroll
                    for (int c = 0; c < 8; ++c)
                        bw += ws[OFF_BWP + (size_t)(b*8 + c)*1024 + r*256 + n];
                    const float fw = ws[OFF_FW + b*1024 + r*256 + n];
                    const float v = md[r*3] * bw + md[r*3+1] * crp[r*256 + n] + md[r*3+2] * fw;
                    rw2_s[r*256 + n] = v;
                    ws[OFF_RW + b*1024 + r*256 + n] = v;
                }
            }
            __syncthreads();

            // ---- rvec = rw_new @ M_new ----
            {
                const int q2 = tid >> 8, r = (tid >> 6) & 3, w = tid & 63;
                float s = 0.0f;
                #pragma unroll 4
                for (int n = q2 * 128; n < q2 * 128 + 128; ++n)
                    s += rw2_s[r*256 + n] * wsM[n * 64 + w];
                Lt2[q2 * 256 + r * 64 + w] = s;
            }
            __syncthreads();
            if (tid < 256)
                ws[OFF_RVEC + b * 256 + tid] = Lt2[tid] + Lt2[256 + tid];
        }
        gsync(ws, lgen, tid, blk);
    }

    // final out(127): h(128) is in buffer (TT&1)=0, rvec holds rvec(128)
    if (blk >= 128)
        out_phase(W_pre, b_pre, W_rout, ws, out, sm, tid, blk - 128, TT);
}

extern "C" void kernel_launch(void* const* d_in, const int* in_sizes, int n_in,
                              void* d_out, int out_size, void* d_ws, size_t ws_size,
                              hipStream_t stream) {
    const float* emb    = (const float*)d_in[0];
    const float* Wx     = (const float*)d_in[1];
    const float* Wh     = (const float*)d_in[2];
    const float* b_lstm = (const float*)d_in[3];
    const float* W_pre  = (const float*)d_in[4];
    const float* b_pre  = (const float*)d_in[5];
    const float* W_if   = (const float*)d_in[6];
    const float* b_if   = (const float*)d_in[7];
    const float* W_rout = (const float*)d_in[8];
    float* out = (float*)d_out;
    float* ws  = (float*)d_ws;

    k_init<<<(TOTAL_STATE + 255) / 256, 256, 0, stream>>>(ws);

    void* args[] = { (void*)&emb, (void*)&Wx, (void*)&Wh, (void*)&b_lstm,
                     (void*)&W_pre, (void*)&b_pre, (void*)&W_if, (void*)&b_if,
                     (void*)&W_rout, (void*)&ws, (void*)&out };
    hipLaunchCooperativeKernel(k_dnc, dim3(256), dim3(512), args, 0, stream);
}

// Round 3
// 15201.083 us; speedup vs baseline: 1.5731x; 1.5731x over previous
//
#include <hip/hip_runtime.h>
#include <math.h>

// ---------------- problem constants ----------------
#define TN   256
#define TWM  64
#define TR   4
#define TH   512
#define TD   512
#define TT   128
#define TB   32
#define IFACE 471
#define EPSI 1e-6f

// ---------------- workspace layout (floats) ----------------
#define OFF_H      0          // 2 x 32*512 ping-pong
#define OFF_C      32768
#define OFF_M      49152      // 32*256*64
#define OFF_USAGE  573440
#define OFF_RW     581632     // 32*4*256
#define OFF_WW     614400
#define OFF_PRECA  622592     // prec ping/pong (2 x 8192)
#define OFF_LINK   638976     // 32*256*256
#define OFF_RVEC   2736128
#define OFF_MNORM  2744320    // 32*256 row norms of current M
#define OFF_ZP     2752512    // 16 x 32 x 480 z partials (cols 471..479 pad)
#define OFF_PARSE  2998272    // 32 x 448 parsed interface (cols 404..447 unwritten)
#define OFF_CRS    3012608    // 32 x 4 x 256 cr logits
#define OFF_FW     3045376    // 32 x 4 x 256
#define OFF_BWP    3078144    // 256 x 4 x 256 bw chunk partials
#define TOTAL_STATE 3340288

// barrier cells live in PARSE pad columns (col 416 of rows 0..9): never plain-written
// after k_init, each on its own 64B line.
#define BAR_GRP(g) (OFF_PARSE + (g)*448 + 416)
#define BAR_ROOT   (OFF_PARSE + 8*448 + 416)
#define BAR_GEN    (OFF_PARSE + 9*448 + 416)

__device__ __forceinline__ float sigm(float x)  { return 1.0f / (1.0f + expf(-x)); }
__device__ __forceinline__ float softpl(float x){ return x > 20.0f ? x : log1pf(expf(x)); }

// ---- device-coherent (MALL-point) scalar access: NO cache maintenance ops ----
__device__ __forceinline__ float ldc(const float* p) {
    return __hip_atomic_load(p, __ATOMIC_RELAXED, __HIP_MEMORY_SCOPE_AGENT);
}
__device__ __forceinline__ void stc(float* p, float v) {
    __hip_atomic_store(p, v, __ATOMIC_RELAXED, __HIP_MEMORY_SCOPE_AGENT);
}
__device__ __forceinline__ float4 ldcv4(const float* p) {
    float4 v;
    v.x = ldc(p); v.y = ldc(p + 1); v.z = ldc(p + 2); v.w = ldc(p + 3);
    return v;
}
__device__ __forceinline__ void stcv4(float* p, float4 v) {
    stc(p, v.x); stc(p + 1, v.y); stc(p + 2, v.z); stc(p + 3, v.w);
}

// ---------------- init ----------------
__global__ void k_init(float* ws) {
    int idx = blockIdx.x * 256 + threadIdx.x;
    if (idx >= TOTAL_STATE) return;
    float v = 0.0f;
    if (idx >= OFF_M && idx < OFF_M + TB*TN*TWM) v = EPSI;
    if (idx >= OFF_MNORM && idx < OFF_MNORM + TB*TN) v = 8e-6f;  // sqrt(64*EPS^2)
    ws[idx] = v;
}

// ---------------- two-level grid barrier: ALL-RELAXED, monotonic, no cache ops ----------------
__device__ __forceinline__ void gsync(float* ws, unsigned& lgen, const int tid, const int blk)
{
    // every wave: drain its coherent stores to the MALL before arriving
    asm volatile("s_waitcnt vmcnt(0) lgkmcnt(0)" ::: "memory");
    __syncthreads();
    if (tid == 0) {
        ++lgen;
        unsigned* grp  = (unsigned*)(ws + BAR_GRP(blk >> 5));
        unsigned* root = (unsigned*)(ws + BAR_ROOT);
        unsigned* gen  = (unsigned*)(ws + BAR_GEN);
        bool published = false;
        if (__hip_atomic_fetch_add(grp, 1u, __ATOMIC_RELAXED, __HIP_MEMORY_SCOPE_AGENT) == lgen * 32u - 1u) {
            if (__hip_atomic_fetch_add(root, 1u, __ATOMIC_RELAXED, __HIP_MEMORY_SCOPE_AGENT) == lgen * 8u - 1u) {
                __hip_atomic_store(gen, lgen, __ATOMIC_RELAXED, __HIP_MEMORY_SCOPE_AGENT);
                published = true;
            }
        }
        if (!published) {
            while (__hip_atomic_load(gen, __ATOMIC_RELAXED, __HIP_MEMORY_SCOPE_AGENT) < lgen)
                __builtin_amdgcn_s_sleep(1);
        }
    }
    __syncthreads();
}

// ---------------- out(t-1) GEMM: one of 128 jobs (B2 in [0,128)) ----------------
__device__ __forceinline__ void out_phase(
    const float* __restrict__ W_pre, const float* __restrict__ b_pre,
    const float* __restrict__ W_rout, const float* __restrict__ ws,
    float* __restrict__ out, float* sm, const int tid, const int B2, const int t)
{
    float* act_s = sm;          // 4 batches x 768
    float* red_s = sm + 3072;   // 16 ksub x 4 b x 32 col
    const int q = B2 >> 5, s = (B2 >> 3) & 3, bg = B2 & 7, b0 = bg * 4;
    {
        const int i0  = tid;
        const int bb0 = i0 / 192;
        const int k00 = (i0 - bb0*192) * 4;
        const float* s0 = (k00 < 512) ? &ws[OFF_H + (t&1)*(TB*TH) + (b0+bb0)*TH + k00]
                                      : &ws[OFF_RVEC + (b0+bb0)*256 + (k00 - 512)];
        float4 va = ldcv4(s0);
        float4 vb = make_float4(0.f,0.f,0.f,0.f);
        int bb1 = 0, k01 = 0;
        if (tid < 256) {
            const int i1 = tid + 512;
            bb1 = i1 / 192; k01 = (i1 - bb1*192) * 4;
            const float* s1 = (k01 < 512) ? &ws[OFF_H + (t&1)*(TB*TH) + (b0+bb1)*TH + k01]
                                          : &ws[OFF_RVEC + (b0+bb1)*256 + (k01 - 512)];
            vb = ldcv4(s1);
        }
        *(float4*)&act_s[bb0*768 + k00] = va;
        if (tid < 256) *(float4*)&act_s[bb1*768 + k01] = vb;
    }
    __syncthreads();
    const int c0 = q*128 + s*32;
    const int col = tid & 31;
    const int ksb = tid >> 5;     // 0..15, 48 k each
    float a0=0, a1=0, a2=0, a3=0;
    for (int kk = ksb*48; kk < ksb*48 + 48; ++kk) {
        const float w = (kk < 512) ? W_pre[(size_t)kk * 512 + c0 + col]
                                   : W_rout[(size_t)(kk - 512) * 512 + c0 + col];
        a0 += act_s[kk]        * w;
        a1 += act_s[768 + kk]  * w;
        a2 += act_s[1536 + kk] * w;
        a3 += act_s[2304 + kk] * w;
    }
    red_s[(ksb*4 + 0)*32 + col] = a0;
    red_s[(ksb*4 + 1)*32 + col] = a1;
    red_s[(ksb*4 + 2)*32 + col] = a2;
    red_s[(ksb*4 + 3)*32 + col] = a3;
    __syncthreads();
    if (tid < 128) {
        const int cc = tid & 31, bb = tid >> 5;
        float ssum = 0.0f;
        #pragma unroll
        for (int ks2 = 0; ks2 < 16; ++ks2) ssum += red_s[(ks2*4 + bb)*32 + cc];
        ssum += b_pre[c0 + cc];
        out[(size_t)(t - 1) * (TB * TD) + (b0+bb) * TD + c0 + cc] = ssum;  // plain: flushed at kernel end
    }
}

// ---------------- THE persistent kernel ----------------
__global__ __launch_bounds__(512) void k_dnc(
    const float* __restrict__ emb, const float* __restrict__ Wx,
    const float* __restrict__ Wh,  const float* __restrict__ b_lstm,
    const float* __restrict__ W_pre, const float* __restrict__ b_pre,
    const float* __restrict__ W_if, const float* __restrict__ b_if,
    const float* __restrict__ W_rout,
    float* __restrict__ ws, float* __restrict__ out)
{
    __shared__ __align__(16) float sm[12352];   // 48.25 KB, reused by every phase
    const int blk = blockIdx.x;
    const int tid = threadIdx.x;
    unsigned lgen = 0;

    for (int t = 0; t < TT; ++t) {
        // ===== P1: gates GEMM + LSTM (all 256 blocks, 2 u-cols each) =====
        {
            const int u0 = blk * 2;
            const int cg = tid & 3;
            const int bg = (tid >> 2) & 7;
            const int ks = tid >> 5;
            const int col0 = cg * 512 + u0;
            const float* hbuf = ws + OFF_H + (t & 1) * (TB * TH);
            float acc[2][4] = {};

            for (int tile = 0; tile < 5; ++tile) {
                const int T0 = tile * 256;
                {
                    const int b = tid & 31, kf4 = tid >> 5;
                    const int klb = kf4 * 16;
                    if (tile < 2) {
                        const float* src = emb + (size_t)t * (TB*TD) + b * TD + T0 + klb;
                        #pragma unroll
                        for (int i = 0; i < 4; ++i) {
                            float4 v = *(const float4*)(src + i * 4);
                            const int kl = klb + i * 4;
                            sm[(kl+0)*32 + b] = v.x;
                            sm[(kl+1)*32 + b] = v.y;
                            sm[(kl+2)*32 + b] = v.z;
                            sm[(kl+3)*32 + b] = v.w;
                        }
                    } else {
                        const float* src = (tile == 2)
                            ? ws + OFF_RVEC + b * 256 + (T0 - 512) + klb
                            : hbuf + b * TH + (T0 - 768) + klb;
                        float4 v0 = ldcv4(src);
                        float4 v1 = ldcv4(src + 4);
                        float4 v2 = ldcv4(src + 8);
                        float4 v3 = ldcv4(src + 12);
                        #pragma unroll
                        for (int i = 0; i < 4; ++i) {
                            const float4 v = (i==0)?v0:(i==1)?v1:(i==2)?v2:v3;
                            const int kl = klb + i * 4;
                            sm[(kl+0)*32 + b] = v.x;
                            sm[(kl+1)*32 + b] = v.y;
                            sm[(kl+2)*32 + b] = v.z;
                            sm[(kl+3)*32 + b] = v.w;
                        }
                    }
                }
                __syncthreads();
                {
                    const int k0 = T0 + ks * 16;
                    const float* wp = (k0 < 768 ? Wx + (size_t)k0 * 2048
                                                : Wh + (size_t)(k0 - 768) * 2048) + col0;
                    const float* ap = &sm[(ks * 16) * 32 + bg * 4];
                    #pragma unroll 8
                    for (int kk = 0; kk < 16; ++kk) {
                        float2 wv = *(const float2*)wp; wp += 2048;
                        float4 av = *(const float4*)ap; ap += 32;
                        acc[0][0] += wv.x*av.x; acc[0][1] += wv.x*av.y; acc[0][2] += wv.x*av.z; acc[0][3] += wv.x*av.w;
                        acc[1][0] += wv.y*av.x; acc[1][1] += wv.y*av.y; acc[1][2] += wv.y*av.z; acc[1][3] += wv.y*av.w;
                    }
                }
                __syncthreads();
            }
            {
                const int rbase = 8192 + ks * 256 + (cg * 2) * 32 + bg * 4;
                *(float4*)&sm[rbase]      = make_float4(acc[0][0], acc[0][1], acc[0][2], acc[0][3]);
                *(float4*)&sm[rbase + 32] = make_float4(acc[1][0], acc[1][1], acc[1][2], acc[1][3]);
            }
            __syncthreads();
            if (tid < 256) {
                float s = 0.0f;
                #pragma unroll
                for (int kq = 0; kq < 16; ++kq) s += sm[8192 + kq * 256 + tid];
                const int cb = tid >> 5;
                s += b_lstm[(cb >> 1) * 512 + u0 + (cb & 1)];
                sm[tid] = s;
            }
            __syncthreads();
            if (tid < 64) {
                const int d = tid >> 5, b = tid & 31;
                const float ig = sm[(0 + d) * 32 + b];
                const float fg = sm[(2 + d) * 32 + b];
                const float gg = sm[(4 + d) * 32 + b];
                const float og = sm[(6 + d) * 32 + b];
                const int ci = b * TH + u0 + d;
                const float cold = ws[OFF_C + ci];          // block-local: plain
                const float cn = sigm(fg) * cold + sigm(ig) * tanhf(gg);
                const float hn = sigm(og) * tanhf(cn);
                ws[OFF_C + ci] = cn;                        // block-local: plain
                stc(&ws[OFF_H + ((t + 1) & 1) * (TB * TH) + ci], hn);  // cross-block
            }
        }
        gsync(ws, lgen, tid, blk);

        // ===== P2: z partials (blk 0..127)  ||  out(t-1) (blk 128..255) =====
        if (blk < 128) {
            const int q = blk >> 5, s = (blk >> 3) & 3, bg = blk & 7, b0 = bg * 4;
            float* h1_s = sm;
            if (tid < 128) {
                const int bb = tid >> 5, kk = tid & 31;
                h1_s[bb*32 + kk] = ldc(&ws[OFF_H + ((t+1)&1)*(TB*TH) + (b0+bb)*TH + q*128 + s*32 + kk]);
            }
            __syncthreads();
            if (tid < IFACE) {
                const int col = tid;
                float a0=0, a1=0, a2=0, a3=0;
                const float* wb = W_if + (size_t)(q*128 + s*32) * IFACE + col;
                #pragma unroll 8
                for (int kk = 0; kk < 32; ++kk) {
                    const float w = *wb; wb += IFACE;
                    a0 += h1_s[kk]      * w;
                    a1 += h1_s[32+kk]   * w;
                    a2 += h1_s[64+kk]   * w;
                    a3 += h1_s[96+kk]   * w;
                }
                const size_t base = OFF_ZP + ((size_t)(q*4+s)*32 + b0) * 480 + col;
                stc(&ws[base],        a0);
                stc(&ws[base + 480],  a1);
                stc(&ws[base + 960],  a2);
                stc(&ws[base + 1440], a3);
            }
        } else if (t > 0) {
            out_phase(W_pre, b_pre, W_rout, ws, out, sm, tid, blk - 128, t);
        }
        gsync(ws, lgen, tid, blk);

        // ===== P3: stepA (blocks 0..31, one batch each) =====
        if (blk < 32) {
            const int b = blk;
            float* z_s      = sm + 0;
            float* rwf_s    = sm + 480;
            float* ww_old_s = sm + 1504;
            float* ww_s     = sm + 1760;
            float* u_s      = sm + 2016;
            float* prec_s   = sm + 2272;
            float* mnorm_s  = sm + 2528;
            float* alloc_s  = sm + 2784;
            float* cw_s     = sm + 3040;
            float* keysp    = sm + 3296;
            float* wkey_s   = sm + 3552;
            float* erase_s  = sm + 3616;
            float* wvec_s   = sm + 3680;
            float* rstr_s   = sm + 3744;
            float* free_s   = sm + 3748;
            float* modesp   = sm + 3752;
            float* knorm_s  = sm + 3764;
            float* sredA_s  = sm + 3772;
            float* sc_s     = sm + 3780;
            float* Pt_s     = sm + 3788;

            const float* wsM = ws + OFF_M + b * (TN * TWM);
            const float* precOld = ws + OFF_PRECA + (t & 1) * (TB * TN) + b * 256;
            float* precNew = ws + OFF_PRECA + ((t + 1) & 1) * (TB * TN) + b * 256;

            if (tid < 256)       { *(float4*)&rwf_s[tid*4] = ldcv4(&ws[OFF_RW + b*1024 + tid*4]); }
            else if (tid < 320)  { const int i = tid-256; *(float4*)&ww_old_s[i*4] = ldcv4(&ws[OFF_WW + b*256 + i*4]); }
            else if (tid < 384)  { const int i = tid-320; *(float4*)&u_s[i*4]      = *(const float4*)&ws[OFF_USAGE + b*256 + i*4]; }  // block-local
            else if (tid < 448)  { const int i = tid-384; *(float4*)&prec_s[i*4]   = ldcv4(&precOld[i*4]); }
            else                 { const int i = tid-448; *(float4*)&mnorm_s[i*4]  = ldcv4(&ws[OFF_MNORM + b*256 + i*4]); }
            if (tid < IFACE) {
                float zv = b_if[tid];
                #pragma unroll
                for (int p = 0; p < 16; ++p)
                    zv += ldc(&ws[OFF_ZP + ((size_t)p*32 + b) * 480 + tid]);
                z_s[tid] = zv;
            }
            __syncthreads();

            if (tid < IFACE) {
                const float v = z_s[tid];
                if (tid < 256)       keysp[(tid >> 6)*64 + (tid & 63)] = v;
                else if (tid < 260)  rstr_s[tid - 256] = 1.0f + softpl(v);
                else if (tid < 324)  wkey_s[tid - 260] = v;
                else if (tid == 324) sc_s[0] = 1.0f + softpl(v);
                else if (tid < 389)  erase_s[tid - 325] = sigm(v);
                else if (tid < 453)  wvec_s[tid - 389] = v;
                else if (tid < 457)  free_s[tid - 453] = sigm(v);
                else if (tid == 457) sc_s[1] = sigm(v);
                else if (tid == 458) sc_s[2] = sigm(v);
            }
            __syncthreads();
            if (tid < 320) {
                const int w5 = tid >> 6, lane = tid & 63;
                const float v = (w5 == 0) ? wkey_s[lane] : keysp[(w5 - 1)*64 + lane];
                float s = v * v;
                #pragma unroll
                for (int m = 1; m <= 32; m <<= 1) s += __shfl_xor(s, m);
                if (lane == 0) knorm_s[w5] = fmaxf(sqrtf(s), EPSI);
            } else if (tid >= 508) {
                const int r = tid - 508;
                const float m0 = z_s[459 + r*3], m1 = z_s[460 + r*3], m2 = z_s[461 + r*3];
                const float mx = fmaxf(m0, fmaxf(m1, m2));
                const float e0 = expf(m0 - mx), e1 = expf(m1 - mx), e2 = expf(m2 - mx);
                const float s = e0 + e1 + e2;
                modesp[r*3+0] = e0 / s; modesp[r*3+1] = e1 / s; modesp[r*3+2] = e2 / s;
            }
            __syncthreads();

            if (tid < 404) {
                float v;
                if (tid < 256)       v = keysp[tid];
                else if (tid < 320)  v = erase_s[tid - 256];
                else if (tid < 384)  v = wvec_s[tid - 320];
                else if (tid < 388)  v = rstr_s[tid - 384];
                else if (tid < 392)  v = knorm_s[tid - 388 + 1];
                else                 v = modesp[tid - 392];
                stc(&ws[OFF_PARSE + b * 448 + tid], v);
            }
            if (tid < 256) {
                float ret = 1.0f;
                #pragma unroll
                for (int r = 0; r < 4; ++r) ret *= 1.0f - free_s[r] * rwf_s[r*256 + tid];
                const float un = (u_s[tid] + ww_old_s[tid] - u_s[tid] * ww_old_s[tid]) * ret;
                u_s[tid] = un;
                ws[OFF_USAGE + b * 256 + tid] = un;   // block-local: plain
            }
            __syncthreads();

            {
                const int q = tid >> 8, n = tid & 255;
                const float un = u_s[n];
                float p = 1.0f;
                #pragma unroll 8
                for (int m = q * 128; m < q * 128 + 128; ++m) {
                    const float um = u_s[m];
                    const bool lt = (um < un) || (um == un && m < n);
                    p *= lt ? um : 1.0f;
                }
                Pt_s[q * 256 + n] = p;
            }
            __syncthreads();
            if (tid < 256)
                alloc_s[tid] = (1.0f - u_s[tid]) * Pt_s[tid] * Pt_s[256 + tid];
            __syncthreads();

            {
                const int n = tid >> 1, q2 = tid & 1;
                const float* mp = wsM + n * 64 + q2 * 32;
                float s = 0.0f;
                #pragma unroll
                for (int it = 0; it < 8; ++it) {
                    float4 mv = ldcv4(mp + it * 4);
                    float4 kv = *(const float4*)&wkey_s[q2 * 32 + it * 4];
                    s += mv.x*kv.x + mv.y*kv.y + mv.z*kv.z + mv.w*kv.w;
                }
                s += __shfl_xor(s, 1);
                if (q2 == 0) cw_s[n] = sc_s[0] * s / (knorm_s[0] * mnorm_s[n]);
            }
            __syncthreads();
            {
                float v = 0.0f, e = 0.0f;
                if (tid < 256) {
                    v = cw_s[tid];
                    float m = v;
                    #pragma unroll
                    for (int mm = 1; mm <= 32; mm <<= 1) m = fmaxf(m, __shfl_xor(m, mm));
                    if ((tid & 63) == 0) sredA_s[tid >> 6] = m;
                }
                __syncthreads();
                if (tid == 0) sc_s[4] = fmaxf(fmaxf(sredA_s[0], sredA_s[1]), fmaxf(sredA_s[2], sredA_s[3]));
                __syncthreads();
                if (tid < 256) {
                    e = expf(v - sc_s[4]);
                    float s2 = e;
                    #pragma unroll
                    for (int mm = 1; mm <= 32; mm <<= 1) s2 += __shfl_xor(s2, mm);
                    if ((tid & 63) == 0) sredA_s[tid >> 6] = s2;
                }
                __syncthreads();
                if (tid == 0) sc_s[5] = sredA_s[0] + sredA_s[1] + sredA_s[2] + sredA_s[3];
                __syncthreads();
                if (tid < 256) cw_s[tid] = e / sc_s[5];
            }
            __syncthreads();

            if (tid < 256) {
                const float wwn = sc_s[2] * (sc_s[1] * alloc_s[tid] + (1.0f - sc_s[1]) * cw_s[tid]);
                ww_s[tid] = wwn;
                stc(&ws[OFF_WW + b * 256 + tid], wwn);
            }
            __syncthreads();
            if (tid < 256) {
                float s = ww_s[tid];
                #pragma unroll
                for (int mm = 1; mm <= 32; mm <<= 1) s += __shfl_xor(s, mm);
                if ((tid & 63) == 0) sredA_s[tid >> 6] = s;
            }
            __syncthreads();
            if (tid == 0) sc_s[3] = sredA_s[0] + sredA_s[1] + sredA_s[2] + sredA_s[3];
            __syncthreads();
            if (tid < 256)
                stc(&precNew[tid], (1.0f - sc_s[3]) * prec_s[tid] + ww_s[tid]);
        }
        gsync(ws, lgen, tid, blk);

        // ===== P4: link/M wide kernel (all 256 blocks) =====
        {
            const int bi = blk;
            const int b  = bi >> 3;
            const int c  = bi & 7;
            float* ww_s   = sm;
            float* prec_s = sm + 256;
            float* rw_s   = sm + 512;
            float* pk_s   = sm + 1536;
            float* Lt     = sm + 2048;   // 32*257
            const float* precOld = ws + OFF_PRECA + (t & 1) * (TB * TN) + b * 256;

            if (tid < 64)        { *(float4*)&ww_s[tid*4] = ldcv4(&ws[OFF_WW + b*256 + tid*4]); }
            else if (tid < 128)  { const int i = tid-64;  *(float4*)&prec_s[i*4] = ldcv4(&precOld[i*4]); }
            else if (tid < 384)  { const int i = tid-128; *(float4*)&rw_s[i*4]   = ldcv4(&ws[OFF_RW + b*1024 + i*4]); }
            else if (tid < 485)  { const int i = tid-384; *(float4*)&pk_s[i*4]   = ldcv4(&ws[OFF_PARSE + b*448 + i*4]); }
            __syncthreads();

            {
                const int ric = tid >> 4, c4 = (tid & 15) * 4;
                const int gi  = c * 32 + ric;
                float* mp = ws + OFF_M + b * (TN*TWM) + gi * 64 + c4;
                float4 m = ldcv4(mp);
                const float wwi = ww_s[gi];
                float4 er = *(const float4*)&pk_s[256 + c4];
                float4 wv = *(const float4*)&pk_s[320 + c4];
                m.x = m.x * (1.0f - wwi * er.x) + wwi * wv.x;
                m.y = m.y * (1.0f - wwi * er.y) + wwi * wv.y;
                m.z = m.z * (1.0f - wwi * er.z) + wwi * wv.z;
                m.w = m.w * (1.0f - wwi * er.w) + wwi * wv.w;
                stcv4(mp, m);
                float sn = m.x*m.x + m.y*m.y + m.z*m.z + m.w*m.w;
                float d0 = m.x*pk_s[c4]     + m.y*pk_s[c4+1]     + m.z*pk_s[c4+2]     + m.w*pk_s[c4+3];
                float d1 = m.x*pk_s[64+c4]  + m.y*pk_s[64+c4+1]  + m.z*pk_s[64+c4+2]  + m.w*pk_s[64+c4+3];
                float d2 = m.x*pk_s[128+c4] + m.y*pk_s[128+c4+1] + m.z*pk_s[128+c4+2] + m.w*pk_s[128+c4+3];
                float d3 = m.x*pk_s[192+c4] + m.y*pk_s[192+c4+1] + m.z*pk_s[192+c4+2] + m.w*pk_s[192+c4+3];
                #pragma unroll
                for (int mm = 1; mm <= 8; mm <<= 1) {
                    sn += __shfl_xor(sn, mm);
                    d0 += __shfl_xor(d0, mm); d1 += __shfl_xor(d1, mm);
                    d2 += __shfl_xor(d2, mm); d3 += __shfl_xor(d3, mm);
                }
                if ((tid & 15) == 0) {
                    const float mn = fmaxf(sqrtf(sn), EPSI);
                    stc(&ws[OFF_MNORM + b*256 + gi], mn);
                    const float inv = 1.0f / mn;
                    stc(&ws[OFF_CRS + b*1024 + 0*256 + gi], pk_s[384+0] * d0 * inv / pk_s[388+0]);
                    stc(&ws[OFF_CRS + b*1024 + 1*256 + gi], pk_s[384+1] * d1 * inv / pk_s[388+1]);
                    stc(&ws[OFF_CRS + b*1024 + 2*256 + gi], pk_s[384+2] * d2 * inv / pk_s[388+2]);
                    stc(&ws[OFF_CRS + b*1024 + 3*256 + gi], pk_s[384+3] * d3 * inv / pk_s[388+3]);
                }
            }

            // ---- link rows update (block-local rows: PLAIN, stays in this XCD's L2) ----
            {
                const int j = tid & 255, p = tid >> 8;
                const float wwj = ww_s[j], pj = prec_s[j];
                #pragma unroll 4
                for (int it = 0; it < 16; ++it) {
                    const int ric = it * 2 + p;
                    const int gi  = c * 32 + ric;
                    float* lp = ws + OFF_LINK + (size_t)b * (TN*TN) + (size_t)gi * 256 + j;
                    const float wwi = ww_s[gi];
                    float v = (1.0f - wwi - wwj) * (*lp) + wwi * pj;
                    if (j == gi) v = 0.0f;
                    *lp = v;
                    Lt[ric * 257 + j] = v;
                }
            }
            __syncthreads();

            // ---- fw ----
            {
                const int ric = tid >> 4, g = tid & 15;
                const int gi = c * 32 + ric;
                float f0=0, f1=0, f2=0, f3=0;
                #pragma unroll 4
                for (int jj = 0; jj < 16; ++jj) {
                    const int j = g * 16 + jj;
                    const float v = Lt[ric * 257 + j];
                    f0 += v * rw_s[j]; f1 += v * rw_s[256+j];
                    f2 += v * rw_s[512+j]; f3 += v * rw_s[768+j];
                }
                #pragma unroll
                for (int mm = 1; mm <= 8; mm <<= 1) {
                    f0 += __shfl_xor(f0, mm); f1 += __shfl_xor(f1, mm);
                    f2 += __shfl_xor(f2, mm); f3 += __shfl_xor(f3, mm);
                }
                if (g == 0) {
                    stc(&ws[OFF_FW + b*1024 + gi],       f0);
                    stc(&ws[OFF_FW + b*1024 + 256 + gi], f1);
                    stc(&ws[OFF_FW + b*1024 + 512 + gi], f2);
                    stc(&ws[OFF_FW + b*1024 + 768 + gi], f3);
                }
            }

            // ---- bw partials ----
            {
                const int j = tid & 255, p = tid >> 8;
                float b0=0, b1=0, b2=0, b3=0;
                #pragma unroll 4
                for (int it = 0; it < 16; ++it) {
                    const int ric = p * 16 + it;
                    const int gi  = c * 32 + ric;
                    const float v = Lt[ric * 257 + j];
                    b0 += v * rw_s[gi]; b1 += v * rw_s[256+gi];
                    b2 += v * rw_s[512+gi]; b3 += v * rw_s[768+gi];
                }
                __syncthreads();
                if (p == 1) { Lt[j] = b0; Lt[256+j] = b1; Lt[512+j] = b2; Lt[768+j] = b3; }
                __syncthreads();
                if (p == 0) {
                    stc(&ws[OFF_BWP + (size_t)bi*1024 + j],       b0 + Lt[j]);
                    stc(&ws[OFF_BWP + (size_t)bi*1024 + 256 + j], b1 + Lt[256+j]);
                    stc(&ws[OFF_BWP + (size_t)bi*1024 + 512 + j], b2 + Lt[512+j]);
                    stc(&ws[OFF_BWP + (size_t)bi*1024 + 768 + j], b3 + Lt[768+j]);
                }
            }
        }
        gsync(ws, lgen, tid, blk);

        // ===== P5: stepB (blocks 0..31) =====
        if (blk < 32) {
            const int b = blk;
            float* crp     = sm;          // 4 x 256
            float* rw2_s   = sm + 1024;   // 1024
            float* Lt2     = sm + 2048;   // 8 groups x 4 r x 64 w = 2048
            float* md      = sm + 4096;   // 12
            float* sredA_s = sm + 4112;   // 8
            float* sredB_s = sm + 4120;   // 8
            float* gmax_s  = sm + 4128;   // 4
            float* gsum_s  = sm + 4132;   // 4
            const float* wsM = ws + OFF_M + b * (TN * TWM);

            crp[tid]       = ldc(&ws[OFF_CRS + b*1024 + tid]);
            crp[tid + 512] = ldc(&ws[OFF_CRS + b*1024 + tid + 512]);
            if (tid < 12) md[tid] = ldc(&ws[OFF_PARSE + b*448 + 392 + tid]);
            __syncthreads();

            // ---- cr softmax ----
            {
                const int rr = tid >> 8, n = tid & 255, wv = tid >> 6, lane = tid & 63;
                float v0 = crp[rr*256 + n], v1 = crp[(rr + 2)*256 + n];
                float m0 = v0, m1 = v1;
                #pragma unroll
                for (int mm = 1; mm <= 32; mm <<= 1) {
                    m0 = fmaxf(m0, __shfl_xor(m0, mm));
                    m1 = fmaxf(m1, __shfl_xor(m1, mm));
                }
                if (lane == 0) { sredA_s[wv] = m0; sredB_s[wv] = m1; }
                __syncthreads();
                if (tid < 4) {
                    const float* base = (tid & 2) ? sredB_s : sredA_s;
                    const int off = (tid & 1) * 4;
                    gmax_s[tid] = fmaxf(fmaxf(base[off], base[off+1]), fmaxf(base[off+2], base[off+3]));
                }
                __syncthreads();
                const float e0 = expf(v0 - gmax_s[rr]);
                const float e1 = expf(v1 - gmax_s[rr + 2]);
                float s0 = e0, s1 = e1;
                #pragma unroll
                for (int mm = 1; mm <= 32; mm <<= 1) {
                    s0 += __shfl_xor(s0, mm); s1 += __shfl_xor(s1, mm);
                }
                if (lane == 0) { sredA_s[wv] = s0; sredB_s[wv] = s1; }
                __syncthreads();
                if (tid < 4) {
                    const float* base = (tid & 2) ? sredB_s : sredA_s;
                    const int off = (tid & 1) * 4;
                    gsum_s[tid] = base[off] + base[off+1] + base[off+2] + base[off+3];
                }
                __syncthreads();
                crp[rr*256 + n]       = e0 / gsum_s[rr];
                crp[(rr + 2)*256 + n] = e1 / gsum_s[rr + 2];
            }
            __syncthreads();

            // ---- bw reduce + rw update ----
            {
                const int rr = tid >> 8, n = tid & 255;
                #pragma unroll
                for (int p = 0; p < 2; ++p) {
                    const int r = rr + 2 * p;
                    float bw = 0.0f;
                    #pragma unroll
                    for (int c = 0; c < 8; ++c)
                        bw += ldc(&ws[OFF_BWP + (size_t)(b*8 + c)*1024 + r*256 + n]);
                    const float fw = ldc(&ws[OFF_FW + b*1024 + r*256 + n]);
                    const float v = md[r*3] * bw + md[r*3+1] * crp[r*256 + n] + md[r*3+2] * fw;
                    rw2_s[r*256 + n] = v;
                    stc(&ws[OFF_RW + b*1024 + r*256 + n], v);
                }
            }
            __syncthreads();

            // ---- rvec = rw_new @ M_new (dedup'd coherent M reads, coalesced) ----
            {
                const int g8 = tid >> 6;       // 0..7 : n-group of 32 rows
                const int w  = tid & 63;
                float p0=0, p1=0, p2=0, p3=0;
                const float* mb = wsM + (size_t)(g8 * 32) * 64 + w;
                #pragma unroll 8
                for (int nn = 0; nn < 32; ++nn) {
                    const float m = ldc(mb + nn * 64);
                    const int n = g8 * 32 + nn;
                    p0 += rw2_s[n]       * m;
                    p1 += rw2_s[256 + n] * m;
                    p2 += rw2_s[512 + n] * m;
                    p3 += rw2_s[768 + n] * m;
                }
                Lt2[(g8*4 + 0)*64 + w] = p0;
                Lt2[(g8*4 + 1)*64 + w] = p1;
                Lt2[(g8*4 + 2)*64 + w] = p2;
                Lt2[(g8*4 + 3)*64 + w] = p3;
            }
            __syncthreads();
            if (tid < 256) {
                const int r = tid >> 6, w = tid & 63;
                float s = 0.0f;
                #pragma unroll
                for (int g = 0; g < 8; ++g) s += Lt2[(g*4 + r)*64 + w];
                stc(&ws[OFF_RVEC + b * 256 + tid], s);
            }
        }
        gsync(ws, lgen, tid, blk);
    }

    // final out(127): h(128) is in buffer (TT&1)=0, rvec holds rvec(128)
    if (blk >= 128)
        out_phase(W_pre, b_pre, W_rout, ws, out, sm, tid, blk - 128, TT);
}

extern "C" void kernel_launch(void* const* d_in, const int* in_sizes, int n_in,
                              void* d_out, int out_size, void* d_ws, size_t ws_size,
                              hipStream_t stream) {
    const float* emb    = (const float*)d_in[0];
    const float* Wx     = (const float*)d_in[1];
    const float* Wh     = (const float*)d_in[2];
    const float* b_lstm = (const float*)d_in[3];
    const float* W_pre  = (const float*)d_in[4];
    const float* b_pre  = (const float*)d_in[5];
    const float* W_if   = (const float*)d_in[6];
    const float* b_if   = (const float*)d_in[7];
    const float* W_rout = (const float*)d_in[8];
    float* out = (float*)d_out;
    float* ws  = (float*)d_ws;

    k_init<<<(TOTAL_STATE + 255) / 256, 256, 0, stream>>>(ws);

    void* args[] = { (void*)&emb, (void*)&Wx, (void*)&Wh, (void*)&b_lstm,
                     (void*)&W_pre, (void*)&b_pre, (void*)&W_if, (void*)&b_if,
                     (void*)&W_rout, (void*)&ws, (void*)&out };
    hipLaunchCooperativeKernel(k_dnc, dim3(256), dim3(512), args, 0, stream);
}

// Round 4
// 12866.641 us; speedup vs baseline: 1.8585x; 1.1814x over previous
//
#include <hip/hip_runtime.h>
#include <math.h>

// ---------------- problem constants ----------------
#define TN   256
#define TWM  64
#define TR   4
#define TH   512
#define TD   512
#define TT   128
#define TB   32
#define IFACE 471
#define EPSI 1e-6f

// ---------------- workspace layout (floats) ----------------
#define OFF_H      0          // 2 x 32*512 ping-pong
#define OFF_C      32768
#define OFF_M      49152      // 32*256*64
#define OFF_USAGE  573440
#define OFF_RW     581632     // 32*4*256
#define OFF_WW     614400
#define OFF_PRECA  622592     // prec ping/pong (2 x 8192)
#define OFF_LINK   638976     // 32*256*256
#define OFF_RVEC   2736128
#define OFF_MNORM  2744320    // 32*256 row norms of current M
#define OFF_ZP     2752512    // 16 x 32 x 480 z partials (cols 471..479 pad)
#define TOTAL_STATE 2998272

__device__ __forceinline__ float sigm(float x)  { return 1.0f / (1.0f + expf(-x)); }
__device__ __forceinline__ float softpl(float x){ return x > 20.0f ? x : log1pf(expf(x)); }

// ---------------- init ----------------
__global__ void k_init(float* ws) {
    int idx = blockIdx.x * 256 + threadIdx.x;
    if (idx >= TOTAL_STATE) return;
    float v = 0.0f;
    if (idx >= OFF_M && idx < OFF_M + TB*TN*TWM) v = EPSI;
    if (idx >= OFF_MNORM && idx < OFF_MNORM + TB*TN) v = 8e-6f;  // sqrt(64*EPS^2)
    ws[idx] = v;
}

// ---------------- out(t-1) GEMM device fn (verbatim round-0 job2) ----------------
__device__ __forceinline__ void out_phase(
    const float* __restrict__ W_pre, const float* __restrict__ b_pre,
    const float* __restrict__ W_rout, const float* __restrict__ ws,
    float* __restrict__ out, float* sm, const int tid, const int B2, const int t)
{
    float* act_s = sm;          // 4 batches x 768
    float* red_s = sm + 3072;   // 16 ksub x 4 b x 32 col
    const int q = B2 >> 5, s = (B2 >> 3) & 3, bg = B2 & 7, b0 = bg * 4;
    for (int i = tid; i < 768; i += 512) {
        const int bb = i / 192;
        const int k0 = (i - bb*192) * 4;
        const float* src = (k0 < 512) ? &ws[OFF_H + (t&1)*(TB*TH) + (b0+bb)*TH + k0]
                                      : &ws[OFF_RVEC + (b0+bb)*256 + (k0 - 512)];
        *(float4*)&act_s[bb*768 + k0] = *(const float4*)src;
    }
    __syncthreads();
    const int c0 = q*128 + s*32;
    const int col = tid & 31;
    const int ksb = tid >> 5;     // 0..15, 48 k each
    float a0=0, a1=0, a2=0, a3=0;
    for (int kk = ksb*48; kk < ksb*48 + 48; ++kk) {
        const float w = (kk < 512) ? W_pre[(size_t)kk * 512 + c0 + col]
                                   : W_rout[(size_t)(kk - 512) * 512 + c0 + col];
        a0 += act_s[kk]        * w;
        a1 += act_s[768 + kk]  * w;
        a2 += act_s[1536 + kk] * w;
        a3 += act_s[2304 + kk] * w;
    }
    red_s[(ksb*4 + 0)*32 + col] = a0;
    red_s[(ksb*4 + 1)*32 + col] = a1;
    red_s[(ksb*4 + 2)*32 + col] = a2;
    red_s[(ksb*4 + 3)*32 + col] = a3;
    __syncthreads();
    if (tid < 128) {
        const int cc = tid & 31, bb = tid >> 5;
        float ssum = 0.0f;
        #pragma unroll
        for (int ks2 = 0; ks2 < 16; ++ks2) ssum += red_s[(ks2*4 + bb)*32 + cc];
        ssum += b_pre[c0 + cc];
        out[(size_t)(t - 1) * (TB * TD) + (b0+bb) * TD + c0 + cc] = ssum;
    }
}

// ---------------- D1: gates (blk 0..127, round-0 verbatim) || out(t-1) (blk 128..255) ----------------
__global__ __launch_bounds__(512) void k_front(
    const float* __restrict__ emb, const float* __restrict__ Wx,
    const float* __restrict__ Wh,  const float* __restrict__ b_lstm,
    const float* __restrict__ W_pre, const float* __restrict__ b_pre,
    const float* __restrict__ W_rout,
    float* __restrict__ ws, float* __restrict__ out, int t)
{
    __shared__ __align__(16) float smem[16384];
    const int tid = threadIdx.x;
    if (blockIdx.x >= 128) {
        if (t == 0) return;
        out_phase(W_pre, b_pre, W_rout, ws, out, smem, tid, blockIdx.x - 128, t);
        return;
    }
    if (t >= TT) return;

    const int u0  = blockIdx.x * 4;
    const int cg  = tid & 3;
    const int bg  = (tid >> 2) & 7;
    const int ks  = tid >> 5;
    const int col0 = cg * 512 + u0;
    const float* hbuf = ws + OFF_H + (t & 1) * (TB * TH);

    float acc[4][4] = {};

    for (int tile = 0; tile < 5; ++tile) {
        const int T0 = tile * 256;
        {
            const int b = tid & 31, kf4 = tid >> 5;
            #pragma unroll
            for (int i = 0; i < 4; ++i) {
                const int kf = kf4 * 4 + i;
                const int kl = kf * 4;
                const int k  = T0 + kl;
                const float* src;
                if (k < 512)      src = emb + (size_t)t * (TB*TD) + b * TD + k;
                else if (k < 768) src = ws + OFF_RVEC + b * 256 + (k - 512);
                else              src = hbuf + b * TH + (k - 768);
                float4 v = *(const float4*)src;
                smem[(kl+0)*32 + b] = v.x;
                smem[(kl+1)*32 + b] = v.y;
                smem[(kl+2)*32 + b] = v.z;
                smem[(kl+3)*32 + b] = v.w;
            }
        }
        __syncthreads();
        {
            const int k0 = T0 + ks * 16;
            const float* wp = (k0 < 768 ? Wx + (size_t)k0 * 2048
                                        : Wh + (size_t)(k0 - 768) * 2048) + col0;
            const float* ap = &smem[(ks * 16) * 32 + bg * 4];
            #pragma unroll 8
            for (int kk = 0; kk < 16; ++kk) {
                float4 wv = *(const float4*)wp; wp += 2048;
                float4 av = *(const float4*)ap; ap += 32;
                acc[0][0] += wv.x*av.x; acc[0][1] += wv.x*av.y; acc[0][2] += wv.x*av.z; acc[0][3] += wv.x*av.w;
                acc[1][0] += wv.y*av.x; acc[1][1] += wv.y*av.y; acc[1][2] += wv.y*av.z; acc[1][3] += wv.y*av.w;
                acc[2][0] += wv.z*av.x; acc[2][1] += wv.z*av.y; acc[2][2] += wv.z*av.z; acc[2][3] += wv.z*av.w;
                acc[3][0] += wv.w*av.x; acc[3][1] += wv.w*av.y; acc[3][2] += wv.w*av.z; acc[3][3] += wv.w*av.w;
            }
        }
        __syncthreads();
    }

    {
        const int rbase = 8192 + ks * 512 + (cg * 8 + bg) * 16;
        *(float4*)&smem[rbase + 0]  = make_float4(acc[0][0], acc[0][1], acc[0][2], acc[0][3]);
        *(float4*)&smem[rbase + 4]  = make_float4(acc[1][0], acc[1][1], acc[1][2], acc[1][3]);
        *(float4*)&smem[rbase + 8]  = make_float4(acc[2][0], acc[2][1], acc[2][2], acc[2][3]);
        *(float4*)&smem[rbase + 12] = make_float4(acc[3][0], acc[3][1], acc[3][2], acc[3][3]);
    }
    __syncthreads();
    {
        const int o = tid;
        float s = 0.0f;
        #pragma unroll
        for (int kq = 0; kq < 16; ++kq) s += smem[8192 + kq * 512 + o];
        const int ocg = o >> 7, obg = (o >> 4) & 7, odu = (o >> 2) & 3, obb = o & 3;
        s += b_lstm[ocg * 512 + u0 + odu];
        smem[(ocg * 4 + odu) * 32 + (obg * 4 + obb)] = s;
    }
    __syncthreads();
    if (tid < 128) {
        const int du = tid >> 5, b = tid & 31;
        const float ig = smem[(0  + du) * 32 + b];
        const float fg = smem[(4  + du) * 32 + b];
        const float gg = smem[(8  + du) * 32 + b];
        const float og = smem[(12 + du) * 32 + b];
        const int ci = b * TH + u0 + du;
        const float cold = ws[OFF_C + ci];
        const float cn = sigm(fg) * cold + sigm(ig) * tanhf(gg);
        const float hn = sigm(og) * tanhf(cn);
        ws[OFF_C + ci] = cn;
        ws[OFF_H + ((t + 1) & 1) * (TB * TH) + ci] = hn;
    }
}

// ---------------- D2: z partials (128 blocks, verbatim round-0 job1) ----------------
__global__ __launch_bounds__(512) void k_zp(
    const float* __restrict__ W_if, float* __restrict__ ws, int t)
{
    __shared__ __align__(16) float h1_s[128];
    const int tid = threadIdx.x;
    const int q  = blockIdx.x >> 5;
    const int s  = (blockIdx.x >> 3) & 3;
    const int bg = blockIdx.x & 7;
    const int b0 = bg * 4;

    if (tid < 128) {
        const int bb = tid >> 5, kk = tid & 31;
        h1_s[bb*32 + kk] = ws[OFF_H + ((t+1)&1)*(TB*TH) + (b0+bb)*TH + q*128 + s*32 + kk];
    }
    __syncthreads();
    if (tid < IFACE) {
        const int col = tid;
        float a0=0, a1=0, a2=0, a3=0;
        const float* wb = W_if + (size_t)(q*128 + s*32) * IFACE + col;
        #pragma unroll 8
        for (int kk = 0; kk < 32; ++kk) {
            const float w = *wb; wb += IFACE;
            a0 += h1_s[kk]      * w;
            a1 += h1_s[32+kk]   * w;
            a2 += h1_s[64+kk]   * w;
            a3 += h1_s[96+kk]   * w;
        }
        const size_t base = OFF_ZP + ((size_t)(q*4+s)*32 + b0) * 480 + col;
        ws[base]         = a0;
        ws[base + 480]   = a1;
        ws[base + 960]   = a2;
        ws[base + 1440]  = a3;
    }
}

// ---------------- D3: per-batch fused stepA + link + stepB (32 blocks) ----------------
__global__ __launch_bounds__(512) void k_batch(
    const float* __restrict__ b_if, float* __restrict__ ws, int t)
{
    __shared__ __align__(16) float sm[16640];   // 65 KB
    float* z_s      = sm;            // 480
    float* rwf_s    = sm + 480;      // 1024 (rw old)
    float* ww_old_s = sm + 1504;     // 256
    float* ww_s     = sm + 1760;     // 256
    float* u_s      = sm + 2016;     // 256
    float* prec_s   = sm + 2272;     // 256 (prec old)
    float* mnorm_s  = sm + 2528;     // 256 (M-norm old)
    float* alloc_s  = sm + 2784;     // 256
    float* cw_s     = sm + 3040;     // 256
    float* keysp    = sm + 3296;     // 256 (4x64 read keys)
    float* wkey_s   = sm + 3552;     // 64
    float* erase_s  = sm + 3616;     // 64
    float* wvec_s   = sm + 3680;     // 64
    float* rstr_s   = sm + 3744;     // 4
    float* free_s   = sm + 3748;     // 4
    float* modesp   = sm + 3752;     // 12
    float* knorm_s  = sm + 3764;     // 8  [0]=wkey, [1..4]=read keys
    float* sredA_s  = sm + 3772;     // 8
    float* sredB_s  = sm + 3780;     // 8
    float* sc_s     = sm + 3788;     // 8
    float* gmax_s   = sm + 3796;     // 4
    float* gsum_s   = sm + 3800;     // 4
    float* Pt_s     = sm + 3808;     // 512
    float* crs_s    = sm + 4320;     // 1024 cr logits
    float* fw_s     = sm + 5344;     // 1024
    float* bw_s     = sm + 6368;     // 1024
    float* rw2_s    = sm + 7392;     // 1024
    float* Lt       = sm + 8416;     // 8224 (32*257), reused as Lt2 in rvec

    const int b   = blockIdx.x;
    const int tid = threadIdx.x;
    float* wsM = ws + OFF_M + b * (TN * TWM);
    const float* precOld = ws + OFF_PRECA + (t & 1) * (TB * TN) + b * 256;
    float* precNew = ws + OFF_PRECA + ((t + 1) & 1) * (TB * TN) + b * 256;

    // ================== stepA ==================
    // ---- stage + z reduce ----
    if (tid < 256)       { *(float4*)&rwf_s[tid*4] = *(const float4*)&ws[OFF_RW + b*1024 + tid*4]; }
    else if (tid < 320)  { const int i = tid-256; *(float4*)&ww_old_s[i*4] = *(const float4*)&ws[OFF_WW + b*256 + i*4]; }
    else if (tid < 384)  { const int i = tid-320; *(float4*)&u_s[i*4]      = *(const float4*)&ws[OFF_USAGE + b*256 + i*4]; }
    else if (tid < 448)  { const int i = tid-384; *(float4*)&prec_s[i*4]   = *(const float4*)&precOld[i*4]; }
    else                 { const int i = tid-448; *(float4*)&mnorm_s[i*4]  = *(const float4*)&ws[OFF_MNORM + b*256 + i*4]; }
    if (tid < IFACE) {
        float zv = b_if[tid];
        #pragma unroll
        for (int p = 0; p < 16; ++p)
            zv += ws[OFF_ZP + ((size_t)p*32 + b) * 480 + tid];
        z_s[tid] = zv;
    }
    // zero bw accumulators
    bw_s[tid] = 0.0f; bw_s[512 + tid] = 0.0f;
    __syncthreads();

    // ---- parse ----
    if (tid < IFACE) {
        const float v = z_s[tid];
        if (tid < 256)       keysp[(tid >> 6)*64 + (tid & 63)] = v;
        else if (tid < 260)  rstr_s[tid - 256] = 1.0f + softpl(v);
        else if (tid < 324)  wkey_s[tid - 260] = v;
        else if (tid == 324) sc_s[0] = 1.0f + softpl(v);
        else if (tid < 389)  erase_s[tid - 325] = sigm(v);
        else if (tid < 453)  wvec_s[tid - 389] = v;
        else if (tid < 457)  free_s[tid - 453] = sigm(v);
        else if (tid == 457) sc_s[1] = sigm(v);
        else if (tid == 458) sc_s[2] = sigm(v);
    }
    __syncthreads();
    // ---- key norms + modes ----
    if (tid < 320) {
        const int w5 = tid >> 6, lane = tid & 63;
        const float v = (w5 == 0) ? wkey_s[lane] : keysp[(w5 - 1)*64 + lane];
        float s = v * v;
        #pragma unroll
        for (int m = 1; m <= 32; m <<= 1) s += __shfl_xor(s, m);
        if (lane == 0) knorm_s[w5] = fmaxf(sqrtf(s), EPSI);
    } else if (tid >= 508) {
        const int r = tid - 508;
        const float m0 = z_s[459 + r*3], m1 = z_s[460 + r*3], m2 = z_s[461 + r*3];
        const float mx = fmaxf(m0, fmaxf(m1, m2));
        const float e0 = expf(m0 - mx), e1 = expf(m1 - mx), e2 = expf(m2 - mx);
        const float s = e0 + e1 + e2;
        modesp[r*3+0] = e0 / s; modesp[r*3+1] = e1 / s; modesp[r*3+2] = e2 / s;
    }
    // ---- usage update ----
    if (tid < 256) {
        float ret = 1.0f;
        #pragma unroll
        for (int r = 0; r < 4; ++r) ret *= 1.0f - free_s[r] * rwf_s[r*256 + tid];
        const float un = (u_s[tid] + ww_old_s[tid] - u_s[tid] * ww_old_s[tid]) * ret;
        u_s[tid] = un;
        ws[OFF_USAGE + b * 256 + tid] = un;
    }
    __syncthreads();

    // ---- allocation (stable lexicographic product) ----
    {
        const int q = tid >> 8, n = tid & 255;
        const float un = u_s[n];
        float p = 1.0f;
        #pragma unroll 8
        for (int m = q * 128; m < q * 128 + 128; ++m) {
            const float um = u_s[m];
            const bool lt = (um < un) || (um == un && m < n);
            p *= lt ? um : 1.0f;
        }
        Pt_s[q * 256 + n] = p;
    }
    __syncthreads();
    if (tid < 256)
        alloc_s[tid] = (1.0f - u_s[tid]) * Pt_s[tid] * Pt_s[256 + tid];
    __syncthreads();

    // ---- cw content sim (M_old; norms precomputed) ----
    {
        const int n = tid >> 1, q2 = tid & 1;
        const float* mp = wsM + n * 64 + q2 * 32;
        float s = 0.0f;
        #pragma unroll
        for (int it = 0; it < 8; ++it) {
            float4 mv = *(const float4*)(mp + it * 4);
            float4 kv = *(const float4*)&wkey_s[q2 * 32 + it * 4];
            s += mv.x*kv.x + mv.y*kv.y + mv.z*kv.z + mv.w*kv.w;
        }
        s += __shfl_xor(s, 1);
        if (q2 == 0) cw_s[n] = sc_s[0] * s / (knorm_s[0] * mnorm_s[n]);
    }
    __syncthreads();
    // ---- cw softmax ----
    {
        float v = 0.0f, e = 0.0f;
        if (tid < 256) {
            v = cw_s[tid];
            float m = v;
            #pragma unroll
            for (int mm = 1; mm <= 32; mm <<= 1) m = fmaxf(m, __shfl_xor(m, mm));
            if ((tid & 63) == 0) sredA_s[tid >> 6] = m;
        }
        __syncthreads();
        if (tid == 0) sc_s[4] = fmaxf(fmaxf(sredA_s[0], sredA_s[1]), fmaxf(sredA_s[2], sredA_s[3]));
        __syncthreads();
        if (tid < 256) {
            e = expf(v - sc_s[4]);
            float s2 = e;
            #pragma unroll
            for (int mm = 1; mm <= 32; mm <<= 1) s2 += __shfl_xor(s2, mm);
            if ((tid & 63) == 0) sredA_s[tid >> 6] = s2;
        }
        __syncthreads();
        if (tid == 0) sc_s[5] = sredA_s[0] + sredA_s[1] + sredA_s[2] + sredA_s[3];
        __syncthreads();
        if (tid < 256) cw_s[tid] = e / sc_s[5];
    }
    __syncthreads();

    // ---- ww, sum(ww), prec_new ----
    if (tid < 256) {
        const float wwn = sc_s[2] * (sc_s[1] * alloc_s[tid] + (1.0f - sc_s[1]) * cw_s[tid]);
        ww_s[tid] = wwn;
        ws[OFF_WW + b * 256 + tid] = wwn;
    }
    __syncthreads();
    if (tid < 256) {
        float s = ww_s[tid];
        #pragma unroll
        for (int mm = 1; mm <= 32; mm <<= 1) s += __shfl_xor(s, mm);
        if ((tid & 63) == 0) sredA_s[tid >> 6] = s;
    }
    __syncthreads();
    if (tid == 0) sc_s[3] = sredA_s[0] + sredA_s[1] + sredA_s[2] + sredA_s[3];
    __syncthreads();
    if (tid < 256)
        precNew[tid] = (1.0f - sc_s[3]) * prec_s[tid] + ww_s[tid];
    __syncthreads();

    // ================== link: 8 chunks of 32 rows ==================
    for (int c = 0; c < 8; ++c) {
        // ---- M update + norms + cr logits for rows [32c, 32c+32) ----
        {
            const int ric = tid >> 4, c4 = (tid & 15) * 4;
            const int gi  = c * 32 + ric;
            float* mp = wsM + gi * 64 + c4;
            float4 m = *(const float4*)mp;
            const float wwi = ww_s[gi];
            float4 er = *(const float4*)&erase_s[c4];
            float4 wv = *(const float4*)&wvec_s[c4];
            m.x = m.x * (1.0f - wwi * er.x) + wwi * wv.x;
            m.y = m.y * (1.0f - wwi * er.y) + wwi * wv.y;
            m.z = m.z * (1.0f - wwi * er.z) + wwi * wv.z;
            m.w = m.w * (1.0f - wwi * er.w) + wwi * wv.w;
            *(float4*)mp = m;
            float sn = m.x*m.x + m.y*m.y + m.z*m.z + m.w*m.w;
            float d0 = m.x*keysp[c4]     + m.y*keysp[c4+1]     + m.z*keysp[c4+2]     + m.w*keysp[c4+3];
            float d1 = m.x*keysp[64+c4]  + m.y*keysp[64+c4+1]  + m.z*keysp[64+c4+2]  + m.w*keysp[64+c4+3];
            float d2 = m.x*keysp[128+c4] + m.y*keysp[128+c4+1] + m.z*keysp[128+c4+2] + m.w*keysp[128+c4+3];
            float d3 = m.x*keysp[192+c4] + m.y*keysp[192+c4+1] + m.z*keysp[192+c4+2] + m.w*keysp[192+c4+3];
            #pragma unroll
            for (int mm = 1; mm <= 8; mm <<= 1) {
                sn += __shfl_xor(sn, mm);
                d0 += __shfl_xor(d0, mm); d1 += __shfl_xor(d1, mm);
                d2 += __shfl_xor(d2, mm); d3 += __shfl_xor(d3, mm);
            }
            if ((tid & 15) == 0) {
                const float mn = fmaxf(sqrtf(sn), EPSI);
                ws[OFF_MNORM + b*256 + gi] = mn;
                const float inv = 1.0f / mn;
                crs_s[0*256 + gi] = rstr_s[0] * d0 * inv / knorm_s[1];
                crs_s[1*256 + gi] = rstr_s[1] * d1 * inv / knorm_s[2];
                crs_s[2*256 + gi] = rstr_s[2] * d2 * inv / knorm_s[3];
                crs_s[3*256 + gi] = rstr_s[3] * d3 * inv / knorm_s[4];
            }
        }

        // ---- link rows update (phase A) ----
        {
            const int j = tid & 255, p = tid >> 8;
            const float wwj = ww_s[j], pj = prec_s[j];
            #pragma unroll 4
            for (int it = 0; it < 16; ++it) {
                const int ric = it * 2 + p;
                const int gi  = c * 32 + ric;
                float* lp = ws + OFF_LINK + (size_t)b * (TN*TN) + (size_t)gi * 256 + j;
                const float wwi = ww_s[gi];
                float v = (1.0f - wwi - wwj) * (*lp) + wwi * pj;
                if (j == gi) v = 0.0f;
                *lp = v;
                Lt[ric * 257 + j] = v;
            }
        }
        __syncthreads();

        // ---- fw (phase B): fw[r][gi] = sum_j L[gi][j]*rw[r][j] ----
        {
            const int ric = tid >> 4, g = tid & 15;
            const int gi = c * 32 + ric;
            float f0=0, f1=0, f2=0, f3=0;
            #pragma unroll 4
            for (int jj = 0; jj < 16; ++jj) {
                const int j = g * 16 + jj;
                const float v = Lt[ric * 257 + j];
                f0 += v * rwf_s[j]; f1 += v * rwf_s[256+j];
                f2 += v * rwf_s[512+j]; f3 += v * rwf_s[768+j];
            }
            #pragma unroll
            for (int mm = 1; mm <= 8; mm <<= 1) {
                f0 += __shfl_xor(f0, mm); f1 += __shfl_xor(f1, mm);
                f2 += __shfl_xor(f2, mm); f3 += __shfl_xor(f3, mm);
            }
            if (g == 0) {
                fw_s[0*256 + gi] = f0;
                fw_s[1*256 + gi] = f1;
                fw_s[2*256 + gi] = f2;
                fw_s[3*256 + gi] = f3;
            }
        }

        // ---- bw partials (phase C): bw[r][j] += sum_{i in chunk} L[i][j]*rw[r][i] ----
        {
            const int j = tid & 255, p = tid >> 8;
            float b0=0, b1=0, b2=0, b3=0;
            #pragma unroll 4
            for (int it = 0; it < 16; ++it) {
                const int ric = p * 16 + it;
                const int gi  = c * 32 + ric;
                const float v = Lt[ric * 257 + j];
                b0 += v * rwf_s[gi]; b1 += v * rwf_s[256+gi];
                b2 += v * rwf_s[512+gi]; b3 += v * rwf_s[768+gi];
            }
            __syncthreads();
            if (p == 1) { Lt[j] = b0; Lt[256+j] = b1; Lt[512+j] = b2; Lt[768+j] = b3; }
            __syncthreads();
            if (p == 0) {
                bw_s[j]       += b0 + Lt[j];
                bw_s[256 + j] += b1 + Lt[256+j];
                bw_s[512 + j] += b2 + Lt[512+j];
                bw_s[768 + j] += b3 + Lt[768+j];
            }
        }
        __syncthreads();   // Lt reused next chunk
    }

    // ================== stepB ==================
    // ---- cr softmax (heads rr, rr+2) on crs_s ----
    {
        const int rr = tid >> 8, n = tid & 255, wv = tid >> 6, lane = tid & 63;
        float v0 = crs_s[rr*256 + n], v1 = crs_s[(rr + 2)*256 + n];
        float m0 = v0, m1 = v1;
        #pragma unroll
        for (int mm = 1; mm <= 32; mm <<= 1) {
            m0 = fmaxf(m0, __shfl_xor(m0, mm));
            m1 = fmaxf(m1, __shfl_xor(m1, mm));
        }
        if (lane == 0) { sredA_s[wv] = m0; sredB_s[wv] = m1; }
        __syncthreads();
        if (tid < 4) {
            const float* base = (tid & 2) ? sredB_s : sredA_s;
            const int off = (tid & 1) * 4;
            gmax_s[tid] = fmaxf(fmaxf(base[off], base[off+1]), fmaxf(base[off+2], base[off+3]));
        }
        __syncthreads();
        const float e0 = expf(v0 - gmax_s[rr]);
        const float e1 = expf(v1 - gmax_s[rr + 2]);
        float s0 = e0, s1 = e1;
        #pragma unroll
        for (int mm = 1; mm <= 32; mm <<= 1) {
            s0 += __shfl_xor(s0, mm); s1 += __shfl_xor(s1, mm);
        }
        if (lane == 0) { sredA_s[wv] = s0; sredB_s[wv] = s1; }
        __syncthreads();
        if (tid < 4) {
            const float* base = (tid & 2) ? sredB_s : sredA_s;
            const int off = (tid & 1) * 4;
            gsum_s[tid] = base[off] + base[off+1] + base[off+2] + base[off+3];
        }
        __syncthreads();
        crs_s[rr*256 + n]       = e0 / gsum_s[rr];
        crs_s[(rr + 2)*256 + n] = e1 / gsum_s[rr + 2];
    }
    __syncthreads();

    // ---- rw update ----
    {
        const int rr = tid >> 8, n = tid & 255;
        #pragma unroll
        for (int p = 0; p < 2; ++p) {
            const int r = rr + 2 * p;
            const float v = modesp[r*3] * bw_s[r*256 + n]
                          + modesp[r*3+1] * crs_s[r*256 + n]
                          + modesp[r*3+2] * fw_s[r*256 + n];
            rw2_s[r*256 + n] = v;
            ws[OFF_RW + b*1024 + r*256 + n] = v;
        }
    }
    __syncthreads();

    // ---- rvec = rw_new @ M_new ----
    {
        const int q2 = tid >> 8, r = (tid >> 6) & 3, w = tid & 63;
        float s = 0.0f;
        #pragma unroll 4
        for (int n = q2 * 128; n < q2 * 128 + 128; ++n)
            s += rw2_s[r*256 + n] * wsM[n * 64 + w];
        Lt[q2 * 256 + r * 64 + w] = s;
    }
    __syncthreads();
    if (tid < 256)
        ws[OFF_RVEC + b * 256 + tid] = Lt[tid] + Lt[256 + tid];
}

extern "C" void kernel_launch(void* const* d_in, const int* in_sizes, int n_in,
                              void* d_out, int out_size, void* d_ws, size_t ws_size,
                              hipStream_t stream) {
    const float* emb    = (const float*)d_in[0];
    const float* Wx     = (const float*)d_in[1];
    const float* Wh     = (const float*)d_in[2];
    const float* b_lstm = (const float*)d_in[3];
    const float* W_pre  = (const float*)d_in[4];
    const float* b_pre  = (const float*)d_in[5];
    const float* W_if   = (const float*)d_in[6];
    const float* b_if   = (const float*)d_in[7];
    const float* W_rout = (const float*)d_in[8];
    float* out = (float*)d_out;
    float* ws  = (float*)d_ws;

    k_init<<<(TOTAL_STATE + 255) / 256, 256, 0, stream>>>(ws);
    for (int t = 0; t < TT; ++t) {
        k_front<<<256, 512, 0, stream>>>(emb, Wx, Wh, b_lstm, W_pre, b_pre, W_rout, ws, out, t);
        k_zp<<<128, 512, 0, stream>>>(W_if, ws, t);
        k_batch<<<32, 512, 0, stream>>>(b_if, ws, t);
    }
    // final out(127): gates half idles (t==TT), out half writes row 127
    k_front<<<256, 512, 0, stream>>>(emb, Wx, Wh, b_lstm, W_pre, b_pre, W_rout, ws, out, TT);
}

// Round 5
// 7467.102 us; speedup vs baseline: 3.2025x; 1.7231x over previous
//
#include <hip/hip_runtime.h>
#include <math.h>

// ---------------- problem constants ----------------
#define TN   256
#define TWM  64
#define TR   4
#define TH   512
#define TD   512
#define TT   128
#define TB   32
#define IFACE 471
#define EPSI 1e-6f

// ---------------- workspace layout (floats) ----------------
#define OFF_H      0          // 2 x 32*512 ping-pong
#define OFF_C      32768
#define OFF_M      49152      // 32*256*64
#define OFF_USAGE  573440
#define OFF_RW     581632     // 32*4*256
#define OFF_WW     614400
#define OFF_PRECA  622592     // prec ping/pong (2 x 8192)
#define OFF_LINK   638976     // 32*256*256
#define OFF_RVEC   2736128
#define OFF_MNORM  2744320    // 32*256
#define OFF_ZP     2752512    // 16 x 32 x 480 z partials
#define OFF_PARSE  2998272    // 32 x 448 parsed interface
#define OFF_CRS    3012608    // 32 x 4 x 256 cr logits
#define OFF_FW     3045376    // 32 x 4 x 256
#define OFF_BWP    3078144    // 256 x 4 x 256 bw chunk partials
#define OFF_CNT    3340288    // 40 counters x 16 floats (8 zp groups, 32 batches)
#define TOTAL_STATE 3340928

__device__ __forceinline__ float sigm(float x)  { return 1.0f / (1.0f + expf(-x)); }
__device__ __forceinline__ float softpl(float x){ return x > 20.0f ? x : log1pf(expf(x)); }

// ---- device-coherent (MALL) access, used ONLY for same-dispatch handoffs ----
__device__ __forceinline__ float ldc(const float* p) {
    return __hip_atomic_load(p, __ATOMIC_RELAXED, __HIP_MEMORY_SCOPE_AGENT);
}
__device__ __forceinline__ void stc(float* p, float v) {
    __hip_atomic_store(p, v, __ATOMIC_RELAXED, __HIP_MEMORY_SCOPE_AGENT);
}
__device__ __forceinline__ void stcv4(float* p, float4 v) {
    stc(p, v.x); stc(p + 1, v.y); stc(p + 2, v.z); stc(p + 3, v.w);
}

// ---------------- init ----------------
__global__ void k_init(float* ws) {
    int idx = blockIdx.x * 256 + threadIdx.x;
    if (idx >= TOTAL_STATE) return;
    float v = 0.0f;
    if (idx >= OFF_M && idx < OFF_M + TB*TN*TWM) v = EPSI;
    if (idx >= OFF_MNORM && idx < OFF_MNORM + TB*TN) v = 8e-6f;
    ws[idx] = v;
}

// ---------------- out(t-1) GEMM device fn (round-0 job2, verbatim) ----------------
__device__ __forceinline__ void out_phase(
    const float* __restrict__ W_pre, const float* __restrict__ b_pre,
    const float* __restrict__ W_rout, const float* __restrict__ ws,
    float* __restrict__ out, float* sm, const int tid, const int B2, const int t)
{
    float* act_s = sm;          // 4 batches x 768
    float* red_s = sm + 3072;   // 16 ksub x 4 b x 32 col
    const int q = B2 >> 5, s = (B2 >> 3) & 3, bg = B2 & 7, b0 = bg * 4;
    for (int i = tid; i < 768; i += 512) {
        const int bb = i / 192;
        const int k0 = (i - bb*192) * 4;
        const float* src = (k0 < 512) ? &ws[OFF_H + (t&1)*(TB*TH) + (b0+bb)*TH + k0]
                                      : &ws[OFF_RVEC + (b0+bb)*256 + (k0 - 512)];
        *(float4*)&act_s[bb*768 + k0] = *(const float4*)src;
    }
    __syncthreads();
    const int c0 = q*128 + s*32;
    const int col = tid & 31;
    const int ksb = tid >> 5;
    float a0=0, a1=0, a2=0, a3=0;
    for (int kk = ksb*48; kk < ksb*48 + 48; ++kk) {
        const float w = (kk < 512) ? W_pre[(size_t)kk * 512 + c0 + col]
                                   : W_rout[(size_t)(kk - 512) * 512 + c0 + col];
        a0 += act_s[kk]        * w;
        a1 += act_s[768 + kk]  * w;
        a2 += act_s[1536 + kk] * w;
        a3 += act_s[2304 + kk] * w;
    }
    red_s[(ksb*4 + 0)*32 + col] = a0;
    red_s[(ksb*4 + 1)*32 + col] = a1;
    red_s[(ksb*4 + 2)*32 + col] = a2;
    red_s[(ksb*4 + 3)*32 + col] = a3;
    __syncthreads();
    if (tid < 128) {
        const int cc = tid & 31, bb = tid >> 5;
        float ssum = 0.0f;
        #pragma unroll
        for (int ks2 = 0; ks2 < 16; ++ks2) ssum += red_s[(ks2*4 + bb)*32 + cc];
        ssum += b_pre[c0 + cc];
        out[(size_t)(t - 1) * (TB * TD) + (b0+bb) * TD + c0 + cc] = ssum;
    }
}

// ---------------- slot 1: gates (blk 0..127) || out(t-1) (blk 128..255) ----------------
__global__ __launch_bounds__(512) void k_front(
    const float* __restrict__ emb, const float* __restrict__ Wx,
    const float* __restrict__ Wh,  const float* __restrict__ b_lstm,
    const float* __restrict__ W_pre, const float* __restrict__ b_pre,
    const float* __restrict__ W_rout,
    float* __restrict__ ws, float* __restrict__ out, int t)
{
    __shared__ __align__(16) float smem[16384];
    const int tid = threadIdx.x;
    if (blockIdx.x >= 128) {
        if (t == 0) return;
        // swizzle so the 8 bg-jobs sharing one (q,s) weight panel land on one XCD
        const int raw2 = blockIdx.x - 128;
        const int B2 = (((raw2 >> 2) & 3) << 5) | ((raw2 & 3) << 3) | (raw2 >> 4);
        out_phase(W_pre, b_pre, W_rout, ws, out, smem, tid, B2, t);
        return;
    }
    if (t >= TT) return;

    // swizzle: 4 col-group-neighbors (one 64B weight line) share an XCD
    const int ublk = ((blockIdx.x & 7) << 4) | (blockIdx.x >> 3);
    const int u0  = ublk * 4;
    const int cg  = tid & 3;
    const int bg  = (tid >> 2) & 7;
    const int ks  = tid >> 5;
    const int col0 = cg * 512 + u0;
    const float* hbuf = ws + OFF_H + (t & 1) * (TB * TH);

    float acc[4][4] = {};

    for (int tile = 0; tile < 5; ++tile) {
        const int T0 = tile * 256;
        {
            const int b = tid & 31, kf4 = tid >> 5;
            #pragma unroll
            for (int i = 0; i < 4; ++i) {
                const int kf = kf4 * 4 + i;
                const int kl = kf * 4;
                const int k  = T0 + kl;
                const float* src;
                if (k < 512)      src = emb + (size_t)t * (TB*TD) + b * TD + k;
                else if (k < 768) src = ws + OFF_RVEC + b * 256 + (k - 512);
                else              src = hbuf + b * TH + (k - 768);
                float4 v = *(const float4*)src;
                smem[(kl+0)*32 + b] = v.x;
                smem[(kl+1)*32 + b] = v.y;
                smem[(kl+2)*32 + b] = v.z;
                smem[(kl+3)*32 + b] = v.w;
            }
        }
        __syncthreads();
        {
            const int k0 = T0 + ks * 16;
            const float* wp = (k0 < 768 ? Wx + (size_t)k0 * 2048
                                        : Wh + (size_t)(k0 - 768) * 2048) + col0;
            const float* ap = &smem[(ks * 16) * 32 + bg * 4];
            #pragma unroll 8
            for (int kk = 0; kk < 16; ++kk) {
                float4 wv = *(const float4*)wp; wp += 2048;
                float4 av = *(const float4*)ap; ap += 32;
                acc[0][0] += wv.x*av.x; acc[0][1] += wv.x*av.y; acc[0][2] += wv.x*av.z; acc[0][3] += wv.x*av.w;
                acc[1][0] += wv.y*av.x; acc[1][1] += wv.y*av.y; acc[1][2] += wv.y*av.z; acc[1][3] += wv.y*av.w;
                acc[2][0] += wv.z*av.x; acc[2][1] += wv.z*av.y; acc[2][2] += wv.z*av.z; acc[2][3] += wv.z*av.w;
                acc[3][0] += wv.w*av.x; acc[3][1] += wv.w*av.y; acc[3][2] += wv.w*av.z; acc[3][3] += wv.w*av.w;
            }
        }
        __syncthreads();
    }

    {
        const int rbase = 8192 + ks * 512 + (cg * 8 + bg) * 16;
        *(float4*)&smem[rbase + 0]  = make_float4(acc[0][0], acc[0][1], acc[0][2], acc[0][3]);
        *(float4*)&smem[rbase + 4]  = make_float4(acc[1][0], acc[1][1], acc[1][2], acc[1][3]);
        *(float4*)&smem[rbase + 8]  = make_float4(acc[2][0], acc[2][1], acc[2][2], acc[2][3]);
        *(float4*)&smem[rbase + 12] = make_float4(acc[3][0], acc[3][1], acc[3][2], acc[3][3]);
    }
    __syncthreads();
    {
        const int o = tid;
        float s = 0.0f;
        #pragma unroll
        for (int kq = 0; kq < 16; ++kq) s += smem[8192 + kq * 512 + o];
        const int ocg = o >> 7, obg = (o >> 4) & 7, odu = (o >> 2) & 3, obb = o & 3;
        s += b_lstm[ocg * 512 + u0 + odu];
        smem[(ocg * 4 + odu) * 32 + (obg * 4 + obb)] = s;
    }
    __syncthreads();
    if (tid < 128) {
        const int du = tid >> 5, b = tid & 31;
        const float ig = smem[(0  + du) * 32 + b];
        const float fg = smem[(4  + du) * 32 + b];
        const float gg = smem[(8  + du) * 32 + b];
        const float og = smem[(12 + du) * 32 + b];
        const int ci = b * TH + u0 + du;
        const float cold = ws[OFF_C + ci];
        const float cn = sigm(fg) * cold + sigm(ig) * tanhf(gg);
        const float hn = sigm(og) * tanhf(cn);
        ws[OFF_C + ci] = cn;
        ws[OFF_H + ((t + 1) & 1) * (TB * TH) + ci] = hn;
    }
}

// ---------------- stepA device fn (round-0 body; ZP via ldc, rest plain) ----------------
__device__ void stepA_fn(const float* __restrict__ b_if, float* __restrict__ ws,
                         const int t, const int b, const int tid, float* sm)
{
    float* z_s      = sm + 0;
    float* rwf_s    = sm + 480;
    float* ww_old_s = sm + 1504;
    float* ww_s     = sm + 1760;
    float* u_s      = sm + 2016;
    float* prec_s   = sm + 2272;
    float* mnorm_s  = sm + 2528;
    float* alloc_s  = sm + 2784;
    float* cw_s     = sm + 3040;
    float* keysp    = sm + 3296;
    float* wkey_s   = sm + 3552;
    float* erase_s  = sm + 3616;
    float* wvec_s   = sm + 3680;
    float* rstr_s   = sm + 3744;
    float* free_s   = sm + 3748;
    float* modesp   = sm + 3752;
    float* knorm_s  = sm + 3764;
    float* sredA_s  = sm + 3772;
    float* sc_s     = sm + 3780;
    float* Pt_s     = sm + 3788;   // 512 -> ends 4300

    const float* wsM = ws + OFF_M + b * (TN * TWM);
    const float* precOld = ws + OFF_PRECA + (t & 1) * (TB * TN) + b * 256;
    float* precNew = ws + OFF_PRECA + ((t + 1) & 1) * (TB * TN) + b * 256;

    // ---- stage (plain: all prev-dispatch data) + z reduce (ZP via ldc) ----
    if (tid < 256)       { *(float4*)&rwf_s[tid*4] = *(const float4*)&ws[OFF_RW + b*1024 + tid*4]; }
    else if (tid < 320)  { const int i = tid-256; *(float4*)&ww_old_s[i*4] = *(const float4*)&ws[OFF_WW + b*256 + i*4]; }
    else if (tid < 384)  { const int i = tid-320; *(float4*)&u_s[i*4]      = *(const float4*)&ws[OFF_USAGE + b*256 + i*4]; }
    else if (tid < 448)  { const int i = tid-384; *(float4*)&prec_s[i*4]   = *(const float4*)&precOld[i*4]; }
    else                 { const int i = tid-448; *(float4*)&mnorm_s[i*4]  = *(const float4*)&ws[OFF_MNORM + b*256 + i*4]; }
    if (tid < IFACE) {
        float part[16];
        #pragma unroll
        for (int p = 0; p < 16; ++p)
            part[p] = ldc(&ws[OFF_ZP + ((size_t)p*32 + b) * 480 + tid]);
        float zv = b_if[tid];
        #pragma unroll
        for (int p = 0; p < 16; ++p) zv += part[p];
        z_s[tid] = zv;
    }
    __syncthreads();

    // ---- parse ----
    if (tid < IFACE) {
        const float v = z_s[tid];
        if (tid < 256)       keysp[(tid >> 6)*64 + (tid & 63)] = v;
        else if (tid < 260)  rstr_s[tid - 256] = 1.0f + softpl(v);
        else if (tid < 324)  wkey_s[tid - 260] = v;
        else if (tid == 324) sc_s[0] = 1.0f + softpl(v);
        else if (tid < 389)  erase_s[tid - 325] = sigm(v);
        else if (tid < 453)  wvec_s[tid - 389] = v;
        else if (tid < 457)  free_s[tid - 453] = sigm(v);
        else if (tid == 457) sc_s[1] = sigm(v);
        else if (tid == 458) sc_s[2] = sigm(v);
    }
    __syncthreads();
    // ---- key norms + modes ----
    if (tid < 320) {
        const int w5 = tid >> 6, lane = tid & 63;
        const float v = (w5 == 0) ? wkey_s[lane] : keysp[(w5 - 1)*64 + lane];
        float s = v * v;
        #pragma unroll
        for (int m = 1; m <= 32; m <<= 1) s += __shfl_xor(s, m);
        if (lane == 0) knorm_s[w5] = fmaxf(sqrtf(s), EPSI);
    } else if (tid >= 508) {
        const int r = tid - 508;
        const float m0 = z_s[459 + r*3], m1 = z_s[460 + r*3], m2 = z_s[461 + r*3];
        const float mx = fmaxf(m0, fmaxf(m1, m2));
        const float e0 = expf(m0 - mx), e1 = expf(m1 - mx), e2 = expf(m2 - mx);
        const float s = e0 + e1 + e2;
        modesp[r*3+0] = e0 / s; modesp[r*3+1] = e1 / s; modesp[r*3+2] = e2 / s;
    }
    __syncthreads();

    // ---- PARSE writeout (plain: consumed next dispatch) + usage ----
    if (tid < 404) {
        float v;
        if (tid < 256)       v = keysp[tid];
        else if (tid < 320)  v = erase_s[tid - 256];
        else if (tid < 384)  v = wvec_s[tid - 320];
        else if (tid < 388)  v = rstr_s[tid - 384];
        else if (tid < 392)  v = knorm_s[tid - 388 + 1];
        else                 v = modesp[tid - 392];
        ws[OFF_PARSE + b * 448 + tid] = v;
    }
    if (tid < 256) {
        float ret = 1.0f;
        #pragma unroll
        for (int r = 0; r < 4; ++r) ret *= 1.0f - free_s[r] * rwf_s[r*256 + tid];
        const float un = (u_s[tid] + ww_old_s[tid] - u_s[tid] * ww_old_s[tid]) * ret;
        u_s[tid] = un;
        ws[OFF_USAGE + b * 256 + tid] = un;
    }
    __syncthreads();

    // ---- allocation ----
    {
        const int q = tid >> 8, n = tid & 255;
        const float un = u_s[n];
        float p = 1.0f;
        #pragma unroll 8
        for (int m = q * 128; m < q * 128 + 128; ++m) {
            const float um = u_s[m];
            const bool lt = (um < un) || (um == un && m < n);
            p *= lt ? um : 1.0f;
        }
        Pt_s[q * 256 + n] = p;
    }
    __syncthreads();
    if (tid < 256)
        alloc_s[tid] = (1.0f - u_s[tid]) * Pt_s[tid] * Pt_s[256 + tid];
    __syncthreads();

    // ---- cw content sim (M_old plain: written prev dispatch) ----
    {
        const int n = tid >> 1, q2 = tid & 1;
        const float* mp = wsM + n * 64 + q2 * 32;
        float s = 0.0f;
        #pragma unroll
        for (int it = 0; it < 8; ++it) {
            float4 mv = *(const float4*)(mp + it * 4);
            float4 kv = *(const float4*)&wkey_s[q2 * 32 + it * 4];
            s += mv.x*kv.x + mv.y*kv.y + mv.z*kv.z + mv.w*kv.w;
        }
        s += __shfl_xor(s, 1);
        if (q2 == 0) cw_s[n] = sc_s[0] * s / (knorm_s[0] * mnorm_s[n]);
    }
    __syncthreads();
    // ---- cw softmax ----
    {
        float v = 0.0f, e = 0.0f;
        if (tid < 256) {
            v = cw_s[tid];
            float m = v;
            #pragma unroll
            for (int mm = 1; mm <= 32; mm <<= 1) m = fmaxf(m, __shfl_xor(m, mm));
            if ((tid & 63) == 0) sredA_s[tid >> 6] = m;
        }
        __syncthreads();
        if (tid == 0) sc_s[4] = fmaxf(fmaxf(sredA_s[0], sredA_s[1]), fmaxf(sredA_s[2], sredA_s[3]));
        __syncthreads();
        if (tid < 256) {
            e = expf(v - sc_s[4]);
            float s2 = e;
            #pragma unroll
            for (int mm = 1; mm <= 32; mm <<= 1) s2 += __shfl_xor(s2, mm);
            if ((tid & 63) == 0) sredA_s[tid >> 6] = s2;
        }
        __syncthreads();
        if (tid == 0) sc_s[5] = sredA_s[0] + sredA_s[1] + sredA_s[2] + sredA_s[3];
        __syncthreads();
        if (tid < 256) cw_s[tid] = e / sc_s[5];
    }
    __syncthreads();

    // ---- ww, sum(ww), prec_new ----
    if (tid < 256) {
        const float wwn = sc_s[2] * (sc_s[1] * alloc_s[tid] + (1.0f - sc_s[1]) * cw_s[tid]);
        ww_s[tid] = wwn;
        ws[OFF_WW + b * 256 + tid] = wwn;
    }
    __syncthreads();
    if (tid < 256) {
        float s = ww_s[tid];
        #pragma unroll
        for (int mm = 1; mm <= 32; mm <<= 1) s += __shfl_xor(s, mm);
        if ((tid & 63) == 0) sredA_s[tid >> 6] = s;
    }
    __syncthreads();
    if (tid == 0) sc_s[3] = sredA_s[0] + sredA_s[1] + sredA_s[2] + sredA_s[3];
    __syncthreads();
    if (tid < 256)
        precNew[tid] = (1.0f - sc_s[3]) * prec_s[tid] + ww_s[tid];
}

// ---------------- slot 2: z partials + stepA tails (128 blocks) ----------------
__global__ __launch_bounds__(512) void k_zpA(
    const float* __restrict__ W_if, const float* __restrict__ b_if,
    float* __restrict__ ws, int t)
{
    __shared__ __align__(16) float h1_s[128];
    __shared__ __align__(16) float smA[4304];
    __shared__ int myBatch;
    const int tid = threadIdx.x;
    const int raw = blockIdx.x;
    const int bgz = raw >> 4;                 // batch group 0..7
    const int q = (raw >> 2) & 3, s = raw & 3;  // same-(q,s) jobs share an XCD
    const int b0 = bgz * 4;

    if (tid < 128) {
        const int bb = tid >> 5, kk = tid & 31;
        h1_s[bb*32 + kk] = ws[OFF_H + ((t+1)&1)*(TB*TH) + (b0+bb)*TH + q*128 + s*32 + kk];
    }
    __syncthreads();
    if (tid < IFACE) {
        const int col = tid;
        float a0=0, a1=0, a2=0, a3=0;
        const float* wb = W_if + (size_t)(q*128 + s*32) * IFACE + col;
        #pragma unroll 8
        for (int kk = 0; kk < 32; ++kk) {
            const float w = *wb; wb += IFACE;
            a0 += h1_s[kk]      * w;
            a1 += h1_s[32+kk]   * w;
            a2 += h1_s[64+kk]   * w;
            a3 += h1_s[96+kk]   * w;
        }
        const size_t base = OFF_ZP + ((size_t)(q*4+s)*32 + b0) * 480 + col;
        stc(&ws[base],        a0);   // same-dispatch consumers -> MALL
        stc(&ws[base + 480],  a1);
        stc(&ws[base + 960],  a2);
        stc(&ws[base + 1440], a3);
    }
    asm volatile("s_waitcnt vmcnt(0)" ::: "memory");  // drain this thread's stc
    __syncthreads();
    if (tid == 0) {
        unsigned* cnt = (unsigned*)(ws + OFF_CNT) + bgz * 16;
        const unsigned old = __hip_atomic_fetch_add(cnt, 1u, __ATOMIC_RELAXED, __HIP_MEMORY_SCOPE_AGENT);
        const unsigned base = 16u * (unsigned)t;
        int mb = -1;
        if (old >= base + 12u) {     // last 4 arrivers become tails, one batch each
            mb = b0 + (int)(old - (base + 12u));
            while (__hip_atomic_load(cnt, __ATOMIC_RELAXED, __HIP_MEMORY_SCOPE_AGENT) < base + 16u)
                __builtin_amdgcn_s_sleep(2);
        }
        myBatch = mb;
    }
    __syncthreads();
    if (myBatch < 0) return;
    stepA_fn(b_if, ws, t, myBatch, tid, smA);
}

// ---------------- stepB device fn (round-3 P5 body; same-dispatch data via ldc) ----------------
__device__ void stepB_fn(float* __restrict__ ws, const int t, const int b,
                         const int tid, float* sm)
{
    float* crp     = sm;          // 4 x 256
    float* rw2_s   = sm + 1024;   // 1024
    float* Lt2     = sm + 2048;   // 2048
    float* md      = sm + 4096;   // 12
    float* sredA_s = sm + 4112;   // 8
    float* sredB_s = sm + 4120;   // 8
    float* gmax_s  = sm + 4128;   // 4
    float* gsum_s  = sm + 4132;   // 4
    const float* wsM = ws + OFF_M + b * (TN * TWM);

    crp[tid]       = ldc(&ws[OFF_CRS + b*1024 + tid]);
    crp[tid + 512] = ldc(&ws[OFF_CRS + b*1024 + tid + 512]);
    if (tid < 12) md[tid] = ws[OFF_PARSE + b*448 + 392 + tid];   // prev dispatch: plain
    __syncthreads();

    // ---- cr softmax ----
    {
        const int rr = tid >> 8, n = tid & 255, wv = tid >> 6, lane = tid & 63;
        float v0 = crp[rr*256 + n], v1 = crp[(rr + 2)*256 + n];
        float m0 = v0, m1 = v1;
        #pragma unroll
        for (int mm = 1; mm <= 32; mm <<= 1) {
            m0 = fmaxf(m0, __shfl_xor(m0, mm));
            m1 = fmaxf(m1, __shfl_xor(m1, mm));
        }
        if (lane == 0) { sredA_s[wv] = m0; sredB_s[wv] = m1; }
        __syncthreads();
        if (tid < 4) {
            const float* base = (tid & 2) ? sredB_s : sredA_s;
            const int off = (tid & 1) * 4;
            gmax_s[tid] = fmaxf(fmaxf(base[off], base[off+1]), fmaxf(base[off+2], base[off+3]));
        }
        __syncthreads();
        const float e0 = expf(v0 - gmax_s[rr]);
        const float e1 = expf(v1 - gmax_s[rr + 2]);
        float s0 = e0, s1 = e1;
        #pragma unroll
        for (int mm = 1; mm <= 32; mm <<= 1) {
            s0 += __shfl_xor(s0, mm); s1 += __shfl_xor(s1, mm);
        }
        if (lane == 0) { sredA_s[wv] = s0; sredB_s[wv] = s1; }
        __syncthreads();
        if (tid < 4) {
            const float* base = (tid & 2) ? sredB_s : sredA_s;
            const int off = (tid & 1) * 4;
            gsum_s[tid] = base[off] + base[off+1] + base[off+2] + base[off+3];
        }
        __syncthreads();
        crp[rr*256 + n]       = e0 / gsum_s[rr];
        crp[(rr + 2)*256 + n] = e1 / gsum_s[rr + 2];
    }
    __syncthreads();

    // ---- bw reduce (BWP/FW via ldc, batched independent loads) + rw update ----
    {
        const int rr = tid >> 8, n = tid & 255;
        #pragma unroll
        for (int p = 0; p < 2; ++p) {
            const int r = rr + 2 * p;
            float part[8];
            #pragma unroll
            for (int c = 0; c < 8; ++c)
                part[c] = ldc(&ws[OFF_BWP + (size_t)(b*8 + c)*1024 + r*256 + n]);
            const float fwv = ldc(&ws[OFF_FW + b*1024 + r*256 + n]);
            float bw = 0.0f;
            #pragma unroll
            for (int c = 0; c < 8; ++c) bw += part[c];
            const float v = md[r*3] * bw + md[r*3+1] * crp[r*256 + n] + md[r*3+2] * fwv;
            rw2_s[r*256 + n] = v;
            ws[OFF_RW + b*1024 + r*256 + n] = v;   // next dispatch: plain
        }
    }
    __syncthreads();

    // ---- rvec = rw_new @ M_new (M via ldc, dedup'd + batched) ----
    {
        const int g8 = tid >> 6, w = tid & 63;
        float p0=0, p1=0, p2=0, p3=0;
        const float* mb = wsM + (size_t)(g8 * 32) * 64 + w;
        for (int gg = 0; gg < 4; ++gg) {
            float mv[8];
            #pragma unroll
            for (int j = 0; j < 8; ++j) mv[j] = ldc(mb + (gg*8 + j) * 64);
            #pragma unroll
            for (int j = 0; j < 8; ++j) {
                const int n = g8*32 + gg*8 + j;
                p0 += rw2_s[n]       * mv[j];
                p1 += rw2_s[256 + n] * mv[j];
                p2 += rw2_s[512 + n] * mv[j];
                p3 += rw2_s[768 + n] * mv[j];
            }
        }
        Lt2[(g8*4 + 0)*64 + w] = p0;
        Lt2[(g8*4 + 1)*64 + w] = p1;
        Lt2[(g8*4 + 2)*64 + w] = p2;
        Lt2[(g8*4 + 3)*64 + w] = p3;
    }
    __syncthreads();
    if (tid < 256) {
        const int r = tid >> 6, w = tid & 63;
        float s = 0.0f;
        #pragma unroll
        for (int g = 0; g < 8; ++g) s += Lt2[(g*4 + r)*64 + w];
        ws[OFF_RVEC + b * 256 + tid] = s;          // next dispatch: plain
    }
}

// ---------------- slot 3: link (256 blocks, round-0) + stepB tail per batch ----------------
__global__ __launch_bounds__(512) void k_linkB(float* __restrict__ ws, int t)
{
    __shared__ __align__(16) float sml[10272];
    __shared__ int isTail;
    float* ww_s   = sml;          // 256
    float* prec_s = sml + 256;    // 256
    float* rw_s   = sml + 512;    // 1024
    float* pk_s   = sml + 1536;   // 448
    float* Lt     = sml + 2048;   // 32*257 = 8224

    const int bi = blockIdx.x;
    const int b  = bi >> 3;
    const int c  = bi & 7;        // bi%8==c -> chunk pinned to one XCD
    const int tid = threadIdx.x;
    const float* precOld = ws + OFF_PRECA + (t & 1) * (TB * TN) + b * 256;

    if (tid < 64)        { *(float4*)&ww_s[tid*4] = *(const float4*)&ws[OFF_WW + b*256 + tid*4]; }
    else if (tid < 128)  { const int i = tid-64;  *(float4*)&prec_s[i*4] = *(const float4*)&precOld[i*4]; }
    else if (tid < 384)  { const int i = tid-128; *(float4*)&rw_s[i*4]   = *(const float4*)&ws[OFF_RW + b*1024 + i*4]; }
    else if (tid < 496)  { const int i = tid-384; *(float4*)&pk_s[i*4]   = *(const float4*)&ws[OFF_PARSE + b*448 + i*4]; }
    __syncthreads();

    // ---- M update + norms + cr logits (M/CRS via stc: same-dispatch tail reads) ----
    {
        const int ric = tid >> 4, c4 = (tid & 15) * 4;
        const int gi  = c * 32 + ric;
        float* mp = ws + OFF_M + b * (TN*TWM) + gi * 64 + c4;
        float4 m = *(const float4*)mp;   // prev-dispatch value: plain read OK
        const float wwi = ww_s[gi];
        float4 er = *(const float4*)&pk_s[256 + c4];
        float4 wv = *(const float4*)&pk_s[320 + c4];
        m.x = m.x * (1.0f - wwi * er.x) + wwi * wv.x;
        m.y = m.y * (1.0f - wwi * er.y) + wwi * wv.y;
        m.z = m.z * (1.0f - wwi * er.z) + wwi * wv.z;
        m.w = m.w * (1.0f - wwi * er.w) + wwi * wv.w;
        stcv4(mp, m);
        float sn = m.x*m.x + m.y*m.y + m.z*m.z + m.w*m.w;
        float d0 = m.x*pk_s[c4]     + m.y*pk_s[c4+1]     + m.z*pk_s[c4+2]     + m.w*pk_s[c4+3];
        float d1 = m.x*pk_s[64+c4]  + m.y*pk_s[64+c4+1]  + m.z*pk_s[64+c4+2]  + m.w*pk_s[64+c4+3];
        float d2 = m.x*pk_s[128+c4] + m.y*pk_s[128+c4+1] + m.z*pk_s[128+c4+2] + m.w*pk_s[128+c4+3];
        float d3 = m.x*pk_s[192+c4] + m.y*pk_s[192+c4+1] + m.z*pk_s[192+c4+2] + m.w*pk_s[192+c4+3];
        #pragma unroll
        for (int mm = 1; mm <= 8; mm <<= 1) {
            sn += __shfl_xor(sn, mm);
            d0 += __shfl_xor(d0, mm); d1 += __shfl_xor(d1, mm);
            d2 += __shfl_xor(d2, mm); d3 += __shfl_xor(d3, mm);
        }
        if ((tid & 15) == 0) {
            const float mn = fmaxf(sqrtf(sn), EPSI);
            ws[OFF_MNORM + b*256 + gi] = mn;       // next dispatch: plain
            const float inv = 1.0f / mn;
            stc(&ws[OFF_CRS + b*1024 + 0*256 + gi], pk_s[384+0] * d0 * inv / pk_s[388+0]);
            stc(&ws[OFF_CRS + b*1024 + 1*256 + gi], pk_s[384+1] * d1 * inv / pk_s[388+1]);
            stc(&ws[OFF_CRS + b*1024 + 2*256 + gi], pk_s[384+2] * d2 * inv / pk_s[388+2]);
            stc(&ws[OFF_CRS + b*1024 + 3*256 + gi], pk_s[384+3] * d3 * inv / pk_s[388+3]);
        }
    }

    // ---- link rows update (block-local: plain, stays in this XCD's L2) ----
    {
        const int j = tid & 255, p = tid >> 8;
        const float wwj = ww_s[j], pj = prec_s[j];
        #pragma unroll 4
        for (int it = 0; it < 16; ++it) {
            const int ric = it * 2 + p;
            const int gi  = c * 32 + ric;
            float* lp = ws + OFF_LINK + (size_t)b * (TN*TN) + (size_t)gi * 256 + j;
            const float wwi = ww_s[gi];
            float v = (1.0f - wwi - wwj) * (*lp) + wwi * pj;
            if (j == gi) v = 0.0f;
            *lp = v;
            Lt[ric * 257 + j] = v;
        }
    }
    __syncthreads();

    // ---- fw ----
    {
        const int ric = tid >> 4, g = tid & 15;
        const int gi = c * 32 + ric;
        float f0=0, f1=0, f2=0, f3=0;
        #pragma unroll 4
        for (int jj = 0; jj < 16; ++jj) {
            const int j = g * 16 + jj;
            const float v = Lt[ric * 257 + j];
            f0 += v * rw_s[j]; f1 += v * rw_s[256+j];
            f2 += v * rw_s[512+j]; f3 += v * rw_s[768+j];
        }
        #pragma unroll
        for (int mm = 1; mm <= 8; mm <<= 1) {
            f0 += __shfl_xor(f0, mm); f1 += __shfl_xor(f1, mm);
            f2 += __shfl_xor(f2, mm); f3 += __shfl_xor(f3, mm);
        }
        if (g == 0) {
            stc(&ws[OFF_FW + b*1024 + gi],       f0);
            stc(&ws[OFF_FW + b*1024 + 256 + gi], f1);
            stc(&ws[OFF_FW + b*1024 + 512 + gi], f2);
            stc(&ws[OFF_FW + b*1024 + 768 + gi], f3);
        }
    }

    // ---- bw partials ----
    {
        const int j = tid & 255, p = tid >> 8;
        float b0=0, b1=0, b2=0, b3=0;
        #pragma unroll 4
        for (int it = 0; it < 16; ++it) {
            const int ric = p * 16 + it;
            const int gi  = c * 32 + ric;
            const float v = Lt[ric * 257 + j];
            b0 += v * rw_s[gi]; b1 += v * rw_s[256+gi];
            b2 += v * rw_s[512+gi]; b3 += v * rw_s[768+gi];
        }
        __syncthreads();
        if (p == 1) { Lt[j] = b0; Lt[256+j] = b1; Lt[512+j] = b2; Lt[768+j] = b3; }
        __syncthreads();
        if (p == 0) {
            stc(&ws[OFF_BWP + (size_t)bi*1024 + j],       b0 + Lt[j]);
            stc(&ws[OFF_BWP + (size_t)bi*1024 + 256 + j], b1 + Lt[256+j]);
            stc(&ws[OFF_BWP + (size_t)bi*1024 + 512 + j], b2 + Lt[512+j]);
            stc(&ws[OFF_BWP + (size_t)bi*1024 + 768 + j], b3 + Lt[768+j]);
        }
    }

    // ---- tail selection: last of the 8 chunk blocks runs stepB for batch b ----
    asm volatile("s_waitcnt vmcnt(0)" ::: "memory");
    __syncthreads();
    if (tid == 0) {
        unsigned* cnt = (unsigned*)(ws + OFF_CNT) + (8 + b) * 16;
        const unsigned old = __hip_atomic_fetch_add(cnt, 1u, __ATOMIC_RELAXED, __HIP_MEMORY_SCOPE_AGENT);
        isTail = (old == 8u * (unsigned)t + 7u) ? 1 : 0;
    }
    __syncthreads();
    if (!isTail) return;
    stepB_fn(ws, t, b, tid, sml);
}

extern "C" void kernel_launch(void* const* d_in, const int* in_sizes, int n_in,
                              void* d_out, int out_size, void* d_ws, size_t ws_size,
                              hipStream_t stream) {
    const float* emb    = (const float*)d_in[0];
    const float* Wx     = (const float*)d_in[1];
    const float* Wh     = (const float*)d_in[2];
    const float* b_lstm = (const float*)d_in[3];
    const float* W_pre  = (const float*)d_in[4];
    const float* b_pre  = (const float*)d_in[5];
    const float* W_if   = (const float*)d_in[6];
    const float* b_if   = (const float*)d_in[7];
    const float* W_rout = (const float*)d_in[8];
    float* out = (float*)d_out;
    float* ws  = (float*)d_ws;

    k_init<<<(TOTAL_STATE + 255) / 256, 256, 0, stream>>>(ws);
    for (int t = 0; t < TT; ++t) {
        k_front<<<256, 512, 0, stream>>>(emb, Wx, Wh, b_lstm, W_pre, b_pre, W_rout, ws, out, t);
        k_zpA<<<128, 512, 0, stream>>>(W_if, b_if, ws, t);
        k_linkB<<<256, 512, 0, stream>>>(ws, t);
    }
    // final out(127)
    k_front<<<256, 512, 0, stream>>>(emb, Wx, Wh, b_lstm, W_pre, b_pre, W_rout, ws, out, TT);
}

// Round 6
// 7305.396 us; speedup vs baseline: 3.2734x; 1.0221x over previous
//
#include <hip/hip_runtime.h>
#include <math.h>

// ---------------- problem constants ----------------
#define TN   256
#define TWM  64
#define TR   4
#define TH   512
#define TD   512
#define TT   128
#define TB   32
#define IFACE 471
#define EPSI 1e-6f

// ---------------- workspace layout (floats) ----------------
#define OFF_H      0          // 2 x 32*512 ping-pong
#define OFF_C      32768
#define OFF_M      49152      // 32*256*64
#define OFF_USAGE  573440
#define OFF_RW     581632     // 32*4*256
#define OFF_WW     614400
#define OFF_PRECA  622592     // prec ping/pong (2 x 8192)
#define OFF_LINK   638976     // 32*256*256
#define OFF_RVEC   2736128
#define OFF_MNORM  2744320    // 32*256
#define OFF_ZP     2752512    // 16 x 32 x 480 z partials
#define OFF_PARSE  2998272    // 32 x 448 parsed interface
#define OFF_CRS    3012608    // 32 x 4 x 256 cr logits
#define OFF_FW     3045376    // 32 x 4 x 256
#define OFF_BWP    3078144    // 256 x 4 x 256 bw chunk partials
#define OFF_CNT    3340288    // 72 counters x 16 floats
#define TOTAL_STATE 3341440

// counters (each on its own 64B line)
#define CNT_ZPG(g) (OFF_CNT + (g)*16)          // 8 zp group counters
#define CNT_SB(b)  (OFF_CNT + (8+(b))*16)      // 32 stepB tail counters
#define CNT_FA(b)  (OFF_CNT + (40+(b))*16)     // 32 stepA done flags

__device__ __forceinline__ float sigm(float x)  { return 1.0f / (1.0f + expf(-x)); }
__device__ __forceinline__ float softpl(float x){ return x > 20.0f ? x : log1pf(expf(x)); }

// ---- device-coherent (MALL) access, used ONLY for same-dispatch handoffs ----
__device__ __forceinline__ float ldc(const float* p) {
    return __hip_atomic_load(p, __ATOMIC_RELAXED, __HIP_MEMORY_SCOPE_AGENT);
}
__device__ __forceinline__ void stc(float* p, float v) {
    __hip_atomic_store(p, v, __ATOMIC_RELAXED, __HIP_MEMORY_SCOPE_AGENT);
}
__device__ __forceinline__ float4 ldcv4(const float* p) {
    float4 v;
    v.x = ldc(p); v.y = ldc(p + 1); v.z = ldc(p + 2); v.w = ldc(p + 3);
    return v;
}
__device__ __forceinline__ void stcv4(float* p, float4 v) {
    stc(p, v.x); stc(p + 1, v.y); stc(p + 2, v.z); stc(p + 3, v.w);
}

// ---------------- init ----------------
__global__ void k_init(float* ws) {
    int idx = blockIdx.x * 256 + threadIdx.x;
    if (idx >= TOTAL_STATE) return;
    float v = 0.0f;
    if (idx >= OFF_M && idx < OFF_M + TB*TN*TWM) v = EPSI;
    if (idx >= OFF_MNORM && idx < OFF_MNORM + TB*TN) v = 8e-6f;
    ws[idx] = v;
}

// ---------------- out(t-1) GEMM device fn ----------------
__device__ __forceinline__ void out_phase(
    const float* __restrict__ W_pre, const float* __restrict__ b_pre,
    const float* __restrict__ W_rout, const float* __restrict__ ws,
    float* __restrict__ out, float* sm, const int tid, const int B2, const int t)
{
    float* act_s = sm;          // 4 batches x 768
    float* red_s = sm + 3072;   // 16 ksub x 4 b x 32 col
    const int q = B2 >> 5, s = (B2 >> 3) & 3, bg = B2 & 7, b0 = bg * 4;
    for (int i = tid; i < 768; i += 512) {
        const int bb = i / 192;
        const int k0 = (i - bb*192) * 4;
        const float* src = (k0 < 512) ? &ws[OFF_H + (t&1)*(TB*TH) + (b0+bb)*TH + k0]
                                      : &ws[OFF_RVEC + (b0+bb)*256 + (k0 - 512)];
        *(float4*)&act_s[bb*768 + k0] = *(const float4*)src;
    }
    __syncthreads();
    const int c0 = q*128 + s*32;
    const int col = tid & 31;
    const int ksb = tid >> 5;
    float a0=0, a1=0, a2=0, a3=0;
    for (int kk = ksb*48; kk < ksb*48 + 48; ++kk) {
        const float w = (kk < 512) ? W_pre[(size_t)kk * 512 + c0 + col]
                                   : W_rout[(size_t)(kk - 512) * 512 + c0 + col];
        a0 += act_s[kk]        * w;
        a1 += act_s[768 + kk]  * w;
        a2 += act_s[1536 + kk] * w;
        a3 += act_s[2304 + kk] * w;
    }
    red_s[(ksb*4 + 0)*32 + col] = a0;
    red_s[(ksb*4 + 1)*32 + col] = a1;
    red_s[(ksb*4 + 2)*32 + col] = a2;
    red_s[(ksb*4 + 3)*32 + col] = a3;
    __syncthreads();
    if (tid < 128) {
        const int cc = tid & 31, bb = tid >> 5;
        float ssum = 0.0f;
        #pragma unroll
        for (int ks2 = 0; ks2 < 16; ++ks2) ssum += red_s[(ks2*4 + bb)*32 + cc];
        ssum += b_pre[c0 + cc];
        out[(size_t)(t - 1) * (TB * TD) + (b0+bb) * TD + c0 + cc] = ssum;
    }
}

// ---------------- slot 1: gates (blk 0..127) || out(t-1) (blk 128..255) ----------------
__global__ __launch_bounds__(512) void k_front(
    const float* __restrict__ emb, const float* __restrict__ Wx,
    const float* __restrict__ Wh,  const float* __restrict__ b_lstm,
    const float* __restrict__ W_pre, const float* __restrict__ b_pre,
    const float* __restrict__ W_rout,
    float* __restrict__ ws, float* __restrict__ out, int t)
{
    __shared__ __align__(16) float smem[16384];
    const int tid = threadIdx.x;
    if (blockIdx.x >= 128) {
        if (t == 0) return;
        const int raw2 = blockIdx.x - 128;
        const int B2 = (((raw2 >> 2) & 3) << 5) | ((raw2 & 3) << 3) | (raw2 >> 4);
        out_phase(W_pre, b_pre, W_rout, ws, out, smem, tid, B2, t);
        return;
    }
    if (t >= TT) return;

    const int ublk = ((blockIdx.x & 7) << 4) | (blockIdx.x >> 3);
    const int u0  = ublk * 4;
    const int cg  = tid & 3;
    const int bg  = (tid >> 2) & 7;
    const int ks  = tid >> 5;
    const int col0 = cg * 512 + u0;
    const float* hbuf = ws + OFF_H + (t & 1) * (TB * TH);

    float acc[4][4] = {};

    for (int tile = 0; tile < 5; ++tile) {
        const int T0 = tile * 256;
        {
            const int b = tid & 31, kf4 = tid >> 5;
            #pragma unroll
            for (int i = 0; i < 4; ++i) {
                const int kf = kf4 * 4 + i;
                const int kl = kf * 4;
                const int k  = T0 + kl;
                const float* src;
                if (k < 512)      src = emb + (size_t)t * (TB*TD) + b * TD + k;
                else if (k < 768) src = ws + OFF_RVEC + b * 256 + (k - 512);
                else              src = hbuf + b * TH + (k - 768);
                float4 v = *(const float4*)src;
                smem[(kl+0)*32 + b] = v.x;
                smem[(kl+1)*32 + b] = v.y;
                smem[(kl+2)*32 + b] = v.z;
                smem[(kl+3)*32 + b] = v.w;
            }
        }
        __syncthreads();
        {
            const int k0 = T0 + ks * 16;
            const float* wp = (k0 < 768 ? Wx + (size_t)k0 * 2048
                                        : Wh + (size_t)(k0 - 768) * 2048) + col0;
            const float* ap = &smem[(ks * 16) * 32 + bg * 4];
            #pragma unroll 8
            for (int kk = 0; kk < 16; ++kk) {
                float4 wv = *(const float4*)wp; wp += 2048;
                float4 av = *(const float4*)ap; ap += 32;
                acc[0][0] += wv.x*av.x; acc[0][1] += wv.x*av.y; acc[0][2] += wv.x*av.z; acc[0][3] += wv.x*av.w;
                acc[1][0] += wv.y*av.x; acc[1][1] += wv.y*av.y; acc[1][2] += wv.y*av.z; acc[1][3] += wv.y*av.w;
                acc[2][0] += wv.z*av.x; acc[2][1] += wv.z*av.y; acc[2][2] += wv.z*av.z; acc[2][3] += wv.z*av.w;
                acc[3][0] += wv.w*av.x; acc[3][1] += wv.w*av.y; acc[3][2] += wv.w*av.z; acc[3][3] += wv.w*av.w;
            }
        }
        __syncthreads();
    }

    {
        const int rbase = 8192 + ks * 512 + (cg * 8 + bg) * 16;
        *(float4*)&smem[rbase + 0]  = make_float4(acc[0][0], acc[0][1], acc[0][2], acc[0][3]);
        *(float4*)&smem[rbase + 4]  = make_float4(acc[1][0], acc[1][1], acc[1][2], acc[1][3]);
        *(float4*)&smem[rbase + 8]  = make_float4(acc[2][0], acc[2][1], acc[2][2], acc[2][3]);
        *(float4*)&smem[rbase + 12] = make_float4(acc[3][0], acc[3][1], acc[3][2], acc[3][3]);
    }
    __syncthreads();
    {
        const int o = tid;
        float s = 0.0f;
        #pragma unroll
        for (int kq = 0; kq < 16; ++kq) s += smem[8192 + kq * 512 + o];
        const int ocg = o >> 7, obg = (o >> 4) & 7, odu = (o >> 2) & 3, obb = o & 3;
        s += b_lstm[ocg * 512 + u0 + odu];
        smem[(ocg * 4 + odu) * 32 + (obg * 4 + obb)] = s;
    }
    __syncthreads();
    if (tid < 128) {
        const int du = tid >> 5, b = tid & 31;
        const float ig = smem[(0  + du) * 32 + b];
        const float fg = smem[(4  + du) * 32 + b];
        const float gg = smem[(8  + du) * 32 + b];
        const float og = smem[(12 + du) * 32 + b];
        const int ci = b * TH + u0 + du;
        const float cold = ws[OFF_C + ci];
        const float cn = sigm(fg) * cold + sigm(ig) * tanhf(gg);
        const float hn = sigm(og) * tanhf(cn);
        ws[OFF_C + ci] = cn;
        ws[OFF_H + ((t + 1) & 1) * (TB * TH) + ci] = hn;
    }
}

// ---------------- stepA device fn (ZP via ldc; WW/PARSE via stc for same-dispatch link) ----------------
__device__ void stepA_fn(const float* __restrict__ b_if, float* __restrict__ ws,
                         const int t, const int b, const int tid, float* sm)
{
    float* z_s      = sm + 0;
    float* rwf_s    = sm + 480;
    float* ww_old_s = sm + 1504;
    float* ww_s     = sm + 1760;
    float* u_s      = sm + 2016;
    float* prec_s   = sm + 2272;
    float* mnorm_s  = sm + 2528;
    float* alloc_s  = sm + 2784;
    float* cw_s     = sm + 3040;
    float* keysp    = sm + 3296;
    float* wkey_s   = sm + 3552;
    float* erase_s  = sm + 3616;
    float* wvec_s   = sm + 3680;
    float* rstr_s   = sm + 3744;
    float* free_s   = sm + 3748;
    float* modesp   = sm + 3752;
    float* knorm_s  = sm + 3764;
    float* sredA_s  = sm + 3772;
    float* sc_s     = sm + 3780;
    float* Pt_s     = sm + 3788;   // 512 -> ends 4300

    const float* wsM = ws + OFF_M + b * (TN * TWM);
    const float* precOld = ws + OFF_PRECA + (t & 1) * (TB * TN) + b * 256;
    float* precNew = ws + OFF_PRECA + ((t + 1) & 1) * (TB * TN) + b * 256;

    // ---- stage (plain: prev-dispatch data) + z reduce (ZP via ldc) ----
    if (tid < 256)       { *(float4*)&rwf_s[tid*4] = *(const float4*)&ws[OFF_RW + b*1024 + tid*4]; }
    else if (tid < 320)  { const int i = tid-256; *(float4*)&ww_old_s[i*4] = *(const float4*)&ws[OFF_WW + b*256 + i*4]; }
    else if (tid < 384)  { const int i = tid-320; *(float4*)&u_s[i*4]      = *(const float4*)&ws[OFF_USAGE + b*256 + i*4]; }
    else if (tid < 448)  { const int i = tid-384; *(float4*)&prec_s[i*4]   = *(const float4*)&precOld[i*4]; }
    else                 { const int i = tid-448; *(float4*)&mnorm_s[i*4]  = *(const float4*)&ws[OFF_MNORM + b*256 + i*4]; }
    if (tid < IFACE) {
        float part[16];
        #pragma unroll
        for (int p = 0; p < 16; ++p)
            part[p] = ldc(&ws[OFF_ZP + ((size_t)p*32 + b) * 480 + tid]);
        float zv = b_if[tid];
        #pragma unroll
        for (int p = 0; p < 16; ++p) zv += part[p];
        z_s[tid] = zv;
    }
    __syncthreads();

    // ---- parse ----
    if (tid < IFACE) {
        const float v = z_s[tid];
        if (tid < 256)       keysp[(tid >> 6)*64 + (tid & 63)] = v;
        else if (tid < 260)  rstr_s[tid - 256] = 1.0f + softpl(v);
        else if (tid < 324)  wkey_s[tid - 260] = v;
        else if (tid == 324) sc_s[0] = 1.0f + softpl(v);
        else if (tid < 389)  erase_s[tid - 325] = sigm(v);
        else if (tid < 453)  wvec_s[tid - 389] = v;
        else if (tid < 457)  free_s[tid - 453] = sigm(v);
        else if (tid == 457) sc_s[1] = sigm(v);
        else if (tid == 458) sc_s[2] = sigm(v);
    }
    __syncthreads();
    // ---- key norms + modes ----
    if (tid < 320) {
        const int w5 = tid >> 6, lane = tid & 63;
        const float v = (w5 == 0) ? wkey_s[lane] : keysp[(w5 - 1)*64 + lane];
        float s = v * v;
        #pragma unroll
        for (int m = 1; m <= 32; m <<= 1) s += __shfl_xor(s, m);
        if (lane == 0) knorm_s[w5] = fmaxf(sqrtf(s), EPSI);
    } else if (tid >= 508) {
        const int r = tid - 508;
        const float m0 = z_s[459 + r*3], m1 = z_s[460 + r*3], m2 = z_s[461 + r*3];
        const float mx = fmaxf(m0, fmaxf(m1, m2));
        const float e0 = expf(m0 - mx), e1 = expf(m1 - mx), e2 = expf(m2 - mx);
        const float s = e0 + e1 + e2;
        modesp[r*3+0] = e0 / s; modesp[r*3+1] = e1 / s; modesp[r*3+2] = e2 / s;
    }
    __syncthreads();

    // ---- PARSE writeout (stc: same-dispatch link/stepB consumers) + usage ----
    if (tid < 404) {
        float v;
        if (tid < 256)       v = keysp[tid];
        else if (tid < 320)  v = erase_s[tid - 256];
        else if (tid < 384)  v = wvec_s[tid - 320];
        else if (tid < 388)  v = rstr_s[tid - 384];
        else if (tid < 392)  v = knorm_s[tid - 388 + 1];
        else                 v = modesp[tid - 392];
        stc(&ws[OFF_PARSE + b * 448 + tid], v);
    }
    if (tid < 256) {
        float ret = 1.0f;
        #pragma unroll
        for (int r = 0; r < 4; ++r) ret *= 1.0f - free_s[r] * rwf_s[r*256 + tid];
        const float un = (u_s[tid] + ww_old_s[tid] - u_s[tid] * ww_old_s[tid]) * ret;
        u_s[tid] = un;
        ws[OFF_USAGE + b * 256 + tid] = un;   // next dispatch: plain
    }
    __syncthreads();

    // ---- allocation ----
    {
        const int q = tid >> 8, n = tid & 255;
        const float un = u_s[n];
        float p = 1.0f;
        #pragma unroll 8
        for (int m = q * 128; m < q * 128 + 128; ++m) {
            const float um = u_s[m];
            const bool lt = (um < un) || (um == un && m < n);
            p *= lt ? um : 1.0f;
        }
        Pt_s[q * 256 + n] = p;
    }
    __syncthreads();
    if (tid < 256)
        alloc_s[tid] = (1.0f - u_s[tid]) * Pt_s[tid] * Pt_s[256 + tid];
    __syncthreads();

    // ---- cw content sim (M_old plain: written prev dispatch) ----
    {
        const int n = tid >> 1, q2 = tid & 1;
        const float* mp = wsM + n * 64 + q2 * 32;
        float s = 0.0f;
        #pragma unroll
        for (int it = 0; it < 8; ++it) {
            float4 mv = *(const float4*)(mp + it * 4);
            float4 kv = *(const float4*)&wkey_s[q2 * 32 + it * 4];
            s += mv.x*kv.x + mv.y*kv.y + mv.z*kv.z + mv.w*kv.w;
        }
        s += __shfl_xor(s, 1);
        if (q2 == 0) cw_s[n] = sc_s[0] * s / (knorm_s[0] * mnorm_s[n]);
    }
    __syncthreads();
    // ---- cw softmax ----
    {
        float v = 0.0f, e = 0.0f;
        if (tid < 256) {
            v = cw_s[tid];
            float m = v;
            #pragma unroll
            for (int mm = 1; mm <= 32; mm <<= 1) m = fmaxf(m, __shfl_xor(m, mm));
            if ((tid & 63) == 0) sredA_s[tid >> 6] = m;
        }
        __syncthreads();
        if (tid == 0) sc_s[4] = fmaxf(fmaxf(sredA_s[0], sredA_s[1]), fmaxf(sredA_s[2], sredA_s[3]));
        __syncthreads();
        if (tid < 256) {
            e = expf(v - sc_s[4]);
            float s2 = e;
            #pragma unroll
            for (int mm = 1; mm <= 32; mm <<= 1) s2 += __shfl_xor(s2, mm);
            if ((tid & 63) == 0) sredA_s[tid >> 6] = s2;
        }
        __syncthreads();
        if (tid == 0) sc_s[5] = sredA_s[0] + sredA_s[1] + sredA_s[2] + sredA_s[3];
        __syncthreads();
        if (tid < 256) cw_s[tid] = e / sc_s[5];
    }
    __syncthreads();

    // ---- ww (stc: same-dispatch link), sum(ww), prec_new ----
    if (tid < 256) {
        const float wwn = sc_s[2] * (sc_s[1] * alloc_s[tid] + (1.0f - sc_s[1]) * cw_s[tid]);
        ww_s[tid] = wwn;
        stc(&ws[OFF_WW + b * 256 + tid], wwn);
    }
    __syncthreads();
    if (tid < 256) {
        float s = ww_s[tid];
        #pragma unroll
        for (int mm = 1; mm <= 32; mm <<= 1) s += __shfl_xor(s, mm);
        if ((tid & 63) == 0) sredA_s[tid >> 6] = s;
    }
    __syncthreads();
    if (tid == 0) sc_s[3] = sredA_s[0] + sredA_s[1] + sredA_s[2] + sredA_s[3];
    __syncthreads();
    if (tid < 256)
        precNew[tid] = (1.0f - sc_s[3]) * prec_s[tid] + ww_s[tid];  // next dispatch: plain
}

// ---------------- stepB device fn (same-dispatch data via ldc) ----------------
__device__ void stepB_fn(float* __restrict__ ws, const int t, const int b,
                         const int tid, float* sm)
{
    float* crp     = sm;          // 4 x 256
    float* rw2_s   = sm + 1024;   // 1024
    float* Lt2     = sm + 2048;   // 2048
    float* md      = sm + 4096;   // 12
    float* sredA_s = sm + 4112;   // 8
    float* sredB_s = sm + 4120;   // 8
    float* gmax_s  = sm + 4128;   // 4
    float* gsum_s  = sm + 4132;   // 4
    const float* wsM = ws + OFF_M + b * (TN * TWM);

    crp[tid]       = ldc(&ws[OFF_CRS + b*1024 + tid]);
    crp[tid + 512] = ldc(&ws[OFF_CRS + b*1024 + tid + 512]);
    if (tid < 12) md[tid] = ldc(&ws[OFF_PARSE + b*448 + 392 + tid]);  // same-dispatch: ldc
    __syncthreads();

    // ---- cr softmax ----
    {
        const int rr = tid >> 8, n = tid & 255, wv = tid >> 6, lane = tid & 63;
        float v0 = crp[rr*256 + n], v1 = crp[(rr + 2)*256 + n];
        float m0 = v0, m1 = v1;
        #pragma unroll
        for (int mm = 1; mm <= 32; mm <<= 1) {
            m0 = fmaxf(m0, __shfl_xor(m0, mm));
            m1 = fmaxf(m1, __shfl_xor(m1, mm));
        }
        if (lane == 0) { sredA_s[wv] = m0; sredB_s[wv] = m1; }
        __syncthreads();
        if (tid < 4) {
            const float* base = (tid & 2) ? sredB_s : sredA_s;
            const int off = (tid & 1) * 4;
            gmax_s[tid] = fmaxf(fmaxf(base[off], base[off+1]), fmaxf(base[off+2], base[off+3]));
        }
        __syncthreads();
        const float e0 = expf(v0 - gmax_s[rr]);
        const float e1 = expf(v1 - gmax_s[rr + 2]);
        float s0 = e0, s1 = e1;
        #pragma unroll
        for (int mm = 1; mm <= 32; mm <<= 1) {
            s0 += __shfl_xor(s0, mm); s1 += __shfl_xor(s1, mm);
        }
        if (lane == 0) { sredA_s[wv] = s0; sredB_s[wv] = s1; }
        __syncthreads();
        if (tid < 4) {
            const float* base = (tid & 2) ? sredB_s : sredA_s;
            const int off = (tid & 1) * 4;
            gsum_s[tid] = base[off] + base[off+1] + base[off+2] + base[off+3];
        }
        __syncthreads();
        crp[rr*256 + n]       = e0 / gsum_s[rr];
        crp[(rr + 2)*256 + n] = e1 / gsum_s[rr + 2];
    }
    __syncthreads();

    // ---- bw reduce (BWP/FW via ldc) + rw update ----
    {
        const int rr = tid >> 8, n = tid & 255;
        #pragma unroll
        for (int p = 0; p < 2; ++p) {
            const int r = rr + 2 * p;
            float part[8];
            #pragma unroll
            for (int c = 0; c < 8; ++c)
                part[c] = ldc(&ws[OFF_BWP + (size_t)(b*8 + c)*1024 + r*256 + n]);
            const float fwv = ldc(&ws[OFF_FW + b*1024 + r*256 + n]);
            float bw = 0.0f;
            #pragma unroll
            for (int c = 0; c < 8; ++c) bw += part[c];
            const float v = md[r*3] * bw + md[r*3+1] * crp[r*256 + n] + md[r*3+2] * fwv;
            rw2_s[r*256 + n] = v;
            ws[OFF_RW + b*1024 + r*256 + n] = v;   // next dispatch: plain
        }
    }
    __syncthreads();

    // ---- rvec = rw_new @ M_new (M via ldc, dedup'd + batched) ----
    {
        const int g8 = tid >> 6, w = tid & 63;
        float p0=0, p1=0, p2=0, p3=0;
        const float* mb = wsM + (size_t)(g8 * 32) * 64 + w;
        for (int gg = 0; gg < 4; ++gg) {
            float mv[8];
            #pragma unroll
            for (int j = 0; j < 8; ++j) mv[j] = ldc(mb + (gg*8 + j) * 64);
            #pragma unroll
            for (int j = 0; j < 8; ++j) {
                const int n = g8*32 + gg*8 + j;
                p0 += rw2_s[n]       * mv[j];
                p1 += rw2_s[256 + n] * mv[j];
                p2 += rw2_s[512 + n] * mv[j];
                p3 += rw2_s[768 + n] * mv[j];
            }
        }
        Lt2[(g8*4 + 0)*64 + w] = p0;
        Lt2[(g8*4 + 1)*64 + w] = p1;
        Lt2[(g8*4 + 2)*64 + w] = p2;
        Lt2[(g8*4 + 3)*64 + w] = p3;
    }
    __syncthreads();
    if (tid < 256) {
        const int r = tid >> 6, w = tid & 63;
        float s = 0.0f;
        #pragma unroll
        for (int g = 0; g < 8; ++g) s += Lt2[(g*4 + r)*64 + w];
        ws[OFF_RVEC + b * 256 + tid] = s;          // next dispatch: plain
    }
}

// ---------------- slot 2: zp + stepA + link + stepB in ONE dispatch (256 blocks) ----------------
__global__ __launch_bounds__(512) void k_step(
    const float* __restrict__ W_if, const float* __restrict__ b_if,
    float* __restrict__ ws, int t)
{
    __shared__ __align__(16) float sm[10272];   // 41 KB, reused per phase
    __shared__ int myBatch;
    __shared__ int isTail;
    const int tid = threadIdx.x;
    const int blk = blockIdx.x;

    // ===== phase 1: z partials (blocks 0..127) + stepA tails =====
    if (blk < 128) {
        const int bgz = blk >> 4;                  // batch group 0..7
        const int q = (blk >> 2) & 3, s = blk & 3;
        const int b0 = bgz * 4;
        float* h1_s = sm;
        if (tid < 128) {
            const int bb = tid >> 5, kk = tid & 31;
            h1_s[bb*32 + kk] = ws[OFF_H + ((t+1)&1)*(TB*TH) + (b0+bb)*TH + q*128 + s*32 + kk];
        }
        __syncthreads();
        if (tid < IFACE) {
            const int col = tid;
            float a0=0, a1=0, a2=0, a3=0;
            const float* wb = W_if + (size_t)(q*128 + s*32) * IFACE + col;
            #pragma unroll 8
            for (int kk = 0; kk < 32; ++kk) {
                const float w = *wb; wb += IFACE;
                a0 += h1_s[kk]      * w;
                a1 += h1_s[32+kk]   * w;
                a2 += h1_s[64+kk]   * w;
                a3 += h1_s[96+kk]   * w;
            }
            const size_t base = OFF_ZP + ((size_t)(q*4+s)*32 + b0) * 480 + col;
            stc(&ws[base],        a0);
            stc(&ws[base + 480],  a1);
            stc(&ws[base + 960],  a2);
            stc(&ws[base + 1440], a3);
        }
        asm volatile("s_waitcnt vmcnt(0)" ::: "memory");
        __syncthreads();
        if (tid == 0) {
            unsigned* cnt = (unsigned*)(ws + CNT_ZPG(bgz));
            const unsigned old = __hip_atomic_fetch_add(cnt, 1u, __ATOMIC_RELAXED, __HIP_MEMORY_SCOPE_AGENT);
            const unsigned base = 16u * (unsigned)t;
            int mb = -1;
            if (old >= base + 12u) {   // last 4 arrivers: stepA for one batch each
                mb = b0 + (int)(old - (base + 12u));
                while (__hip_atomic_load(cnt, __ATOMIC_RELAXED, __HIP_MEMORY_SCOPE_AGENT) < base + 16u)
                    __builtin_amdgcn_s_sleep(2);
            }
            myBatch = mb;
        }
        __syncthreads();
        if (myBatch >= 0) {
            stepA_fn(b_if, ws, t, myBatch, tid, sm);
            asm volatile("s_waitcnt vmcnt(0)" ::: "memory");  // drain ww/PARSE stc
            __syncthreads();
            if (tid == 0)
                __hip_atomic_store((unsigned*)(ws + CNT_FA(myBatch)), (unsigned)(t + 1),
                                   __ATOMIC_RELAXED, __HIP_MEMORY_SCOPE_AGENT);
        }
    }

    // ===== phase 2: link for (b, c) — wait for stepA[b] =====
    const int b = blk >> 3;
    const int c = blk & 7;
    if (tid == 0) {
        const unsigned* fa = (const unsigned*)(ws + CNT_FA(b));
        while (__hip_atomic_load(fa, __ATOMIC_RELAXED, __HIP_MEMORY_SCOPE_AGENT) < (unsigned)(t + 1))
            __builtin_amdgcn_s_sleep(2);
    }
    __syncthreads();
    asm volatile("" ::: "memory");

    {
        float* ww_s   = sm;          // 256
        float* prec_s = sm + 256;    // 256
        float* rw_s   = sm + 512;    // 1024
        float* pk_s   = sm + 1536;   // 448
        float* Lt     = sm + 2048;   // 32*257 = 8224
        const float* precOld = ws + OFF_PRECA + (t & 1) * (TB * TN) + b * 256;

        if (tid < 64)        { *(float4*)&ww_s[tid*4] = ldcv4(&ws[OFF_WW + b*256 + tid*4]); }
        else if (tid < 128)  { const int i = tid-64;  *(float4*)&prec_s[i*4] = *(const float4*)&precOld[i*4]; }
        else if (tid < 384)  { const int i = tid-128; *(float4*)&rw_s[i*4]   = *(const float4*)&ws[OFF_RW + b*1024 + i*4]; }
        else if (tid < 496)  { const int i = tid-384; *(float4*)&pk_s[i*4]   = ldcv4(&ws[OFF_PARSE + b*448 + i*4]); }
        __syncthreads();

        // ---- M update + norms + cr logits ----
        {
            const int ric = tid >> 4, c4 = (tid & 15) * 4;
            const int gi  = c * 32 + ric;
            float* mp = ws + OFF_M + b * (TN*TWM) + gi * 64 + c4;
            float4 m = *(const float4*)mp;   // prev-dispatch value
            const float wwi = ww_s[gi];
            float4 er = *(const float4*)&pk_s[256 + c4];
            float4 wv = *(const float4*)&pk_s[320 + c4];
            m.x = m.x * (1.0f - wwi * er.x) + wwi * wv.x;
            m.y = m.y * (1.0f - wwi * er.y) + wwi * wv.y;
            m.z = m.z * (1.0f - wwi * er.z) + wwi * wv.z;
            m.w = m.w * (1.0f - wwi * er.w) + wwi * wv.w;
            stcv4(mp, m);
            float sn = m.x*m.x + m.y*m.y + m.z*m.z + m.w*m.w;
            float d0 = m.x*pk_s[c4]     + m.y*pk_s[c4+1]     + m.z*pk_s[c4+2]     + m.w*pk_s[c4+3];
            float d1 = m.x*pk_s[64+c4]  + m.y*pk_s[64+c4+1]  + m.z*pk_s[64+c4+2]  + m.w*pk_s[64+c4+3];
            float d2 = m.x*pk_s[128+c4] + m.y*pk_s[128+c4+1] + m.z*pk_s[128+c4+2] + m.w*pk_s[128+c4+3];
            float d3 = m.x*pk_s[192+c4] + m.y*pk_s[192+c4+1] + m.z*pk_s[192+c4+2] + m.w*pk_s[192+c4+3];
            #pragma unroll
            for (int mm = 1; mm <= 8; mm <<= 1) {
                sn += __shfl_xor(sn, mm);
                d0 += __shfl_xor(d0, mm); d1 += __shfl_xor(d1, mm);
                d2 += __shfl_xor(d2, mm); d3 += __shfl_xor(d3, mm);
            }
            if ((tid & 15) == 0) {
                const float mn = fmaxf(sqrtf(sn), EPSI);
                ws[OFF_MNORM + b*256 + gi] = mn;   // next dispatch: plain
                const float inv = 1.0f / mn;
                stc(&ws[OFF_CRS + b*1024 + 0*256 + gi], pk_s[384+0] * d0 * inv / pk_s[388+0]);
                stc(&ws[OFF_CRS + b*1024 + 1*256 + gi], pk_s[384+1] * d1 * inv / pk_s[388+1]);
                stc(&ws[OFF_CRS + b*1024 + 2*256 + gi], pk_s[384+2] * d2 * inv / pk_s[388+2]);
                stc(&ws[OFF_CRS + b*1024 + 3*256 + gi], pk_s[384+3] * d3 * inv / pk_s[388+3]);
            }
        }

        // ---- link rows update (block-local: plain, stays in this XCD's L2) ----
        {
            const int j = tid & 255, p = tid >> 8;
            const float wwj = ww_s[j], pj = prec_s[j];
            #pragma unroll 4
            for (int it = 0; it < 16; ++it) {
                const int ric = it * 2 + p;
                const int gi  = c * 32 + ric;
                float* lp = ws + OFF_LINK + (size_t)b * (TN*TN) + (size_t)gi * 256 + j;
                const float wwi = ww_s[gi];
                float v = (1.0f - wwi - wwj) * (*lp) + wwi * pj;
                if (j == gi) v = 0.0f;
                *lp = v;
                Lt[ric * 257 + j] = v;
            }
        }
        __syncthreads();

        // ---- fw ----
        {
            const int ric = tid >> 4, g = tid & 15;
            const int gi = c * 32 + ric;
            float f0=0, f1=0, f2=0, f3=0;
            #pragma unroll 4
            for (int jj = 0; jj < 16; ++jj) {
                const int j = g * 16 + jj;
                const float v = Lt[ric * 257 + j];
                f0 += v * rw_s[j]; f1 += v * rw_s[256+j];
                f2 += v * rw_s[512+j]; f3 += v * rw_s[768+j];
            }
            #pragma unroll
            for (int mm = 1; mm <= 8; mm <<= 1) {
                f0 += __shfl_xor(f0, mm); f1 += __shfl_xor(f1, mm);
                f2 += __shfl_xor(f2, mm); f3 += __shfl_xor(f3, mm);
            }
            if (g == 0) {
                stc(&ws[OFF_FW + b*1024 + gi],       f0);
                stc(&ws[OFF_FW + b*1024 + 256 + gi], f1);
                stc(&ws[OFF_FW + b*1024 + 512 + gi], f2);
                stc(&ws[OFF_FW + b*1024 + 768 + gi], f3);
            }
        }

        // ---- bw partials ----
        {
            const int j = tid & 255, p = tid >> 8;
            float b0=0, b1=0, b2=0, b3=0;
            #pragma unroll 4
            for (int it = 0; it < 16; ++it) {
                const int ric = p * 16 + it;
                const int gi  = c * 32 + ric;
                const float v = Lt[ric * 257 + j];
                b0 += v * rw_s[gi]; b1 += v * rw_s[256+gi];
                b2 += v * rw_s[512+gi]; b3 += v * rw_s[768+gi];
            }
            __syncthreads();
            if (p == 1) { Lt[j] = b0; Lt[256+j] = b1; Lt[512+j] = b2; Lt[768+j] = b3; }
            __syncthreads();
            if (p == 0) {
                stc(&ws[OFF_BWP + (size_t)blk*1024 + j],       b0 + Lt[j]);
                stc(&ws[OFF_BWP + (size_t)blk*1024 + 256 + j], b1 + Lt[256+j]);
                stc(&ws[OFF_BWP + (size_t)blk*1024 + 512 + j], b2 + Lt[512+j]);
                stc(&ws[OFF_BWP + (size_t)blk*1024 + 768 + j], b3 + Lt[768+j]);
            }
        }
    }

    // ===== phase 3: stepB tail (last of the 8 chunk blocks per batch) =====
    asm volatile("s_waitcnt vmcnt(0)" ::: "memory");
    __syncthreads();
    if (tid == 0) {
        unsigned* cnt = (unsigned*)(ws + CNT_SB(b));
        const unsigned old = __hip_atomic_fetch_add(cnt, 1u, __ATOMIC_RELAXED, __HIP_MEMORY_SCOPE_AGENT);
        isTail = (old == 8u * (unsigned)t + 7u) ? 1 : 0;
    }
    __syncthreads();
    if (!isTail) return;
    stepB_fn(ws, t, b, tid, sm);
}

extern "C" void kernel_launch(void* const* d_in, const int* in_sizes, int n_in,
                              void* d_out, int out_size, void* d_ws, size_t ws_size,
                              hipStream_t stream) {
    const float* emb    = (const float*)d_in[0];
    const float* Wx     = (const float*)d_in[1];
    const float* Wh     = (const float*)d_in[2];
    const float* b_lstm = (const float*)d_in[3];
    const float* W_pre  = (const float*)d_in[4];
    const float* b_pre  = (const float*)d_in[5];
    const float* W_if   = (const float*)d_in[6];
    const float* b_if   = (const float*)d_in[7];
    const float* W_rout = (const float*)d_in[8];
    float* out = (float*)d_out;
    float* ws  = (float*)d_ws;

    k_init<<<(TOTAL_STATE + 255) / 256, 256, 0, stream>>>(ws);
    for (int t = 0; t < TT; ++t) {
        k_front<<<256, 512, 0, stream>>>(emb, Wx, Wh, b_lstm, W_pre, b_pre, W_rout, ws, out, t);
        k_step<<<256, 512, 0, stream>>>(W_if, b_if, ws, t);
    }
    // final out(127)
    k_front<<<256, 512, 0, stream>>>(emb, Wx, Wh, b_lstm, W_pre, b_pre, W_rout, ws, out, TT);
}

// Round 7
// 7252.848 us; speedup vs baseline: 3.2971x; 1.0072x over previous
//
#include <hip/hip_runtime.h>
#include <math.h>

// ---------------- problem constants ----------------
#define TN   256
#define TWM  64
#define TR   4
#define TH   512
#define TD   512
#define TT   128
#define TB   32
#define IFACE 471
#define EPSI 1e-6f

// ---------------- workspace layout (floats) ----------------
#define OFF_H      0          // 2 x 32*512 ping-pong
#define OFF_C      32768
#define OFF_M      49152      // 32*256*64
#define OFF_USAGE  573440
#define OFF_RW     581632     // 32*4*256
#define OFF_WW     614400
#define OFF_PRECA  622592     // prec ping/pong (2 x 8192)
#define OFF_LINK   638976     // 32*256*256
#define OFF_RVEC   2736128
#define OFF_MNORM  2744320    // 32*256
#define OFF_ZP     2752512    // 16 x 32 x 480 z partials
#define OFF_PARSE  2998272    // 32 x 448 parsed interface
#define OFF_CRS    3012608    // 32 x 4 x 256 cr logits
#define OFF_FW     3045376    // 32 x 4 x 256
#define OFF_BWP    3078144    // 256 x 4 x 256 bw chunk partials
#define OFF_CNT    3340288    // 88 counters x 16 floats
#define TOTAL_STATE 3341696

// counters (each on its own 64B line), all monotonic across t
#define CNT_ZPG(g) (OFF_CNT + (g)*16)          // 8 zp group counters
#define CNT_SB(b)  (OFF_CNT + (8+(b))*16)      // 32 stepB tail counters
#define CNT_FA(b)  (OFF_CNT + (40+(b))*16)     // 32 stepA done flags
#define CNT_GG(g)  (OFF_CNT + (72+(g))*16)     // 16 gates col-group counters

__device__ __forceinline__ float sigm(float x)  { return 1.0f / (1.0f + expf(-x)); }
__device__ __forceinline__ float softpl(float x){ return x > 20.0f ? x : log1pf(expf(x)); }

// ---- device-coherent (MALL) access, used ONLY for same-dispatch handoffs ----
__device__ __forceinline__ float ldc(const float* p) {
    return __hip_atomic_load(p, __ATOMIC_RELAXED, __HIP_MEMORY_SCOPE_AGENT);
}
__device__ __forceinline__ void stc(float* p, float v) {
    __hip_atomic_store(p, v, __ATOMIC_RELAXED, __HIP_MEMORY_SCOPE_AGENT);
}
__device__ __forceinline__ float4 ldcv4(const float* p) {
    float4 v;
    v.x = ldc(p); v.y = ldc(p + 1); v.z = ldc(p + 2); v.w = ldc(p + 3);
    return v;
}
__device__ __forceinline__ void stcv4(float* p, float4 v) {
    stc(p, v.x); stc(p + 1, v.y); stc(p + 2, v.z); stc(p + 3, v.w);
}

// ---------------- init ----------------
__global__ void k_init(float* ws) {
    int idx = blockIdx.x * 256 + threadIdx.x;
    if (idx >= TOTAL_STATE) return;
    float v = 0.0f;
    if (idx >= OFF_M && idx < OFF_M + TB*TN*TWM) v = EPSI;
    if (idx >= OFF_MNORM && idx < OFF_MNORM + TB*TN) v = 8e-6f;
    ws[idx] = v;
}

// ---------------- out(t-1) GEMM device fn (prev-dispatch inputs: plain) ----------------
__device__ __forceinline__ void out_phase(
    const float* __restrict__ W_pre, const float* __restrict__ b_pre,
    const float* __restrict__ W_rout, const float* __restrict__ ws,
    float* __restrict__ out, float* sm, const int tid, const int B2, const int t)
{
    float* act_s = sm;          // 4 batches x 768
    float* red_s = sm + 3072;   // 16 ksub x 4 b x 32 col
    const int q = B2 >> 5, s = (B2 >> 3) & 3, bg = B2 & 7, b0 = bg * 4;
    for (int i = tid; i < 768; i += 512) {
        const int bb = i / 192;
        const int k0 = (i - bb*192) * 4;
        const float* src = (k0 < 512) ? &ws[OFF_H + (t&1)*(TB*TH) + (b0+bb)*TH + k0]
                                      : &ws[OFF_RVEC + (b0+bb)*256 + (k0 - 512)];
        *(float4*)&act_s[bb*768 + k0] = *(const float4*)src;
    }
    __syncthreads();
    const int c0 = q*128 + s*32;
    const int col = tid & 31;
    const int ksb = tid >> 5;
    float a0=0, a1=0, a2=0, a3=0;
    for (int kk = ksb*48; kk < ksb*48 + 48; ++kk) {
        const float w = (kk < 512) ? W_pre[(size_t)kk * 512 + c0 + col]
                                   : W_rout[(size_t)(kk - 512) * 512 + c0 + col];
        a0 += act_s[kk]        * w;
        a1 += act_s[768 + kk]  * w;
        a2 += act_s[1536 + kk] * w;
        a3 += act_s[2304 + kk] * w;
    }
    red_s[(ksb*4 + 0)*32 + col] = a0;
    red_s[(ksb*4 + 1)*32 + col] = a1;
    red_s[(ksb*4 + 2)*32 + col] = a2;
    red_s[(ksb*4 + 3)*32 + col] = a3;
    __syncthreads();
    if (tid < 128) {
        const int cc = tid & 31, bb = tid >> 5;
        float ssum = 0.0f;
        #pragma unroll
        for (int ks2 = 0; ks2 < 16; ++ks2) ssum += red_s[(ks2*4 + bb)*32 + cc];
        ssum += b_pre[c0 + cc];
        out[(size_t)(t - 1) * (TB * TD) + (b0+bb) * TD + c0 + cc] = ssum;
    }
}

// ---------------- stepA device fn (ZP via ldc; WW/PARSE via stc) ----------------
__device__ void stepA_fn(const float* __restrict__ b_if, float* __restrict__ ws,
                         const int t, const int b, const int tid, float* sm)
{
    float* z_s      = sm + 0;
    float* rwf_s    = sm + 480;
    float* ww_old_s = sm + 1504;
    float* ww_s     = sm + 1760;
    float* u_s      = sm + 2016;
    float* prec_s   = sm + 2272;
    float* mnorm_s  = sm + 2528;
    float* alloc_s  = sm + 2784;
    float* cw_s     = sm + 3040;
    float* keysp    = sm + 3296;
    float* wkey_s   = sm + 3552;
    float* erase_s  = sm + 3616;
    float* wvec_s   = sm + 3680;
    float* rstr_s   = sm + 3744;
    float* free_s   = sm + 3748;
    float* modesp   = sm + 3752;
    float* knorm_s  = sm + 3764;
    float* sredA_s  = sm + 3772;
    float* sc_s     = sm + 3780;
    float* Pt_s     = sm + 3788;   // 512 -> ends 4300

    const float* wsM = ws + OFF_M + b * (TN * TWM);
    const float* precOld = ws + OFF_PRECA + (t & 1) * (TB * TN) + b * 256;
    float* precNew = ws + OFF_PRECA + ((t + 1) & 1) * (TB * TN) + b * 256;

    if (tid < 256)       { *(float4*)&rwf_s[tid*4] = *(const float4*)&ws[OFF_RW + b*1024 + tid*4]; }
    else if (tid < 320)  { const int i = tid-256; *(float4*)&ww_old_s[i*4] = *(const float4*)&ws[OFF_WW + b*256 + i*4]; }
    else if (tid < 384)  { const int i = tid-320; *(float4*)&u_s[i*4]      = *(const float4*)&ws[OFF_USAGE + b*256 + i*4]; }
    else if (tid < 448)  { const int i = tid-384; *(float4*)&prec_s[i*4]   = *(const float4*)&precOld[i*4]; }
    else                 { const int i = tid-448; *(float4*)&mnorm_s[i*4]  = *(const float4*)&ws[OFF_MNORM + b*256 + i*4]; }
    if (tid < IFACE) {
        float part[16];
        #pragma unroll
        for (int p = 0; p < 16; ++p)
            part[p] = ldc(&ws[OFF_ZP + ((size_t)p*32 + b) * 480 + tid]);
        float zv = b_if[tid];
        #pragma unroll
        for (int p = 0; p < 16; ++p) zv += part[p];
        z_s[tid] = zv;
    }
    __syncthreads();

    if (tid < IFACE) {
        const float v = z_s[tid];
        if (tid < 256)       keysp[(tid >> 6)*64 + (tid & 63)] = v;
        else if (tid < 260)  rstr_s[tid - 256] = 1.0f + softpl(v);
        else if (tid < 324)  wkey_s[tid - 260] = v;
        else if (tid == 324) sc_s[0] = 1.0f + softpl(v);
        else if (tid < 389)  erase_s[tid - 325] = sigm(v);
        else if (tid < 453)  wvec_s[tid - 389] = v;
        else if (tid < 457)  free_s[tid - 453] = sigm(v);
        else if (tid == 457) sc_s[1] = sigm(v);
        else if (tid == 458) sc_s[2] = sigm(v);
    }
    __syncthreads();
    if (tid < 320) {
        const int w5 = tid >> 6, lane = tid & 63;
        const float v = (w5 == 0) ? wkey_s[lane] : keysp[(w5 - 1)*64 + lane];
        float s = v * v;
        #pragma unroll
        for (int m = 1; m <= 32; m <<= 1) s += __shfl_xor(s, m);
        if (lane == 0) knorm_s[w5] = fmaxf(sqrtf(s), EPSI);
    } else if (tid >= 508) {
        const int r = tid - 508;
        const float m0 = z_s[459 + r*3], m1 = z_s[460 + r*3], m2 = z_s[461 + r*3];
        const float mx = fmaxf(m0, fmaxf(m1, m2));
        const float e0 = expf(m0 - mx), e1 = expf(m1 - mx), e2 = expf(m2 - mx);
        const float s = e0 + e1 + e2;
        modesp[r*3+0] = e0 / s; modesp[r*3+1] = e1 / s; modesp[r*3+2] = e2 / s;
    }
    __syncthreads();

    if (tid < 404) {
        float v;
        if (tid < 256)       v = keysp[tid];
        else if (tid < 320)  v = erase_s[tid - 256];
        else if (tid < 384)  v = wvec_s[tid - 320];
        else if (tid < 388)  v = rstr_s[tid - 384];
        else if (tid < 392)  v = knorm_s[tid - 388 + 1];
        else                 v = modesp[tid - 392];
        stc(&ws[OFF_PARSE + b * 448 + tid], v);
    }
    if (tid < 256) {
        float ret = 1.0f;
        #pragma unroll
        for (int r = 0; r < 4; ++r) ret *= 1.0f - free_s[r] * rwf_s[r*256 + tid];
        const float un = (u_s[tid] + ww_old_s[tid] - u_s[tid] * ww_old_s[tid]) * ret;
        u_s[tid] = un;
        ws[OFF_USAGE + b * 256 + tid] = un;   // next dispatch: plain
    }
    __syncthreads();

    {
        const int q = tid >> 8, n = tid & 255;
        const float un = u_s[n];
        float p = 1.0f;
        #pragma unroll 8
        for (int m = q * 128; m < q * 128 + 128; ++m) {
            const float um = u_s[m];
            const bool lt = (um < un) || (um == un && m < n);
            p *= lt ? um : 1.0f;
        }
        Pt_s[q * 256 + n] = p;
    }
    __syncthreads();
    if (tid < 256)
        alloc_s[tid] = (1.0f - u_s[tid]) * Pt_s[tid] * Pt_s[256 + tid];
    __syncthreads();

    {
        const int n = tid >> 1, q2 = tid & 1;
        const float* mp = wsM + n * 64 + q2 * 32;
        float s = 0.0f;
        #pragma unroll
        for (int it = 0; it < 8; ++it) {
            float4 mv = *(const float4*)(mp + it * 4);
            float4 kv = *(const float4*)&wkey_s[q2 * 32 + it * 4];
            s += mv.x*kv.x + mv.y*kv.y + mv.z*kv.z + mv.w*kv.w;
        }
        s += __shfl_xor(s, 1);
        if (q2 == 0) cw_s[n] = sc_s[0] * s / (knorm_s[0] * mnorm_s[n]);
    }
    __syncthreads();
    {
        float v = 0.0f, e = 0.0f;
        if (tid < 256) {
            v = cw_s[tid];
            float m = v;
            #pragma unroll
            for (int mm = 1; mm <= 32; mm <<= 1) m = fmaxf(m, __shfl_xor(m, mm));
            if ((tid & 63) == 0) sredA_s[tid >> 6] = m;
        }
        __syncthreads();
        if (tid == 0) sc_s[4] = fmaxf(fmaxf(sredA_s[0], sredA_s[1]), fmaxf(sredA_s[2], sredA_s[3]));
        __syncthreads();
        if (tid < 256) {
            e = expf(v - sc_s[4]);
            float s2 = e;
            #pragma unroll
            for (int mm = 1; mm <= 32; mm <<= 1) s2 += __shfl_xor(s2, mm);
            if ((tid & 63) == 0) sredA_s[tid >> 6] = s2;
        }
        __syncthreads();
        if (tid == 0) sc_s[5] = sredA_s[0] + sredA_s[1] + sredA_s[2] + sredA_s[3];
        __syncthreads();
        if (tid < 256) cw_s[tid] = e / sc_s[5];
    }
    __syncthreads();

    if (tid < 256) {
        const float wwn = sc_s[2] * (sc_s[1] * alloc_s[tid] + (1.0f - sc_s[1]) * cw_s[tid]);
        ww_s[tid] = wwn;
        stc(&ws[OFF_WW + b * 256 + tid], wwn);
    }
    __syncthreads();
    if (tid < 256) {
        float s = ww_s[tid];
        #pragma unroll
        for (int mm = 1; mm <= 32; mm <<= 1) s += __shfl_xor(s, mm);
        if ((tid & 63) == 0) sredA_s[tid >> 6] = s;
    }
    __syncthreads();
    if (tid == 0) sc_s[3] = sredA_s[0] + sredA_s[1] + sredA_s[2] + sredA_s[3];
    __syncthreads();
    if (tid < 256)
        precNew[tid] = (1.0f - sc_s[3]) * prec_s[tid] + ww_s[tid];  // next dispatch: plain
}

// ---------------- stepB device fn (same-dispatch data via ldc) ----------------
__device__ void stepB_fn(float* __restrict__ ws, const int t, const int b,
                         const int tid, float* sm)
{
    float* crp     = sm;          // 4 x 256
    float* rw2_s   = sm + 1024;   // 1024
    float* Lt2     = sm + 2048;   // 2048
    float* md      = sm + 4096;   // 12
    float* sredA_s = sm + 4112;   // 8
    float* sredB_s = sm + 4120;   // 8
    float* gmax_s  = sm + 4128;   // 4
    float* gsum_s  = sm + 4132;   // 4
    const float* wsM = ws + OFF_M + b * (TN * TWM);

    crp[tid]       = ldc(&ws[OFF_CRS + b*1024 + tid]);
    crp[tid + 512] = ldc(&ws[OFF_CRS + b*1024 + tid + 512]);
    if (tid < 12) md[tid] = ldc(&ws[OFF_PARSE + b*448 + 392 + tid]);
    __syncthreads();

    {
        const int rr = tid >> 8, n = tid & 255, wv = tid >> 6, lane = tid & 63;
        float v0 = crp[rr*256 + n], v1 = crp[(rr + 2)*256 + n];
        float m0 = v0, m1 = v1;
        #pragma unroll
        for (int mm = 1; mm <= 32; mm <<= 1) {
            m0 = fmaxf(m0, __shfl_xor(m0, mm));
            m1 = fmaxf(m1, __shfl_xor(m1, mm));
        }
        if (lane == 0) { sredA_s[wv] = m0; sredB_s[wv] = m1; }
        __syncthreads();
        if (tid < 4) {
            const float* base = (tid & 2) ? sredB_s : sredA_s;
            const int off = (tid & 1) * 4;
            gmax_s[tid] = fmaxf(fmaxf(base[off], base[off+1]), fmaxf(base[off+2], base[off+3]));
        }
        __syncthreads();
        const float e0 = expf(v0 - gmax_s[rr]);
        const float e1 = expf(v1 - gmax_s[rr + 2]);
        float s0 = e0, s1 = e1;
        #pragma unroll
        for (int mm = 1; mm <= 32; mm <<= 1) {
            s0 += __shfl_xor(s0, mm); s1 += __shfl_xor(s1, mm);
        }
        if (lane == 0) { sredA_s[wv] = s0; sredB_s[wv] = s1; }
        __syncthreads();
        if (tid < 4) {
            const float* base = (tid & 2) ? sredB_s : sredA_s;
            const int off = (tid & 1) * 4;
            gsum_s[tid] = base[off] + base[off+1] + base[off+2] + base[off+3];
        }
        __syncthreads();
        crp[rr*256 + n]       = e0 / gsum_s[rr];
        crp[(rr + 2)*256 + n] = e1 / gsum_s[rr + 2];
    }
    __syncthreads();

    {
        const int rr = tid >> 8, n = tid & 255;
        #pragma unroll
        for (int p = 0; p < 2; ++p) {
            const int r = rr + 2 * p;
            float part[8];
            #pragma unroll
            for (int c = 0; c < 8; ++c)
                part[c] = ldc(&ws[OFF_BWP + (size_t)(b*8 + c)*1024 + r*256 + n]);
            const float fwv = ldc(&ws[OFF_FW + b*1024 + r*256 + n]);
            float bw = 0.0f;
            #pragma unroll
            for (int c = 0; c < 8; ++c) bw += part[c];
            const float v = md[r*3] * bw + md[r*3+1] * crp[r*256 + n] + md[r*3+2] * fwv;
            rw2_s[r*256 + n] = v;
            ws[OFF_RW + b*1024 + r*256 + n] = v;   // next dispatch: plain
        }
    }
    __syncthreads();

    {
        const int g8 = tid >> 6, w = tid & 63;
        float p0=0, p1=0, p2=0, p3=0;
        const float* mb = wsM + (size_t)(g8 * 32) * 64 + w;
        for (int gg = 0; gg < 4; ++gg) {
            float mv[8];
            #pragma unroll
            for (int j = 0; j < 8; ++j) mv[j] = ldc(mb + (gg*8 + j) * 64);
            #pragma unroll
            for (int j = 0; j < 8; ++j) {
                const int n = g8*32 + gg*8 + j;
                p0 += rw2_s[n]       * mv[j];
                p1 += rw2_s[256 + n] * mv[j];
                p2 += rw2_s[512 + n] * mv[j];
                p3 += rw2_s[768 + n] * mv[j];
            }
        }
        Lt2[(g8*4 + 0)*64 + w] = p0;
        Lt2[(g8*4 + 1)*64 + w] = p1;
        Lt2[(g8*4 + 2)*64 + w] = p2;
        Lt2[(g8*4 + 3)*64 + w] = p3;
    }
    __syncthreads();
    if (tid < 256) {
        const int r = tid >> 6, w = tid & 63;
        float s = 0.0f;
        #pragma unroll
        for (int g = 0; g < 8; ++g) s += Lt2[(g*4 + r)*64 + w];
        ws[OFF_RVEC + b * 256 + tid] = s;          // next dispatch: plain
    }
}

// ---------------- THE step kernel: gates||out -> zp -> stepA -> link -> stepB ----------------
__global__ __launch_bounds__(512) void k_all(
    const float* __restrict__ emb, const float* __restrict__ Wx,
    const float* __restrict__ Wh,  const float* __restrict__ b_lstm,
    const float* __restrict__ W_pre, const float* __restrict__ b_pre,
    const float* __restrict__ W_rout,
    const float* __restrict__ W_if, const float* __restrict__ b_if,
    float* __restrict__ ws, float* __restrict__ out, int t)
{
    __shared__ __align__(16) float sm[16384];   // 64 KB, reused per phase
    __shared__ int myBatch;
    __shared__ int isTail;
    const int tid = threadIdx.x;
    const int blk = blockIdx.x;

    if (blk >= 128) {
        // ===== out(t-1) =====
        if (t > 0) {
            const int raw2 = blk - 128;
            const int B2 = (((raw2 >> 2) & 3) << 5) | ((raw2 & 3) << 3) | (raw2 >> 4);
            out_phase(W_pre, b_pre, W_rout, ws, out, sm, tid, B2, t);
        }
    } else if (t < TT) {
        // ===== gates (4 u-cols per block) =====
        const int ublk = ((blk & 7) << 4) | (blk >> 3);
        const int u0  = ublk * 4;
        {
            const int cg  = tid & 3;
            const int bg  = (tid >> 2) & 7;
            const int ks  = tid >> 5;
            const int col0 = cg * 512 + u0;
            const float* hbuf = ws + OFF_H + (t & 1) * (TB * TH);

            float acc[4][4] = {};

            for (int tile = 0; tile < 5; ++tile) {
                const int T0 = tile * 256;
                {
                    const int b = tid & 31, kf4 = tid >> 5;
                    #pragma unroll
                    for (int i = 0; i < 4; ++i) {
                        const int kf = kf4 * 4 + i;
                        const int kl = kf * 4;
                        const int k  = T0 + kl;
                        const float* src;
                        if (k < 512)      src = emb + (size_t)t * (TB*TD) + b * TD + k;
                        else if (k < 768) src = ws + OFF_RVEC + b * 256 + (k - 512);
                        else              src = hbuf + b * TH + (k - 768);
                        float4 v = *(const float4*)src;
                        sm[(kl+0)*32 + b] = v.x;
                        sm[(kl+1)*32 + b] = v.y;
                        sm[(kl+2)*32 + b] = v.z;
                        sm[(kl+3)*32 + b] = v.w;
                    }
                }
                __syncthreads();
                {
                    const int k0 = T0 + ks * 16;
                    const float* wp = (k0 < 768 ? Wx + (size_t)k0 * 2048
                                                : Wh + (size_t)(k0 - 768) * 2048) + col0;
                    const float* ap = &sm[(ks * 16) * 32 + bg * 4];
                    #pragma unroll 8
                    for (int kk = 0; kk < 16; ++kk) {
                        float4 wv = *(const float4*)wp; wp += 2048;
                        float4 av = *(const float4*)ap; ap += 32;
                        acc[0][0] += wv.x*av.x; acc[0][1] += wv.x*av.y; acc[0][2] += wv.x*av.z; acc[0][3] += wv.x*av.w;
                        acc[1][0] += wv.y*av.x; acc[1][1] += wv.y*av.y; acc[1][2] += wv.y*av.z; acc[1][3] += wv.y*av.w;
                        acc[2][0] += wv.z*av.x; acc[2][1] += wv.z*av.y; acc[2][2] += wv.z*av.z; acc[2][3] += wv.z*av.w;
                        acc[3][0] += wv.w*av.x; acc[3][1] += wv.w*av.y; acc[3][2] += wv.w*av.z; acc[3][3] += wv.w*av.w;
                    }
                }
                __syncthreads();
            }

            {
                const int rbase = 8192 + ks * 512 + (cg * 8 + bg) * 16;
                *(float4*)&sm[rbase + 0]  = make_float4(acc[0][0], acc[0][1], acc[0][2], acc[0][3]);
                *(float4*)&sm[rbase + 4]  = make_float4(acc[1][0], acc[1][1], acc[1][2], acc[1][3]);
                *(float4*)&sm[rbase + 8]  = make_float4(acc[2][0], acc[2][1], acc[2][2], acc[2][3]);
                *(float4*)&sm[rbase + 12] = make_float4(acc[3][0], acc[3][1], acc[3][2], acc[3][3]);
            }
            __syncthreads();
            {
                const int o = tid;
                float s = 0.0f;
                #pragma unroll
                for (int kq = 0; kq < 16; ++kq) s += sm[8192 + kq * 512 + o];
                const int ocg = o >> 7, obg = (o >> 4) & 7, odu = (o >> 2) & 3, obb = o & 3;
                s += b_lstm[ocg * 512 + u0 + odu];
                sm[(ocg * 4 + odu) * 32 + (obg * 4 + obb)] = s;
            }
            __syncthreads();
            if (tid < 128) {
                const int du = tid >> 5, b = tid & 31;
                const float ig = sm[(0  + du) * 32 + b];
                const float fg = sm[(4  + du) * 32 + b];
                const float gg = sm[(8  + du) * 32 + b];
                const float og = sm[(12 + du) * 32 + b];
                const int ci = b * TH + u0 + du;
                const float cold = ws[OFF_C + ci];        // block-local
                const float cn = sigm(fg) * cold + sigm(ig) * tanhf(gg);
                const float hn = sigm(og) * tanhf(cn);
                ws[OFF_C + ci] = cn;                      // block-local
                stc(&ws[OFF_H + ((t + 1) & 1) * (TB * TH) + ci], hn);  // same-dispatch zp reads
            }
        }
        asm volatile("s_waitcnt vmcnt(0)" ::: "memory");
        __syncthreads();
        if (tid == 0)
            __hip_atomic_fetch_add((unsigned*)(ws + CNT_GG(ublk >> 3)), 1u,
                                   __ATOMIC_RELAXED, __HIP_MEMORY_SCOPE_AGENT);

        // ===== zp (wait only for own col-group: 8 gates blocks) =====
        const int bgz = blk >> 4;
        const int q = (blk >> 2) & 3, s = blk & 3;
        const int b0 = bgz * 4;
        if (tid == 0) {
            const unsigned* gg = (const unsigned*)(ws + CNT_GG(q*4 + s));
            while (__hip_atomic_load(gg, __ATOMIC_RELAXED, __HIP_MEMORY_SCOPE_AGENT) < 8u * (unsigned)(t + 1))
                __builtin_amdgcn_s_sleep(2);
        }
        __syncthreads();
        {
            float* h1_s = sm;
            if (tid < 128) {
                const int bb = tid >> 5, kk = tid & 31;
                h1_s[bb*32 + kk] = ldc(&ws[OFF_H + ((t+1)&1)*(TB*TH) + (b0+bb)*TH + q*128 + s*32 + kk]);
            }
            __syncthreads();
            if (tid < IFACE) {
                const int col = tid;
                float a0=0, a1=0, a2=0, a3=0;
                const float* wb = W_if + (size_t)(q*128 + s*32) * IFACE + col;
                #pragma unroll 8
                for (int kk = 0; kk < 32; ++kk) {
                    const float w = *wb; wb += IFACE;
                    a0 += h1_s[kk]      * w;
                    a1 += h1_s[32+kk]   * w;
                    a2 += h1_s[64+kk]   * w;
                    a3 += h1_s[96+kk]   * w;
                }
                const size_t base = OFF_ZP + ((size_t)(q*4+s)*32 + b0) * 480 + col;
                stc(&ws[base],        a0);
                stc(&ws[base + 480],  a1);
                stc(&ws[base + 960],  a2);
                stc(&ws[base + 1440], a3);
            }
        }
        asm volatile("s_waitcnt vmcnt(0)" ::: "memory");
        __syncthreads();
        if (tid == 0) {
            unsigned* cnt = (unsigned*)(ws + CNT_ZPG(bgz));
            const unsigned old = __hip_atomic_fetch_add(cnt, 1u, __ATOMIC_RELAXED, __HIP_MEMORY_SCOPE_AGENT);
            const unsigned base = 16u * (unsigned)t;
            int mb = -1;
            if (old >= base + 12u) {   // last 4 arrivers: stepA for one batch each
                mb = b0 + (int)(old - (base + 12u));
                while (__hip_atomic_load(cnt, __ATOMIC_RELAXED, __HIP_MEMORY_SCOPE_AGENT) < base + 16u)
                    __builtin_amdgcn_s_sleep(2);
            }
            myBatch = mb;
        }
        __syncthreads();
        if (myBatch >= 0) {
            stepA_fn(b_if, ws, t, myBatch, tid, sm);
            asm volatile("s_waitcnt vmcnt(0)" ::: "memory");
            __syncthreads();
            if (tid == 0)
                __hip_atomic_store((unsigned*)(ws + CNT_FA(myBatch)), (unsigned)(t + 1),
                                   __ATOMIC_RELAXED, __HIP_MEMORY_SCOPE_AGENT);
        }
    }

    if (t >= TT) return;

    // ===== link for (b, c) — wait for stepA[b] =====
    const int b = blk >> 3;
    const int c = blk & 7;
    if (tid == 0) {
        const unsigned* fa = (const unsigned*)(ws + CNT_FA(b));
        while (__hip_atomic_load(fa, __ATOMIC_RELAXED, __HIP_MEMORY_SCOPE_AGENT) < (unsigned)(t + 1))
            __builtin_amdgcn_s_sleep(2);
    }
    __syncthreads();
    asm volatile("" ::: "memory");

    {
        float* ww_s   = sm;          // 256
        float* prec_s = sm + 256;    // 256
        float* rw_s   = sm + 512;    // 1024
        float* pk_s   = sm + 1536;   // 448
        float* Lt     = sm + 2048;   // 32*257 = 8224
        const float* precOld = ws + OFF_PRECA + (t & 1) * (TB * TN) + b * 256;

        if (tid < 64)        { *(float4*)&ww_s[tid*4] = ldcv4(&ws[OFF_WW + b*256 + tid*4]); }
        else if (tid < 128)  { const int i = tid-64;  *(float4*)&prec_s[i*4] = *(const float4*)&precOld[i*4]; }
        else if (tid < 384)  { const int i = tid-128; *(float4*)&rw_s[i*4]   = *(const float4*)&ws[OFF_RW + b*1024 + i*4]; }
        else if (tid < 496)  { const int i = tid-384; *(float4*)&pk_s[i*4]   = ldcv4(&ws[OFF_PARSE + b*448 + i*4]); }
        __syncthreads();

        // ---- M update + norms + cr logits ----
        {
            const int ric = tid >> 4, c4 = (tid & 15) * 4;
            const int gi  = c * 32 + ric;
            float* mp = ws + OFF_M + b * (TN*TWM) + gi * 64 + c4;
            float4 m = *(const float4*)mp;   // prev-dispatch value
            const float wwi = ww_s[gi];
            float4 er = *(const float4*)&pk_s[256 + c4];
            float4 wv = *(const float4*)&pk_s[320 + c4];
            m.x = m.x * (1.0f - wwi * er.x) + wwi * wv.x;
            m.y = m.y * (1.0f - wwi * er.y) + wwi * wv.y;
            m.z = m.z * (1.0f - wwi * er.z) + wwi * wv.z;
            m.w = m.w * (1.0f - wwi * er.w) + wwi * wv.w;
            stcv4(mp, m);
            float sn = m.x*m.x + m.y*m.y + m.z*m.z + m.w*m.w;
            float d0 = m.x*pk_s[c4]     + m.y*pk_s[c4+1]     + m.z*pk_s[c4+2]     + m.w*pk_s[c4+3];
            float d1 = m.x*pk_s[64+c4]  + m.y*pk_s[64+c4+1]  + m.z*pk_s[64+c4+2]  + m.w*pk_s[64+c4+3];
            float d2 = m.x*pk_s[128+c4] + m.y*pk_s[128+c4+1] + m.z*pk_s[128+c4+2] + m.w*pk_s[128+c4+3];
            float d3 = m.x*pk_s[192+c4] + m.y*pk_s[192+c4+1] + m.z*pk_s[192+c4+2] + m.w*pk_s[192+c4+3];
            #pragma unroll
            for (int mm = 1; mm <= 8; mm <<= 1) {
                sn += __shfl_xor(sn, mm);
                d0 += __shfl_xor(d0, mm); d1 += __shfl_xor(d1, mm);
                d2 += __shfl_xor(d2, mm); d3 += __shfl_xor(d3, mm);
            }
            if ((tid & 15) == 0) {
                const float mn = fmaxf(sqrtf(sn), EPSI);
                ws[OFF_MNORM + b*256 + gi] = mn;   // next dispatch: plain
                const float inv = 1.0f / mn;
                stc(&ws[OFF_CRS + b*1024 + 0*256 + gi], pk_s[384+0] * d0 * inv / pk_s[388+0]);
                stc(&ws[OFF_CRS + b*1024 + 1*256 + gi], pk_s[384+1] * d1 * inv / pk_s[388+1]);
                stc(&ws[OFF_CRS + b*1024 + 2*256 + gi], pk_s[384+2] * d2 * inv / pk_s[388+2]);
                stc(&ws[OFF_CRS + b*1024 + 3*256 + gi], pk_s[384+3] * d3 * inv / pk_s[388+3]);
            }
        }

        // ---- link rows update (block-local: plain) ----
        {
            const int j = tid & 255, p = tid >> 8;
            const float wwj = ww_s[j], pj = prec_s[j];
            #pragma unroll 4
            for (int it = 0; it < 16; ++it) {
                const int ric = it * 2 + p;
                const int gi  = c * 32 + ric;
                float* lp = ws + OFF_LINK + (size_t)b * (TN*TN) + (size_t)gi * 256 + j;
                const float wwi = ww_s[gi];
                float v = (1.0f - wwi - wwj) * (*lp) + wwi * pj;
                if (j == gi) v = 0.0f;
                *lp = v;
                Lt[ric * 257 + j] = v;
            }
        }
        __syncthreads();

        // ---- fw ----
        {
            const int ric = tid >> 4, g = tid & 15;
            const int gi = c * 32 + ric;
            float f0=0, f1=0, f2=0, f3=0;
            #pragma unroll 4
            for (int jj = 0; jj < 16; ++jj) {
                const int j = g * 16 + jj;
                const float v = Lt[ric * 257 + j];
                f0 += v * rw_s[j]; f1 += v * rw_s[256+j];
                f2 += v * rw_s[512+j]; f3 += v * rw_s[768+j];
            }
            #pragma unroll
            for (int mm = 1; mm <= 8; mm <<= 1) {
                f0 += __shfl_xor(f0, mm); f1 += __shfl_xor(f1, mm);
                f2 += __shfl_xor(f2, mm); f3 += __shfl_xor(f3, mm);
            }
            if (g == 0) {
                stc(&ws[OFF_FW + b*1024 + gi],       f0);
                stc(&ws[OFF_FW + b*1024 + 256 + gi], f1);
                stc(&ws[OFF_FW + b*1024 + 512 + gi], f2);
                stc(&ws[OFF_FW + b*1024 + 768 + gi], f3);
            }
        }

        // ---- bw partials ----
        {
            const int j = tid & 255, p = tid >> 8;
            float b0=0, b1=0, b2=0, b3=0;
            #pragma unroll 4
            for (int it = 0; it < 16; ++it) {
                const int ric = p * 16 + it;
                const int gi  = c * 32 + ric;
                const float v = Lt[ric * 257 + j];
                b0 += v * rw_s[gi]; b1 += v * rw_s[256+gi];
                b2 += v * rw_s[512+gi]; b3 += v * rw_s[768+gi];
            }
            __syncthreads();
            if (p == 1) { Lt[j] = b0; Lt[256+j] = b1; Lt[512+j] = b2; Lt[768+j] = b3; }
            __syncthreads();
            if (p == 0) {
                stc(&ws[OFF_BWP + (size_t)blk*1024 + j],       b0 + Lt[j]);
                stc(&ws[OFF_BWP + (size_t)blk*1024 + 256 + j], b1 + Lt[256+j]);
                stc(&ws[OFF_BWP + (size_t)blk*1024 + 512 + j], b2 + Lt[512+j]);
                stc(&ws[OFF_BWP + (size_t)blk*1024 + 768 + j], b3 + Lt[768+j]);
            }
        }
    }

    // ===== stepB tail (last of the 8 chunk blocks per batch) =====
    asm volatile("s_waitcnt vmcnt(0)" ::: "memory");
    __syncthreads();
    if (tid == 0) {
        unsigned* cnt = (unsigned*)(ws + CNT_SB(b));
        const unsigned old = __hip_atomic_fetch_add(cnt, 1u, __ATOMIC_RELAXED, __HIP_MEMORY_SCOPE_AGENT);
        isTail = (old == 8u * (unsigned)t + 7u) ? 1 : 0;
    }
    __syncthreads();
    if (!isTail) return;
    stepB_fn(ws, t, b, tid, sm);
}

extern "C" void kernel_launch(void* const* d_in, const int* in_sizes, int n_in,
                              void* d_out, int out_size, void* d_ws, size_t ws_size,
                              hipStream_t stream) {
    const float* emb    = (const float*)d_in[0];
    const float* Wx     = (const float*)d_in[1];
    const float* Wh     = (const float*)d_in[2];
    const float* b_lstm = (const float*)d_in[3];
    const float* W_pre  = (const float*)d_in[4];
    const float* b_pre  = (const float*)d_in[5];
    const float* W_if   = (const float*)d_in[6];
    const float* b_if   = (const float*)d_in[7];
    const float* W_rout = (const float*)d_in[8];
    float* out = (float*)d_out;
    float* ws  = (float*)d_ws;

    k_init<<<(TOTAL_STATE + 255) / 256, 256, 0, stream>>>(ws);
    for (int t = 0; t < TT; ++t) {
        k_all<<<256, 512, 0, stream>>>(emb, Wx, Wh, b_lstm, W_pre, b_pre, W_rout,
                                       W_if, b_if, ws, out, t);
    }
    // final out(127): blocks 0..127 idle, blocks 128..255 write row 127
    k_all<<<256, 512, 0, stream>>>(emb, Wx, Wh, b_lstm, W_pre, b_pre, W_rout,
                                   W_if, b_if, ws, out, TT);
}